// Round 3
// baseline (452.562 us; speedup 1.0000x reference)
//
#include <hip/hip_runtime.h>
#include <hip/hip_bf16.h>

#define N_NODES 6144
#define NQ_ 3072
#define D 128
#define H 4
#define C 32
#define F_IN 10
#define L_LAYERS 4
#define E_EDGES 393216
#define E_TOT (E_EDGES + N_NODES)
#define SPLITS 4
#define KV_PER (N_NODES / SPLITS)  // 1536 keys per split = 24 tiles of 64

typedef __attribute__((ext_vector_type(8))) short bf16x8;
typedef __attribute__((ext_vector_type(4))) float f32x4;

__device__ __forceinline__ unsigned short f2bf(float f) {
  unsigned u = __float_as_uint(f);
  unsigned r = (u + 0x7fffu + ((u >> 16) & 1u)) >> 16;
  return (unsigned short)r;
}

// ---------- helpers ----------
__device__ __forceinline__ float red128_sum(float v, float* tmp2, int tid) {
#pragma unroll
  for (int m = 1; m < 64; m <<= 1) v += __shfl_xor(v, m, 64);
  __syncthreads();                 // protect tmp2 reuse across calls
  if ((tid & 63) == 0) tmp2[tid >> 6] = v;
  __syncthreads();
  return tmp2[0] + tmp2[1];
}

// ---------- CSR build ----------
__global__ void k_zero(int* cnt, int* cur, float* pooled) {
  int i = blockIdx.x * blockDim.x + threadIdx.x;
  if (i < N_NODES) { cnt[i] = 0; cur[i] = 0; }
  if (i < D) pooled[i] = 0.f;
}

__global__ void k_hist(const int* __restrict__ dst, int* __restrict__ cnt) {
  for (int i = blockIdx.x * blockDim.x + threadIdx.x; i < E_EDGES; i += gridDim.x * blockDim.x)
    atomicAdd(&cnt[dst[i]], 1);
}

__global__ void k_scan(const int* __restrict__ cnt, int* __restrict__ indptr) {
  __shared__ int ps[256];
  int tid = threadIdx.x;
  const int CH = N_NODES / 256;  // 24
  int base = tid * CH;
  int loc[CH];
  int s = 0;
#pragma unroll
  for (int i = 0; i < CH; i++) { loc[i] = cnt[base + i] + 1; s += loc[i]; }  // +1 self loop
  ps[tid] = s;
  __syncthreads();
  for (int off = 1; off < 256; off <<= 1) {
    int v = (tid >= off) ? ps[tid - off] : 0;
    __syncthreads();
    ps[tid] += v;
    __syncthreads();
  }
  int run = (tid == 0) ? 0 : ps[tid - 1];
#pragma unroll
  for (int i = 0; i < CH; i++) { indptr[base + i] = run; run += loc[i]; }
  if (tid == 255) indptr[N_NODES] = run;
}

__global__ void k_scatter(const int* __restrict__ src, const int* __restrict__ dst,
                          const int* __restrict__ indptr, int* __restrict__ cur,
                          int* __restrict__ sorted) {
  for (int i = blockIdx.x * blockDim.x + threadIdx.x; i < E_TOT; i += gridDim.x * blockDim.x) {
    if (i < E_EDGES) {
      int d = dst[i];
      int p = atomicAdd(&cur[d], 1);
      sorted[indptr[d] + p] = src[i];
    } else {
      int n = i - E_EDGES;
      int p = atomicAdd(&cur[n], 1);
      sorted[indptr[n] + p] = n;
    }
  }
}

// ---------- embedding ----------
__global__ __launch_bounds__(128) void k_embed(const float* __restrict__ nf,
                                               const float* __restrict__ W,
                                               const float* __restrict__ b,
                                               const float* __restrict__ g,
                                               const float* __restrict__ bb,
                                               float* __restrict__ x) {
  int n = blockIdx.x, j = threadIdx.x;
  __shared__ float f[F_IN];
  __shared__ float tmp2[2];
  if (j < F_IN) f[j] = nf[n * F_IN + j];
  __syncthreads();
  float acc = b[j];
#pragma unroll
  for (int k = 0; k < F_IN; k++) acc += f[k] * W[k * D + j];
  float s1 = red128_sum(acc, tmp2, j);
  float s2 = red128_sum(acc * acc, tmp2, j);
  float mean = s1 * (1.f / D);
  float var = s2 * (1.f / D) - mean * mean;
  float y = (acc - mean) * rsqrtf(var + 1e-5f) * g[j] + bb[j];
  x[n * D + j] = fmaxf(y, 0.f);
}

// ---------- GAT: h = x@W, a_s, a_d ----------
__global__ __launch_bounds__(128) void k_gat_gemm(const float* __restrict__ x,
                                                  const float* __restrict__ W,
                                                  const float* __restrict__ asrc,
                                                  const float* __restrict__ adst,
                                                  float* __restrict__ h,
                                                  float* __restrict__ a_s,
                                                  float* __restrict__ a_d) {
  int tid = threadIdx.x;
  int r0 = blockIdx.x * 8;
  __shared__ float xs[8][D];
#pragma unroll
  for (int r = 0; r < 8; r++) xs[r][tid] = x[(r0 + r) * D + tid];
  __syncthreads();
  float acc[8];
#pragma unroll
  for (int r = 0; r < 8; r++) acc[r] = 0.f;
  for (int k = 0; k < D; k++) {
    float w = W[k * D + tid];
#pragma unroll
    for (int r = 0; r < 8; r++) acc[r] += xs[r][k] * w;
  }
  float av = asrc[tid], dv = adst[tid];
  int head = tid >> 5;
#pragma unroll
  for (int r = 0; r < 8; r++) {
    h[(r0 + r) * D + tid] = acc[r];
    float p = acc[r] * av;
    float q = acc[r] * dv;
#pragma unroll
    for (int m = 1; m < 32; m <<= 1) { p += __shfl_xor(p, m, 64); q += __shfl_xor(q, m, 64); }
    if ((tid & 31) == 0) {
      a_s[(r0 + r) * H + head] = p;
      a_d[(r0 + r) * H + head] = q;
    }
  }
}

__device__ __forceinline__ float leaky(float v) { return v > 0.f ? v : 0.2f * v; }

// ---------- GAT aggregation + residual + LN (block per dst node) ----------
__global__ __launch_bounds__(128) void k_gat_agg(const float* __restrict__ h,
                                                 const float* __restrict__ a_s,
                                                 const float* __restrict__ a_d,
                                                 const int* __restrict__ indptr,
                                                 const int* __restrict__ sorted,
                                                 const float* __restrict__ gb,
                                                 const float* __restrict__ g,
                                                 const float* __restrict__ bb,
                                                 float* __restrict__ x) {
  int n = blockIdx.x, tid = threadIdx.x;
  int beg = indptr[n], end = indptr[n + 1];
  __shared__ float mxs[H], inv[H];
  __shared__ float rtmp[8];
  __shared__ int s_src[128];
  __shared__ float s_alpha[128 * 4];
  __shared__ float tmp2[2];
  float4 ad = *(const float4*)&a_d[n * H];

  // phase 1: per-head max
  float mx0 = -1e30f, mx1 = -1e30f, mx2 = -1e30f, mx3 = -1e30f;
  for (int e = beg + tid; e < end; e += 128) {
    int s = sorted[e];
    float4 as = *(const float4*)&a_s[s * H];
    mx0 = fmaxf(mx0, leaky(as.x + ad.x));
    mx1 = fmaxf(mx1, leaky(as.y + ad.y));
    mx2 = fmaxf(mx2, leaky(as.z + ad.z));
    mx3 = fmaxf(mx3, leaky(as.w + ad.w));
  }
#pragma unroll
  for (int m = 1; m < 64; m <<= 1) {
    mx0 = fmaxf(mx0, __shfl_xor(mx0, m, 64));
    mx1 = fmaxf(mx1, __shfl_xor(mx1, m, 64));
    mx2 = fmaxf(mx2, __shfl_xor(mx2, m, 64));
    mx3 = fmaxf(mx3, __shfl_xor(mx3, m, 64));
  }
  if ((tid & 63) == 0) {
    int w = tid >> 6;
    rtmp[w * 4 + 0] = mx0; rtmp[w * 4 + 1] = mx1; rtmp[w * 4 + 2] = mx2; rtmp[w * 4 + 3] = mx3;
  }
  __syncthreads();
  if (tid < 4) mxs[tid] = fmaxf(rtmp[tid], rtmp[4 + tid]);
  __syncthreads();

  // phase 2: denom
  float s0 = 0.f, s1 = 0.f, s2 = 0.f, s3 = 0.f;
  for (int e = beg + tid; e < end; e += 128) {
    int s = sorted[e];
    float4 as = *(const float4*)&a_s[s * H];
    s0 += __expf(leaky(as.x + ad.x) - mxs[0]);
    s1 += __expf(leaky(as.y + ad.y) - mxs[1]);
    s2 += __expf(leaky(as.z + ad.z) - mxs[2]);
    s3 += __expf(leaky(as.w + ad.w) - mxs[3]);
  }
#pragma unroll
  for (int m = 1; m < 64; m <<= 1) {
    s0 += __shfl_xor(s0, m, 64);
    s1 += __shfl_xor(s1, m, 64);
    s2 += __shfl_xor(s2, m, 64);
    s3 += __shfl_xor(s3, m, 64);
  }
  __syncthreads();  // rtmp reuse
  if ((tid & 63) == 0) {
    int w = tid >> 6;
    rtmp[w * 4 + 0] = s0; rtmp[w * 4 + 1] = s1; rtmp[w * 4 + 2] = s2; rtmp[w * 4 + 3] = s3;
  }
  __syncthreads();
  if (tid < 4) inv[tid] = 1.f / (rtmp[tid] + rtmp[4 + tid] + 1e-16f);

  // phase 3: weighted aggregation; thread = output channel
  int hd = tid >> 5;
  float acc = 0.f;
  for (int c0 = beg; c0 < end; c0 += 128) {
    __syncthreads();
    int e = c0 + tid;
    if (e < end) {
      int s = sorted[e];
      s_src[tid] = s;
      float4 as = *(const float4*)&a_s[s * H];
      s_alpha[tid * 4 + 0] = __expf(leaky(as.x + ad.x) - mxs[0]) * inv[0];
      s_alpha[tid * 4 + 1] = __expf(leaky(as.y + ad.y) - mxs[1]) * inv[1];
      s_alpha[tid * 4 + 2] = __expf(leaky(as.z + ad.z) - mxs[2]) * inv[2];
      s_alpha[tid * 4 + 3] = __expf(leaky(as.w + ad.w) - mxs[3]) * inv[3];
    }
    __syncthreads();
    int nc = min(128, end - c0);
#pragma unroll 4
    for (int i = 0; i < nc; i++) {
      float al = s_alpha[i * 4 + hd];
      acc += al * h[s_src[i] * D + tid];
    }
  }
  // epilogue: +b, relu, residual, LN
  float out = acc + gb[tid];
  float y = x[n * D + tid] + fmaxf(out, 0.f);
  float t1 = red128_sum(y, tmp2, tid);
  float t2 = red128_sum(y * y, tmp2, tid);
  float mean = t1 * (1.f / D);
  float var = t2 * (1.f / D) - mean * mean;
  x[n * D + tid] = (y - mean) * rsqrtf(var + 1e-5f) * g[tid] + bb[tid];
}

// ---------- q/k/v projections -> bf16 q (scale*log2e folded), bf16 K, bf16 V^T ----------
__global__ __launch_bounds__(128) void k_qkv(const float* __restrict__ x,
                                             const float* __restrict__ pe,
                                             const float* __restrict__ Wq,
                                             const float* __restrict__ Wk,
                                             const float* __restrict__ Wv,
                                             const float* __restrict__ bq,
                                             const float* __restrict__ bk,
                                             const float* __restrict__ bv,
                                             unsigned short* __restrict__ qbf,
                                             unsigned short* __restrict__ kbf,
                                             unsigned short* __restrict__ vtb) {
  int tid = threadIdx.x, r0 = blockIdx.x * 8;
  __shared__ float xs[8][D], ps[8][D];
#pragma unroll
  for (int r = 0; r < 8; r++) {
    xs[r][tid] = x[(r0 + r) * D + tid];
    ps[r][tid] = pe[(r0 + r) * D + tid];
  }
  __syncthreads();
  float aq[8], ak[8], av[8];
#pragma unroll
  for (int r = 0; r < 8; r++) { aq[r] = 0.f; ak[r] = 0.f; av[r] = 0.f; }
  for (int kk = 0; kk < D; kk++) {
    float wq = Wq[kk * D + tid], wk = Wk[kk * D + tid], wv = Wv[kk * D + tid];
#pragma unroll
    for (int r = 0; r < 8; r++) {
      aq[r] += xs[r][kk] * wq;
      ak[r] += ps[r][kk] * wk;
      av[r] += ps[r][kk] * wv;
    }
  }
  // 1/sqrt(32) * log2(e) folded into q -> softmax runs in exp2 domain
  const float sc = 0.25503491f;
  float bqv = bq[tid], bkv = bk[tid], bvv = bv[tid];
#pragma unroll
  for (int r = 0; r < 8; r++) {
    qbf[(r0 + r) * D + tid] = f2bf((aq[r] + bqv) * sc);
    kbf[(r0 + r) * D + tid] = f2bf(ak[r] + bkv);
  }
  // V^T: thread tid owns channel tid for rows r0..r0+7 -> one 16B store
  unsigned u0 = (unsigned)f2bf(av[0] + bvv) | ((unsigned)f2bf(av[1] + bvv) << 16);
  unsigned u1 = (unsigned)f2bf(av[2] + bvv) | ((unsigned)f2bf(av[3] + bvv) << 16);
  unsigned u2 = (unsigned)f2bf(av[4] + bvv) | ((unsigned)f2bf(av[5] + bvv) << 16);
  unsigned u3 = (unsigned)f2bf(av[6] + bvv) | ((unsigned)f2bf(av[7] + bvv) << 16);
  uint4 uu = make_uint4(u0, u1, u2, u3);
  *(uint4*)(vtb + (size_t)tid * N_NODES + r0) = uu;
}

// ---------- flash attention, bf16 MFMA, K-split ----------
#define MFMA16(A, B, CIN) __builtin_amdgcn_mfma_f32_16x16x32_bf16(A, B, CIN, 0, 0, 0)
#define REDMAX4(v) { v = fmaxf(v, __shfl_xor(v, 1)); v = fmaxf(v, __shfl_xor(v, 2)); \
                     v = fmaxf(v, __shfl_xor(v, 4)); v = fmaxf(v, __shfl_xor(v, 8)); }
#define REDSUM4(v) { v += __shfl_xor(v, 1); v += __shfl_xor(v, 2); \
                     v += __shfl_xor(v, 4); v += __shfl_xor(v, 8); }

// store one softmax row-register (4 key-blocks) to swizzled P_lds
#define PSTORE(RR, a0, a1, a2, a3) do { \
  int row_ = lg * 4 + (RR); \
  int xr_ = (row_ & 7) << 4; \
  char* rp_ = pb + row_ * 128 + ((lr * 2) ^ (xr_ & 0x10)); \
  int bx_ = xr_ & 0x60; \
  *(unsigned short*)(rp_ + (0 ^ bx_))  = f2bf(a0); \
  *(unsigned short*)(rp_ + (32 ^ bx_)) = f2bf(a1); \
  *(unsigned short*)(rp_ + (64 ^ bx_)) = f2bf(a2); \
  *(unsigned short*)(rp_ + (96 ^ bx_)) = f2bf(a3); \
} while (0)

#define ATTN_TILE(K0, K1, K2, K3, V0, V1, V2, V3) do { \
  f32x4 zz = {0.f, 0.f, 0.f, 0.f}; \
  f32x4 s0 = MFMA16(aq, K0, zz); \
  f32x4 s1 = MFMA16(aq, K1, zz); \
  f32x4 s2 = MFMA16(aq, K2, zz); \
  f32x4 s3 = MFMA16(aq, K3, zz); \
  float x0 = fmaxf(fmaxf(s0[0], s1[0]), fmaxf(s2[0], s3[0])); \
  float x1 = fmaxf(fmaxf(s0[1], s1[1]), fmaxf(s2[1], s3[1])); \
  float x2 = fmaxf(fmaxf(s0[2], s1[2]), fmaxf(s2[2], s3[2])); \
  float x3 = fmaxf(fmaxf(s0[3], s1[3]), fmaxf(s2[3], s3[3])); \
  REDMAX4(x0); REDMAX4(x1); REDMAX4(x2); REDMAX4(x3); \
  float n0 = fmaxf(m0, x0), n1 = fmaxf(m1, x1), n2 = fmaxf(m2, x2), n3 = fmaxf(m3, x3); \
  float c0_ = exp2f(m0 - n0), c1_ = exp2f(m1 - n1), c2_ = exp2f(m2 - n2), c3_ = exp2f(m3 - n3); \
  m0 = n0; m1 = n1; m2 = n2; m3 = n3; \
  float q00 = exp2f(s0[0] - n0), q01 = exp2f(s1[0] - n0), q02 = exp2f(s2[0] - n0), q03 = exp2f(s3[0] - n0); \
  float q10 = exp2f(s0[1] - n1), q11 = exp2f(s1[1] - n1), q12 = exp2f(s2[1] - n1), q13 = exp2f(s3[1] - n1); \
  float q20 = exp2f(s0[2] - n2), q21 = exp2f(s1[2] - n2), q22 = exp2f(s2[2] - n2), q23 = exp2f(s3[2] - n2); \
  float q30 = exp2f(s0[3] - n3), q31 = exp2f(s1[3] - n3), q32 = exp2f(s2[3] - n3), q33 = exp2f(s3[3] - n3); \
  float t0_ = q00 + q01 + q02 + q03, t1_ = q10 + q11 + q12 + q13; \
  float t2_ = q20 + q21 + q22 + q23, t3_ = q30 + q31 + q32 + q33; \
  REDSUM4(t0_); REDSUM4(t1_); REDSUM4(t2_); REDSUM4(t3_); \
  l0 = l0 * c0_ + t0_; l1 = l1 * c1_ + t1_; l2 = l2 * c2_ + t2_; l3 = l3 * c3_ + t3_; \
  PSTORE(0, q00, q01, q02, q03); \
  PSTORE(1, q10, q11, q12, q13); \
  PSTORE(2, q20, q21, q22, q23); \
  PSTORE(3, q30, q31, q32, q33); \
  o0[0] *= c0_; o0[1] *= c1_; o0[2] *= c2_; o0[3] *= c3_; \
  o1[0] *= c0_; o1[1] *= c1_; o1[2] *= c2_; o1[3] *= c3_; \
  bf16x8 pa0 = *(const bf16x8*)(pb + pr0); \
  bf16x8 pa1 = *(const bf16x8*)(pb + pr1); \
  o0 = MFMA16(pa0, V0, o0); \
  o1 = MFMA16(pa0, V1, o1); \
  o0 = MFMA16(pa1, V2, o0); \
  o1 = MFMA16(pa1, V3, o1); \
} while (0)

#define LOADKV(K0, K1, K2, K3, V0, V1, V2, V3, KT0) do { \
  const unsigned short* kp_ = kB + (size_t)(KT0) * D; \
  K0 = *(const bf16x8*)(kp_); \
  K1 = *(const bf16x8*)(kp_ + 16 * D); \
  K2 = *(const bf16x8*)(kp_ + 32 * D); \
  K3 = *(const bf16x8*)(kp_ + 48 * D); \
  V0 = *(const bf16x8*)(vB0 + (KT0)); \
  V1 = *(const bf16x8*)(vB1 + (KT0)); \
  V2 = *(const bf16x8*)(vB0 + (KT0) + 32); \
  V3 = *(const bf16x8*)(vB1 + (KT0) + 32); \
} while (0)

__global__ __launch_bounds__(128) void k_attn_split(const unsigned short* __restrict__ qbf,
                                                    const unsigned short* __restrict__ kbf,
                                                    const unsigned short* __restrict__ vtb,
                                                    float* __restrict__ po,
                                                    float* __restrict__ pm,
                                                    float* __restrict__ pl) {
  int hh = blockIdx.y;
  int sp = blockIdx.z;
  int q0 = blockIdx.x * 32;
  int t = threadIdx.x;
  int wv = t >> 6, l = t & 63, lr = l & 15, lg = l >> 4;
  __shared__ unsigned short P_lds[2][16][64];
  char* pb = (char*)(&P_lds[wv][0][0]);

  bf16x8 aq = *(const bf16x8*)(qbf + (size_t)(q0 + wv * 16 + lr) * D + hh * 32 + lg * 8);
  const unsigned short* kB = kbf + (size_t)(sp * KV_PER + lr) * D + hh * 32 + lg * 8;
  const unsigned short* vB0 = vtb + (size_t)(hh * 32 + lr) * N_NODES + sp * KV_PER + lg * 8;
  const unsigned short* vB1 = vB0 + 16 * N_NODES;
  int xr2 = (lr & 7) << 4;
  int pr0 = lr * 128 + ((lg * 16) ^ xr2);
  int pr1 = lr * 128 + ((64 + lg * 16) ^ xr2);

  f32x4 o0 = {0.f, 0.f, 0.f, 0.f}, o1 = {0.f, 0.f, 0.f, 0.f};
  float m0 = -3e38f, m1 = -3e38f, m2 = -3e38f, m3 = -3e38f;
  float l0 = 0.f, l1 = 0.f, l2 = 0.f, l3 = 0.f;

  bf16x8 ka0, ka1, ka2, ka3, va0, va1, va2, va3;
  bf16x8 kb0, kb1, kb2, kb3, vb0, vb1, vb2, vb3;
  LOADKV(ka0, ka1, ka2, ka3, va0, va1, va2, va3, 0);
  const int NT = KV_PER / 64;  // 24 tiles
  for (int it = 0; it < NT; it += 2) {
    LOADKV(kb0, kb1, kb2, kb3, vb0, vb1, vb2, vb3, (it + 1) * 64);
    ATTN_TILE(ka0, ka1, ka2, ka3, va0, va1, va2, va3);
    if (it + 2 < NT) LOADKV(ka0, ka1, ka2, ka3, va0, va1, va2, va3, (it + 2) * 64);
    ATTN_TILE(kb0, kb1, kb2, kb3, vb0, vb1, vb2, vb3);
  }

  // write unnormalized partials: o (32 ch), m, l  (log2-domain m)
  size_t pbase = (size_t)(sp * H + hh) * N_NODES + (q0 + wv * 16);
  float* pop = po + (pbase + lg * 4) * 32 + lr;
#pragma unroll
  for (int r = 0; r < 4; r++) {
    pop[r * 32]      = o0[r];
    pop[r * 32 + 16] = o1[r];
  }
  if (lr == 0) {
    float* pmp = pm + pbase + lg * 4;
    float* plp = pl + pbase + lg * 4;
    pmp[0] = m0; pmp[1] = m1; pmp[2] = m2; pmp[3] = m3;
    plp[0] = l0; plp[1] = l1; plp[2] = l2; plp[3] = l3;
  }
}

__global__ __launch_bounds__(256) void k_attn_combine(const float* __restrict__ po,
                                                      const float* __restrict__ pm,
                                                      const float* __restrict__ pl,
                                                      float* __restrict__ xa) {
  int t = blockIdx.x * 256 + threadIdx.x;  // N*128 total
  int q = t >> 7, hc = t & 127, hh = hc >> 5, c = hc & 31;
  int base = hh * N_NODES + q;
  const int SN = H * N_NODES;
  float m0 = pm[base], m1 = pm[SN + base], m2 = pm[2 * SN + base], m3 = pm[3 * SN + base];
  float mm = fmaxf(fmaxf(m0, m1), fmaxf(m2, m3));
  float w0 = exp2f(m0 - mm), w1 = exp2f(m1 - mm), w2 = exp2f(m2 - mm), w3 = exp2f(m3 - mm);
  float ll = w0 * pl[base] + w1 * pl[SN + base] + w2 * pl[2 * SN + base] + w3 * pl[3 * SN + base];
  size_t ob = (size_t)base * 32 + c;
  size_t st = (size_t)SN * 32;
  float o = w0 * po[ob] + w1 * po[st + ob] + w2 * po[2 * st + ob] + w3 * po[3 * st + ob];
  xa[(size_t)q * D + hh * 32 + c] = o / ll;
}

// ---------- Wo + residual + LN + pooled partial ----------
__global__ __launch_bounds__(128) void k_ca(const float* __restrict__ xa,
                                            const float* __restrict__ Wo,
                                            const float* __restrict__ bo,
                                            const float* __restrict__ g,
                                            const float* __restrict__ bb,
                                            float* __restrict__ x, float* __restrict__ pooled,
                                            float* __restrict__ outx) {
  int tid = threadIdx.x, r0 = blockIdx.x * 8;
  __shared__ float xs[8][D];
  __shared__ float tmp2[2];
#pragma unroll
  for (int r = 0; r < 8; r++) xs[r][tid] = xa[(r0 + r) * D + tid];
  __syncthreads();
  float acc[8];
#pragma unroll
  for (int r = 0; r < 8; r++) acc[r] = bo[tid];
  for (int kk = 0; kk < D; kk++) {
    float w = Wo[kk * D + tid];
#pragma unroll
    for (int r = 0; r < 8; r++) acc[r] += xs[r][kk] * w;
  }
  float gv = g[tid], bv = bb[tid];
  float psum = 0.f;
#pragma unroll
  for (int r = 0; r < 8; r++) {
    float y = x[(r0 + r) * D + tid] + acc[r];
    float t1 = red128_sum(y, tmp2, tid);
    float t2 = red128_sum(y * y, tmp2, tid);
    float mean = t1 * (1.f / D);
    float var = t2 * (1.f / D) - mean * mean;
    float o = (y - mean) * rsqrtf(var + 1e-5f) * gv + bv;
    x[(r0 + r) * D + tid] = o;
    outx[(r0 + r) * D + tid] = o;
    psum += o;
  }
  atomicAdd(&pooled[tid], psum);
}

// ---------- policy head (block per query node) ----------
__global__ __launch_bounds__(128) void k_policy(const float* __restrict__ x,
                                                const float* __restrict__ W1,
                                                const float* __restrict__ b1,
                                                const float* __restrict__ W2,
                                                const float* __restrict__ b2,
                                                const float* __restrict__ W3,
                                                const float* __restrict__ b3,
                                                float* __restrict__ logits) {
  int n = blockIdx.x, tid = threadIdx.x;
  __shared__ float xs[D], h1[D], h2[64];
  xs[tid] = x[n * D + tid];
  __syncthreads();
  float a = b1[tid];
  for (int kk = 0; kk < D; kk++) a += xs[kk] * W1[kk * D + tid];
  h1[tid] = fmaxf(a, 0.f);
  __syncthreads();
  if (tid < 64) {
    float a2 = b2[tid];
    for (int kk = 0; kk < D; kk++) a2 += h1[kk] * W2[kk * 64 + tid];
    h2[tid] = fmaxf(a2, 0.f);
  }
  __syncthreads();
  float p0 = 0.f, p1 = 0.f;
  if (tid < 64) { p0 = h2[tid] * W3[tid * 2]; p1 = h2[tid] * W3[tid * 2 + 1]; }
#pragma unroll
  for (int m = 1; m < 64; m <<= 1) { p0 += __shfl_xor(p0, m, 64); p1 += __shfl_xor(p1, m, 64); }
  if (tid == 0) {
    logits[n * 2] = p0 + b3[0];
    logits[n * 2 + 1] = p1 + b3[1];
  }
}

// ---------- value head (single block) ----------
__global__ __launch_bounds__(128) void k_value(const float* __restrict__ pooled,
                                               const float* __restrict__ W1,
                                               const float* __restrict__ b1,
                                               const float* __restrict__ W2,
                                               const float* __restrict__ b2,
                                               const float* __restrict__ W3,
                                               const float* __restrict__ b3,
                                               float* __restrict__ val) {
  int tid = threadIdx.x;
  __shared__ float ps[D], v1[D], v2[64];
  ps[tid] = pooled[tid] * (1.f / N_NODES);
  __syncthreads();
  float a = b1[tid];
  for (int kk = 0; kk < D; kk++) a += ps[kk] * W1[kk * D + tid];
  v1[tid] = fmaxf(a, 0.f);
  __syncthreads();
  if (tid < 64) {
    float a2 = b2[tid];
    for (int kk = 0; kk < D; kk++) a2 += v1[kk] * W2[kk * 64 + tid];
    v2[tid] = fmaxf(a2, 0.f);
  }
  __syncthreads();
  float p = (tid < 64) ? v2[tid] * W3[tid] : 0.f;
#pragma unroll
  for (int m = 1; m < 64; m <<= 1) p += __shfl_xor(p, m, 64);
  if (tid == 0) val[0] = p + b3[0];
}

extern "C" void kernel_launch(void* const* d_in, const int* in_sizes, int n_in,
                              void* d_out, int out_size, void* d_ws, size_t ws_size,
                              hipStream_t stream) {
  const float* nf   = (const float*)d_in[0];
  const int*   ei   = (const int*)d_in[1];
  const float* pe   = (const float*)d_in[2];
  const float* embW = (const float*)d_in[3];
  const float* embB = (const float*)d_in[4];
  const float* elng = (const float*)d_in[5];
  const float* elnb = (const float*)d_in[6];
  const float* gatW = (const float*)d_in[7];
  const float* aS   = (const float*)d_in[8];
  const float* aD   = (const float*)d_in[9];
  const float* gatB = (const float*)d_in[10];
  const float* lng  = (const float*)d_in[11];
  const float* lnb  = (const float*)d_in[12];
  const float* Wq   = (const float*)d_in[13];
  const float* Wk   = (const float*)d_in[14];
  const float* Wv   = (const float*)d_in[15];
  const float* Wo   = (const float*)d_in[16];
  const float* bq   = (const float*)d_in[17];
  const float* bk   = (const float*)d_in[18];
  const float* bv   = (const float*)d_in[19];
  const float* bo   = (const float*)d_in[20];
  const float* cag  = (const float*)d_in[21];
  const float* cab  = (const float*)d_in[22];
  const float* pW1  = (const float*)d_in[23];
  const float* pb1  = (const float*)d_in[24];
  const float* pW2  = (const float*)d_in[25];
  const float* pb2  = (const float*)d_in[26];
  const float* pW3  = (const float*)d_in[27];
  const float* pb3  = (const float*)d_in[28];
  const float* vW1  = (const float*)d_in[29];
  const float* vb1  = (const float*)d_in[30];
  const float* vW2  = (const float*)d_in[31];
  const float* vb2  = (const float*)d_in[32];
  const float* vW3  = (const float*)d_in[33];
  const float* vb3  = (const float*)d_in[34];

  // workspace layout: fp32 buffers, then bf16 buffers, then attn partials, then int CSR arrays
  float* fw = (float*)d_ws;
  float* x      = fw; fw += N_NODES * D;
  float* hbuf   = fw; fw += N_NODES * D;   // reused as xa after GAT layers
  float* a_s    = fw; fw += N_NODES * H;
  float* a_d    = fw; fw += N_NODES * H;
  float* pooled = fw; fw += 128;
  float* po     = fw; fw += (size_t)SPLITS * H * N_NODES * 32;
  float* pm     = fw; fw += SPLITS * H * N_NODES;
  float* pl     = fw; fw += SPLITS * H * N_NODES;
  unsigned short* ub = (unsigned short*)fw;
  unsigned short* qbf = ub; ub += N_NODES * D;
  unsigned short* kbf = ub; ub += N_NODES * D;
  unsigned short* vtb = ub; ub += N_NODES * D;
  int* ib     = (int*)ub;
  int* cnt    = ib; ib += N_NODES;
  int* cur    = ib; ib += N_NODES;
  int* indptr = ib; ib += N_NODES + 16;
  int* sorted = ib;

  float* out    = (float*)d_out;
  float* logits = out;
  float* val    = out + NQ_ * 2;
  float* outx   = out + NQ_ * 2 + 1;

  const int* esrc = ei;
  const int* edst = ei + E_EDGES;

  hipLaunchKernelGGL(k_zero, dim3(24), dim3(256), 0, stream, cnt, cur, pooled);
  hipLaunchKernelGGL(k_hist, dim3(512), dim3(256), 0, stream, edst, cnt);
  hipLaunchKernelGGL(k_scan, dim3(1), dim3(256), 0, stream, cnt, indptr);
  hipLaunchKernelGGL(k_scatter, dim3(512), dim3(256), 0, stream, esrc, edst, indptr, cur, sorted);
  hipLaunchKernelGGL(k_embed, dim3(N_NODES), dim3(128), 0, stream, nf, embW, embB, elng, elnb, x);
  for (int l = 0; l < L_LAYERS; l++) {
    hipLaunchKernelGGL(k_gat_gemm, dim3(N_NODES / 8), dim3(128), 0, stream,
                       x, gatW + l * D * D, aS + l * D, aD + l * D, hbuf, a_s, a_d);
    hipLaunchKernelGGL(k_gat_agg, dim3(N_NODES), dim3(128), 0, stream,
                       hbuf, a_s, a_d, indptr, sorted, gatB + l * D, lng + l * D, lnb + l * D, x);
  }
  hipLaunchKernelGGL(k_qkv, dim3(N_NODES / 8), dim3(128), 0, stream,
                     x, pe, Wq, Wk, Wv, bq, bk, bv, qbf, kbf, vtb);
  hipLaunchKernelGGL(k_attn_split, dim3(N_NODES / 32, H, SPLITS), dim3(128), 0, stream,
                     qbf, kbf, vtb, po, pm, pl);
  hipLaunchKernelGGL(k_attn_combine, dim3(N_NODES * D / 256), dim3(256), 0, stream,
                     po, pm, pl, hbuf);
  hipLaunchKernelGGL(k_ca, dim3(N_NODES / 8), dim3(128), 0, stream,
                     hbuf, Wo, bo, cag, cab, x, pooled, outx);
  hipLaunchKernelGGL(k_policy, dim3(NQ_), dim3(128), 0, stream,
                     x, pW1, pb1, pW2, pb2, pW3, pb3, logits);
  hipLaunchKernelGGL(k_value, dim3(1), dim3(128), 0, stream,
                     pooled, vW1, vb1, vW2, vb2, vW3, vb3, val);
}

// Round 5
// 387.315 us; speedup vs baseline: 1.1685x; 1.1685x over previous
//
#include <hip/hip_runtime.h>
#include <hip/hip_bf16.h>

#define N_NODES 6144
#define NQ_ 3072
#define D 128
#define H 4
#define C 32
#define F_IN 10
#define L_LAYERS 4
#define E_EDGES 393216
#define E_TOT (E_EDGES + N_NODES)
#define SPLITS 4
#define KV_PER (N_NODES / SPLITS)  // 1536 keys per split = 48 tiles of 32

typedef __attribute__((ext_vector_type(8))) short bf16x8;
typedef __attribute__((ext_vector_type(4))) float f32x4;
typedef __attribute__((ext_vector_type(16))) float f32x16;

__device__ __forceinline__ unsigned short f2bf(float f) {
  unsigned u = __float_as_uint(f);
  unsigned r = (u + 0x7fffu + ((u >> 16) & 1u)) >> 16;
  return (unsigned short)r;
}

__device__ __forceinline__ unsigned cvtpk(float lo, float hi) {
  unsigned r;
  asm volatile("v_cvt_pk_bf16_f32 %0, %1, %2" : "=v"(r) : "v"(lo), "v"(hi));
  return r;
}

// vdst-high(lanes 32-63) <-> src0-low(lanes 0-31)
#define P32SWAP(a, b) asm volatile("v_permlane32_swap_b32 %0, %1" : "+v"(a), "+v"(b))

// ---------- helpers ----------
__device__ __forceinline__ float red128_sum(float v, float* tmp2, int tid) {
#pragma unroll
  for (int m = 1; m < 64; m <<= 1) v += __shfl_xor(v, m, 64);
  __syncthreads();                 // protect tmp2 reuse across calls
  if ((tid & 63) == 0) tmp2[tid >> 6] = v;
  __syncthreads();
  return tmp2[0] + tmp2[1];
}

// ---------- CSR build ----------
__global__ void k_zero(int* cnt, int* cur, float* pooled) {
  int i = blockIdx.x * blockDim.x + threadIdx.x;
  if (i < N_NODES) { cnt[i] = 0; cur[i] = 0; }
  if (i < D) pooled[i] = 0.f;
}

__global__ void k_hist(const int* __restrict__ dst, int* __restrict__ cnt) {
  for (int i = blockIdx.x * blockDim.x + threadIdx.x; i < E_EDGES; i += gridDim.x * blockDim.x)
    atomicAdd(&cnt[dst[i]], 1);
}

__global__ void k_scan(const int* __restrict__ cnt, int* __restrict__ indptr) {
  __shared__ int ps[256];
  int tid = threadIdx.x;
  const int CH = N_NODES / 256;  // 24
  int base = tid * CH;
  int loc[CH];
  int s = 0;
#pragma unroll
  for (int i = 0; i < CH; i++) { loc[i] = cnt[base + i] + 1; s += loc[i]; }  // +1 self loop
  ps[tid] = s;
  __syncthreads();
  for (int off = 1; off < 256; off <<= 1) {
    int v = (tid >= off) ? ps[tid - off] : 0;
    __syncthreads();
    ps[tid] += v;
    __syncthreads();
  }
  int run = (tid == 0) ? 0 : ps[tid - 1];
#pragma unroll
  for (int i = 0; i < CH; i++) { indptr[base + i] = run; run += loc[i]; }
  if (tid == 255) indptr[N_NODES] = run;
}

__global__ void k_scatter(const int* __restrict__ src, const int* __restrict__ dst,
                          const int* __restrict__ indptr, int* __restrict__ cur,
                          int* __restrict__ sorted) {
  for (int i = blockIdx.x * blockDim.x + threadIdx.x; i < E_TOT; i += gridDim.x * blockDim.x) {
    if (i < E_EDGES) {
      int d = dst[i];
      int p = atomicAdd(&cur[d], 1);
      sorted[indptr[d] + p] = src[i];
    } else {
      int n = i - E_EDGES;
      int p = atomicAdd(&cur[n], 1);
      sorted[indptr[n] + p] = n;
    }
  }
}

// ---------- embedding ----------
__global__ __launch_bounds__(128) void k_embed(const float* __restrict__ nf,
                                               const float* __restrict__ W,
                                               const float* __restrict__ b,
                                               const float* __restrict__ g,
                                               const float* __restrict__ bb,
                                               float* __restrict__ x) {
  int n = blockIdx.x, j = threadIdx.x;
  __shared__ float f[F_IN];
  __shared__ float tmp2[2];
  if (j < F_IN) f[j] = nf[n * F_IN + j];
  __syncthreads();
  float acc = b[j];
#pragma unroll
  for (int k = 0; k < F_IN; k++) acc += f[k] * W[k * D + j];
  float s1 = red128_sum(acc, tmp2, j);
  float s2 = red128_sum(acc * acc, tmp2, j);
  float mean = s1 * (1.f / D);
  float var = s2 * (1.f / D) - mean * mean;
  float y = (acc - mean) * rsqrtf(var + 1e-5f) * g[j] + bb[j];
  x[n * D + j] = fmaxf(y, 0.f);
}

// ---------- GAT: h = x@W, a_s, a_d ----------
__global__ __launch_bounds__(128) void k_gat_gemm(const float* __restrict__ x,
                                                  const float* __restrict__ W,
                                                  const float* __restrict__ asrc,
                                                  const float* __restrict__ adst,
                                                  float* __restrict__ h,
                                                  float* __restrict__ a_s,
                                                  float* __restrict__ a_d) {
  int tid = threadIdx.x;
  int r0 = blockIdx.x * 8;
  __shared__ float xs[8][D];
#pragma unroll
  for (int r = 0; r < 8; r++) xs[r][tid] = x[(r0 + r) * D + tid];
  __syncthreads();
  float acc[8];
#pragma unroll
  for (int r = 0; r < 8; r++) acc[r] = 0.f;
  for (int k = 0; k < D; k++) {
    float w = W[k * D + tid];
#pragma unroll
    for (int r = 0; r < 8; r++) acc[r] += xs[r][k] * w;
  }
  float av = asrc[tid], dv = adst[tid];
  int head = tid >> 5;
#pragma unroll
  for (int r = 0; r < 8; r++) {
    h[(r0 + r) * D + tid] = acc[r];
    float p = acc[r] * av;
    float q = acc[r] * dv;
#pragma unroll
    for (int m = 1; m < 32; m <<= 1) { p += __shfl_xor(p, m, 64); q += __shfl_xor(q, m, 64); }
    if ((tid & 31) == 0) {
      a_s[(r0 + r) * H + head] = p;
      a_d[(r0 + r) * H + head] = q;
    }
  }
}

__device__ __forceinline__ float leaky(float v) { return v > 0.f ? v : 0.2f * v; }

// ---------- GAT aggregation + residual + LN (block per dst node) ----------
__global__ __launch_bounds__(128) void k_gat_agg(const float* __restrict__ h,
                                                 const float* __restrict__ a_s,
                                                 const float* __restrict__ a_d,
                                                 const int* __restrict__ indptr,
                                                 const int* __restrict__ sorted,
                                                 const float* __restrict__ gb,
                                                 const float* __restrict__ g,
                                                 const float* __restrict__ bb,
                                                 float* __restrict__ x) {
  int n = blockIdx.x, tid = threadIdx.x;
  int beg = indptr[n], end = indptr[n + 1];
  __shared__ float mxs[H], inv[H];
  __shared__ float rtmp[8];
  __shared__ int s_src[128];
  __shared__ float s_alpha[128 * 4];
  __shared__ float tmp2[2];
  float4 ad = *(const float4*)&a_d[n * H];

  // phase 1: per-head max
  float mx0 = -1e30f, mx1 = -1e30f, mx2 = -1e30f, mx3 = -1e30f;
  for (int e = beg + tid; e < end; e += 128) {
    int s = sorted[e];
    float4 as = *(const float4*)&a_s[s * H];
    mx0 = fmaxf(mx0, leaky(as.x + ad.x));
    mx1 = fmaxf(mx1, leaky(as.y + ad.y));
    mx2 = fmaxf(mx2, leaky(as.z + ad.z));
    mx3 = fmaxf(mx3, leaky(as.w + ad.w));
  }
#pragma unroll
  for (int m = 1; m < 64; m <<= 1) {
    mx0 = fmaxf(mx0, __shfl_xor(mx0, m, 64));
    mx1 = fmaxf(mx1, __shfl_xor(mx1, m, 64));
    mx2 = fmaxf(mx2, __shfl_xor(mx2, m, 64));
    mx3 = fmaxf(mx3, __shfl_xor(mx3, m, 64));
  }
  if ((tid & 63) == 0) {
    int w = tid >> 6;
    rtmp[w * 4 + 0] = mx0; rtmp[w * 4 + 1] = mx1; rtmp[w * 4 + 2] = mx2; rtmp[w * 4 + 3] = mx3;
  }
  __syncthreads();
  if (tid < 4) mxs[tid] = fmaxf(rtmp[tid], rtmp[4 + tid]);
  __syncthreads();

  // phase 2: denom
  float s0 = 0.f, s1 = 0.f, s2 = 0.f, s3 = 0.f;
  for (int e = beg + tid; e < end; e += 128) {
    int s = sorted[e];
    float4 as = *(const float4*)&a_s[s * H];
    s0 += __expf(leaky(as.x + ad.x) - mxs[0]);
    s1 += __expf(leaky(as.y + ad.y) - mxs[1]);
    s2 += __expf(leaky(as.z + ad.z) - mxs[2]);
    s3 += __expf(leaky(as.w + ad.w) - mxs[3]);
  }
#pragma unroll
  for (int m = 1; m < 64; m <<= 1) {
    s0 += __shfl_xor(s0, m, 64);
    s1 += __shfl_xor(s1, m, 64);
    s2 += __shfl_xor(s2, m, 64);
    s3 += __shfl_xor(s3, m, 64);
  }
  __syncthreads();  // rtmp reuse
  if ((tid & 63) == 0) {
    int w = tid >> 6;
    rtmp[w * 4 + 0] = s0; rtmp[w * 4 + 1] = s1; rtmp[w * 4 + 2] = s2; rtmp[w * 4 + 3] = s3;
  }
  __syncthreads();
  if (tid < 4) inv[tid] = 1.f / (rtmp[tid] + rtmp[4 + tid] + 1e-16f);

  // phase 3: weighted aggregation; thread = output channel
  int hd = tid >> 5;
  float acc = 0.f;
  for (int c0 = beg; c0 < end; c0 += 128) {
    __syncthreads();
    int e = c0 + tid;
    if (e < end) {
      int s = sorted[e];
      s_src[tid] = s;
      float4 as = *(const float4*)&a_s[s * H];
      s_alpha[tid * 4 + 0] = __expf(leaky(as.x + ad.x) - mxs[0]) * inv[0];
      s_alpha[tid * 4 + 1] = __expf(leaky(as.y + ad.y) - mxs[1]) * inv[1];
      s_alpha[tid * 4 + 2] = __expf(leaky(as.z + ad.z) - mxs[2]) * inv[2];
      s_alpha[tid * 4 + 3] = __expf(leaky(as.w + ad.w) - mxs[3]) * inv[3];
    }
    __syncthreads();
    int nc = min(128, end - c0);
#pragma unroll 4
    for (int i = 0; i < nc; i++) {
      float al = s_alpha[i * 4 + hd];
      acc += al * h[s_src[i] * D + tid];
    }
  }
  // epilogue: +b, relu, residual, LN
  float out = acc + gb[tid];
  float y = x[n * D + tid] + fmaxf(out, 0.f);
  float t1 = red128_sum(y, tmp2, tid);
  float t2 = red128_sum(y * y, tmp2, tid);
  float mean = t1 * (1.f / D);
  float var = t2 * (1.f / D) - mean * mean;
  x[n * D + tid] = (y - mean) * rsqrtf(var + 1e-5f) * g[tid] + bb[tid];
}

// ---------- q/k/v projections -> bf16 q (scale*log2e folded), bf16 K, bf16 V^T ----------
__global__ __launch_bounds__(128) void k_qkv(const float* __restrict__ x,
                                             const float* __restrict__ pe,
                                             const float* __restrict__ Wq,
                                             const float* __restrict__ Wk,
                                             const float* __restrict__ Wv,
                                             const float* __restrict__ bq,
                                             const float* __restrict__ bk,
                                             const float* __restrict__ bv,
                                             unsigned short* __restrict__ qbf,
                                             unsigned short* __restrict__ kbf,
                                             unsigned short* __restrict__ vtb) {
  int tid = threadIdx.x, r0 = blockIdx.x * 8;
  __shared__ float xs[8][D], ps[8][D];
#pragma unroll
  for (int r = 0; r < 8; r++) {
    xs[r][tid] = x[(r0 + r) * D + tid];
    ps[r][tid] = pe[(r0 + r) * D + tid];
  }
  __syncthreads();
  float aq[8], ak[8], av[8];
#pragma unroll
  for (int r = 0; r < 8; r++) { aq[r] = 0.f; ak[r] = 0.f; av[r] = 0.f; }
  for (int kk = 0; kk < D; kk++) {
    float wq = Wq[kk * D + tid], wk = Wk[kk * D + tid], wv = Wv[kk * D + tid];
#pragma unroll
    for (int r = 0; r < 8; r++) {
      aq[r] += xs[r][kk] * wq;
      ak[r] += ps[r][kk] * wk;
      av[r] += ps[r][kk] * wv;
    }
  }
  // 1/sqrt(32) * log2(e) folded into q -> softmax runs in exp2 domain
  const float sc = 0.25503491f;
  float bqv = bq[tid], bkv = bk[tid], bvv = bv[tid];
#pragma unroll
  for (int r = 0; r < 8; r++) {
    qbf[(r0 + r) * D + tid] = f2bf((aq[r] + bqv) * sc);
    kbf[(r0 + r) * D + tid] = f2bf(ak[r] + bkv);
  }
  // V^T: thread tid owns channel tid for rows r0..r0+7 -> one 16B store
  unsigned u0 = (unsigned)f2bf(av[0] + bvv) | ((unsigned)f2bf(av[1] + bvv) << 16);
  unsigned u1 = (unsigned)f2bf(av[2] + bvv) | ((unsigned)f2bf(av[3] + bvv) << 16);
  unsigned u2 = (unsigned)f2bf(av[4] + bvv) | ((unsigned)f2bf(av[5] + bvv) << 16);
  unsigned u3 = (unsigned)f2bf(av[6] + bvv) | ((unsigned)f2bf(av[7] + bvv) << 16);
  uint4 uu = make_uint4(u0, u1, u2, u3);
  *(uint4*)(vtb + (size_t)tid * N_NODES + r0) = uu;
}

// ---------- flash attention: swapped-operand 32x32 MFMA, in-register softmax ----------
#define MFMA32(A, B, CIN) __builtin_amdgcn_mfma_f32_32x32x16_bf16(A, B, CIN, 0, 0, 0)

// load K A-frags (2 chan-halves) and V^T frags (2 key-halves) for a 32-key tile
#define ALOAD(KA0, KA1, VB0_, VB1_, KT0) do { \
  const unsigned short* kp_ = kB + (size_t)(KT0) * D; \
  KA0 = *(const bf16x8*)(kp_); \
  KA1 = *(const bf16x8*)(kp_ + 16); \
  VB0_ = *(const bf16x8*)(vB + (KT0)); \
  VB1_ = *(const bf16x8*)(vB + (KT0) + 16); \
} while (0)

#define TILE32(KA0, KA1, VB0_, VB1_) do { \
  f32x16 s = MFMA32(KA0, qa0, zz16); \
  s = MFMA32(KA1, qa1, s); \
  float ta_ = fmaxf(fmaxf(s[0], s[1]), fmaxf(s[2], s[3])); \
  float tb_ = fmaxf(fmaxf(s[4], s[5]), fmaxf(s[6], s[7])); \
  float tc_ = fmaxf(fmaxf(s[8], s[9]), fmaxf(s[10], s[11])); \
  float td_ = fmaxf(fmaxf(s[12], s[13]), fmaxf(s[14], s[15])); \
  float t_ = fmaxf(fmaxf(ta_, tb_), fmaxf(tc_, td_)); \
  t_ = fmaxf(t_, __shfl_xor(t_, 32, 64)); \
  float mn_ = fmaxf(m, t_); \
  float cr_ = __builtin_amdgcn_exp2f(m - mn_); \
  m = mn_; \
  float p0 = __builtin_amdgcn_exp2f(s[0] - mn_), p1 = __builtin_amdgcn_exp2f(s[1] - mn_); \
  float p2 = __builtin_amdgcn_exp2f(s[2] - mn_), p3 = __builtin_amdgcn_exp2f(s[3] - mn_); \
  float p4 = __builtin_amdgcn_exp2f(s[4] - mn_), p5 = __builtin_amdgcn_exp2f(s[5] - mn_); \
  float p6 = __builtin_amdgcn_exp2f(s[6] - mn_), p7 = __builtin_amdgcn_exp2f(s[7] - mn_); \
  float p8 = __builtin_amdgcn_exp2f(s[8] - mn_), p9 = __builtin_amdgcn_exp2f(s[9] - mn_); \
  float pa = __builtin_amdgcn_exp2f(s[10] - mn_), pc = __builtin_amdgcn_exp2f(s[11] - mn_); \
  float pd = __builtin_amdgcn_exp2f(s[12] - mn_), pe_ = __builtin_amdgcn_exp2f(s[13] - mn_); \
  float pf = __builtin_amdgcn_exp2f(s[14] - mn_), pg = __builtin_amdgcn_exp2f(s[15] - mn_); \
  float ts_ = (((p0 + p1) + (p2 + p3)) + ((p4 + p5) + (p6 + p7))) + \
              (((p8 + p9) + (pa + pc)) + ((pd + pe_) + (pf + pg))); \
  lsum = lsum * cr_ + ts_; \
  o *= cr_; \
  unsigned x0_ = cvtpk(p0, p1), x1_ = cvtpk(p2, p3); \
  unsigned y0_ = cvtpk(p4, p5), y1_ = cvtpk(p6, p7); \
  P32SWAP(x0_, y0_); P32SWAP(x1_, y1_); \
  unsigned x2_ = cvtpk(p8, p9), x3_ = cvtpk(pa, pc); \
  unsigned y2_ = cvtpk(pd, pe_), y3_ = cvtpk(pf, pg); \
  P32SWAP(x2_, y2_); P32SWAP(x3_, y3_); \
  union { unsigned u[4]; bf16x8 v; } fa_, fb_; \
  fa_.u[0] = x0_; fa_.u[1] = x1_; fa_.u[2] = y0_; fa_.u[3] = y1_; \
  fb_.u[0] = x2_; fb_.u[1] = x3_; fb_.u[2] = y2_; fb_.u[3] = y3_; \
  o = MFMA32(VB0_, fa_.v, o); \
  o = MFMA32(VB1_, fb_.v, o); \
} while (0)

__global__ __launch_bounds__(256) void k_attn_split(const unsigned short* __restrict__ qbf,
                                                    const unsigned short* __restrict__ kbf,
                                                    const unsigned short* __restrict__ vtb,
                                                    float* __restrict__ po,
                                                    float* __restrict__ pm,
                                                    float* __restrict__ pl) {
  int hh = blockIdx.y;
  int sp = blockIdx.z;
  int t = threadIdx.x;
  int wid = t >> 6, l = t & 63;
  int qc = l & 31, hi = l >> 5;
  int q0w = blockIdx.x * 128 + wid * 32;

  const f32x16 zz16 = {0.f};

  // Q^T B-frags (loop-invariant): lane l -> Q[q0w+qc][hh*32 + hi*8 + (0|16) + j]
  const unsigned short* qp = qbf + (size_t)(q0w + qc) * D + hh * 32 + hi * 8;
  bf16x8 qa0 = *(const bf16x8*)(qp);
  bf16x8 qa1 = *(const bf16x8*)(qp + 16);

  // K A-frag base: lane l -> K[key base + qc][chans hi*8(+16)]
  const unsigned short* kB = kbf + (size_t)(sp * KV_PER + qc) * D + hh * 32 + hi * 8;
  // V^T A-frag base: lane l -> V^T[chan hh*32+qc][sp*KV_PER + hi*8 + key]
  const unsigned short* vB = vtb + (size_t)(hh * 32 + qc) * N_NODES + sp * KV_PER + hi * 8;

  f32x16 o = {0.f};
  float m = -3e38f, lsum = 0.f;

  bf16x8 ka0, ka1, va0, va1, kb0r, kb1r, vb0r, vb1r;
  ALOAD(ka0, ka1, va0, va1, 0);
  const int NT = KV_PER / 32;  // 48 tiles
  for (int it = 0; it < NT; it += 2) {
    ALOAD(kb0r, kb1r, vb0r, vb1r, (it + 1) * 32);
    TILE32(ka0, ka1, va0, va1);
    if (it + 2 < NT) ALOAD(ka0, ka1, va0, va1, (it + 2) * 32);
    TILE32(kb0r, kb1r, vb0r, vb1r);
  }

  // lane l holds O^T[chan = (r&3)+8*(r>>2)+4*hi][q = qc] (unnormalized)
  float lt = lsum + __shfl_xor(lsum, 32, 64);
  size_t pbase = (size_t)(sp * H + hh) * N_NODES + q0w + qc;
  float* pop = po + pbase * 32 + 4 * hi;
  *(float4*)(pop)      = make_float4(o[0], o[1], o[2], o[3]);
  *(float4*)(pop + 8)  = make_float4(o[4], o[5], o[6], o[7]);
  *(float4*)(pop + 16) = make_float4(o[8], o[9], o[10], o[11]);
  *(float4*)(pop + 24) = make_float4(o[12], o[13], o[14], o[15]);
  if (l < 32) {
    pm[pbase] = m;
    pl[pbase] = lt;
  }
}

__global__ __launch_bounds__(256) void k_attn_combine(const float* __restrict__ po,
                                                      const float* __restrict__ pm,
                                                      const float* __restrict__ pl,
                                                      float* __restrict__ xa) {
  int t = blockIdx.x * 256 + threadIdx.x;  // N*128 total
  int q = t >> 7, hc = t & 127, hh = hc >> 5, c = hc & 31;
  int base = hh * N_NODES + q;
  const int SN = H * N_NODES;
  float m0 = pm[base], m1 = pm[SN + base], m2 = pm[2 * SN + base], m3 = pm[3 * SN + base];
  float mm = fmaxf(fmaxf(m0, m1), fmaxf(m2, m3));
  float w0 = exp2f(m0 - mm), w1 = exp2f(m1 - mm), w2 = exp2f(m2 - mm), w3 = exp2f(m3 - mm);
  float ll = w0 * pl[base] + w1 * pl[SN + base] + w2 * pl[2 * SN + base] + w3 * pl[3 * SN + base];
  size_t ob = (size_t)base * 32 + c;
  size_t st = (size_t)SN * 32;
  float o = w0 * po[ob] + w1 * po[st + ob] + w2 * po[2 * st + ob] + w3 * po[3 * st + ob];
  xa[(size_t)q * D + hh * 32 + c] = o / ll;
}

// ---------- Wo + residual + LN + pooled partial ----------
__global__ __launch_bounds__(128) void k_ca(const float* __restrict__ xa,
                                            const float* __restrict__ Wo,
                                            const float* __restrict__ bo,
                                            const float* __restrict__ g,
                                            const float* __restrict__ bb,
                                            float* __restrict__ x, float* __restrict__ pooled,
                                            float* __restrict__ outx) {
  int tid = threadIdx.x, r0 = blockIdx.x * 8;
  __shared__ float xs[8][D];
  __shared__ float tmp2[2];
#pragma unroll
  for (int r = 0; r < 8; r++) xs[r][tid] = xa[(r0 + r) * D + tid];
  __syncthreads();
  float acc[8];
#pragma unroll
  for (int r = 0; r < 8; r++) acc[r] = bo[tid];
  for (int kk = 0; kk < D; kk++) {
    float w = Wo[kk * D + tid];
#pragma unroll
    for (int r = 0; r < 8; r++) acc[r] += xs[r][kk] * w;
  }
  float gv = g[tid], bv = bb[tid];
  float psum = 0.f;
#pragma unroll
  for (int r = 0; r < 8; r++) {
    float y = x[(r0 + r) * D + tid] + acc[r];
    float t1 = red128_sum(y, tmp2, tid);
    float t2 = red128_sum(y * y, tmp2, tid);
    float mean = t1 * (1.f / D);
    float var = t2 * (1.f / D) - mean * mean;
    float o = (y - mean) * rsqrtf(var + 1e-5f) * gv + bv;
    x[(r0 + r) * D + tid] = o;
    outx[(r0 + r) * D + tid] = o;
    psum += o;
  }
  atomicAdd(&pooled[tid], psum);
}

// ---------- policy head (block per query node) ----------
__global__ __launch_bounds__(128) void k_policy(const float* __restrict__ x,
                                                const float* __restrict__ W1,
                                                const float* __restrict__ b1,
                                                const float* __restrict__ W2,
                                                const float* __restrict__ b2,
                                                const float* __restrict__ W3,
                                                const float* __restrict__ b3,
                                                float* __restrict__ logits) {
  int n = blockIdx.x, tid = threadIdx.x;
  __shared__ float xs[D], h1[D], h2[64];
  xs[tid] = x[n * D + tid];
  __syncthreads();
  float a = b1[tid];
  for (int kk = 0; kk < D; kk++) a += xs[kk] * W1[kk * D + tid];
  h1[tid] = fmaxf(a, 0.f);
  __syncthreads();
  if (tid < 64) {
    float a2 = b2[tid];
    for (int kk = 0; kk < D; kk++) a2 += h1[kk] * W2[kk * 64 + tid];
    h2[tid] = fmaxf(a2, 0.f);
  }
  __syncthreads();
  float p0 = 0.f, p1 = 0.f;
  if (tid < 64) { p0 = h2[tid] * W3[tid * 2]; p1 = h2[tid] * W3[tid * 2 + 1]; }
#pragma unroll
  for (int m = 1; m < 64; m <<= 1) { p0 += __shfl_xor(p0, m, 64); p1 += __shfl_xor(p1, m, 64); }
  if (tid == 0) {
    logits[n * 2] = p0 + b3[0];
    logits[n * 2 + 1] = p1 + b3[1];
  }
}

// ---------- value head (single block) ----------
__global__ __launch_bounds__(128) void k_value(const float* __restrict__ pooled,
                                               const float* __restrict__ W1,
                                               const float* __restrict__ b1,
                                               const float* __restrict__ W2,
                                               const float* __restrict__ b2,
                                               const float* __restrict__ W3,
                                               const float* __restrict__ b3,
                                               float* __restrict__ val) {
  int tid = threadIdx.x;
  __shared__ float ps[D], v1[D], v2[64];
  ps[tid] = pooled[tid] * (1.f / N_NODES);
  __syncthreads();
  float a = b1[tid];
  for (int kk = 0; kk < D; kk++) a += ps[kk] * W1[kk * D + tid];
  v1[tid] = fmaxf(a, 0.f);
  __syncthreads();
  if (tid < 64) {
    float a2 = b2[tid];
    for (int kk = 0; kk < D; kk++) a2 += v1[kk] * W2[kk * 64 + tid];
    v2[tid] = fmaxf(a2, 0.f);
  }
  __syncthreads();
  float p = (tid < 64) ? v2[tid] * W3[tid] : 0.f;
#pragma unroll
  for (int m = 1; m < 64; m <<= 1) p += __shfl_xor(p, m, 64);
  if (tid == 0) val[0] = p + b3[0];
}

extern "C" void kernel_launch(void* const* d_in, const int* in_sizes, int n_in,
                              void* d_out, int out_size, void* d_ws, size_t ws_size,
                              hipStream_t stream) {
  const float* nf   = (const float*)d_in[0];
  const int*   ei   = (const int*)d_in[1];
  const float* pe   = (const float*)d_in[2];
  const float* embW = (const float*)d_in[3];
  const float* embB = (const float*)d_in[4];
  const float* elng = (const float*)d_in[5];
  const float* elnb = (const float*)d_in[6];
  const float* gatW = (const float*)d_in[7];
  const float* aS   = (const float*)d_in[8];
  const float* aD   = (const float*)d_in[9];
  const float* gatB = (const float*)d_in[10];
  const float* lng  = (const float*)d_in[11];
  const float* lnb  = (const float*)d_in[12];
  const float* Wq   = (const float*)d_in[13];
  const float* Wk   = (const float*)d_in[14];
  const float* Wv   = (const float*)d_in[15];
  const float* Wo   = (const float*)d_in[16];
  const float* bq   = (const float*)d_in[17];
  const float* bk   = (const float*)d_in[18];
  const float* bv   = (const float*)d_in[19];
  const float* bo   = (const float*)d_in[20];
  const float* cag  = (const float*)d_in[21];
  const float* cab  = (const float*)d_in[22];
  const float* pW1  = (const float*)d_in[23];
  const float* pb1  = (const float*)d_in[24];
  const float* pW2  = (const float*)d_in[25];
  const float* pb2  = (const float*)d_in[26];
  const float* pW3  = (const float*)d_in[27];
  const float* pb3  = (const float*)d_in[28];
  const float* vW1  = (const float*)d_in[29];
  const float* vb1  = (const float*)d_in[30];
  const float* vW2  = (const float*)d_in[31];
  const float* vb2  = (const float*)d_in[32];
  const float* vW3  = (const float*)d_in[33];
  const float* vb3  = (const float*)d_in[34];

  // workspace layout: fp32 buffers, then bf16 buffers, then attn partials, then int CSR arrays
  float* fw = (float*)d_ws;
  float* x      = fw; fw += N_NODES * D;
  float* hbuf   = fw; fw += N_NODES * D;   // reused as xa after GAT layers
  float* a_s    = fw; fw += N_NODES * H;
  float* a_d    = fw; fw += N_NODES * H;
  float* pooled = fw; fw += 128;
  float* po     = fw; fw += (size_t)SPLITS * H * N_NODES * 32;
  float* pm     = fw; fw += SPLITS * H * N_NODES;
  float* pl     = fw; fw += SPLITS * H * N_NODES;
  unsigned short* ub = (unsigned short*)fw;
  unsigned short* qbf = ub; ub += N_NODES * D;
  unsigned short* kbf = ub; ub += N_NODES * D;
  unsigned short* vtb = ub; ub += N_NODES * D;
  int* ib     = (int*)ub;
  int* cnt    = ib; ib += N_NODES;
  int* cur    = ib; ib += N_NODES;
  int* indptr = ib; ib += N_NODES + 16;
  int* sorted = ib;

  float* out    = (float*)d_out;
  float* logits = out;
  float* val    = out + NQ_ * 2;
  float* outx   = out + NQ_ * 2 + 1;

  const int* esrc = ei;
  const int* edst = ei + E_EDGES;

  hipLaunchKernelGGL(k_zero, dim3(24), dim3(256), 0, stream, cnt, cur, pooled);
  hipLaunchKernelGGL(k_hist, dim3(512), dim3(256), 0, stream, edst, cnt);
  hipLaunchKernelGGL(k_scan, dim3(1), dim3(256), 0, stream, cnt, indptr);
  hipLaunchKernelGGL(k_scatter, dim3(512), dim3(256), 0, stream, esrc, edst, indptr, cur, sorted);
  hipLaunchKernelGGL(k_embed, dim3(N_NODES), dim3(128), 0, stream, nf, embW, embB, elng, elnb, x);
  for (int l = 0; l < L_LAYERS; l++) {
    hipLaunchKernelGGL(k_gat_gemm, dim3(N_NODES / 8), dim3(128), 0, stream,
                       x, gatW + l * D * D, aS + l * D, aD + l * D, hbuf, a_s, a_d);
    hipLaunchKernelGGL(k_gat_agg, dim3(N_NODES), dim3(128), 0, stream,
                       hbuf, a_s, a_d, indptr, sorted, gatB + l * D, lng + l * D, lnb + l * D, x);
  }
  hipLaunchKernelGGL(k_qkv, dim3(N_NODES / 8), dim3(128), 0, stream,
                     x, pe, Wq, Wk, Wv, bq, bk, bv, qbf, kbf, vtb);
  hipLaunchKernelGGL(k_attn_split, dim3(N_NODES / 128, H, SPLITS), dim3(256), 0, stream,
                     qbf, kbf, vtb, po, pm, pl);
  hipLaunchKernelGGL(k_attn_combine, dim3(N_NODES * D / 256), dim3(256), 0, stream,
                     po, pm, pl, hbuf);
  hipLaunchKernelGGL(k_ca, dim3(N_NODES / 8), dim3(128), 0, stream,
                     hbuf, Wo, bo, cag, cab, x, pooled, outx);
  hipLaunchKernelGGL(k_policy, dim3(NQ_), dim3(128), 0, stream,
                     x, pW1, pb1, pW2, pb2, pW3, pb3, logits);
  hipLaunchKernelGGL(k_value, dim3(1), dim3(128), 0, stream,
                     pooled, vW1, vb1, vW2, vb2, vW3, vb3, val);
}

// Round 6
// 363.841 us; speedup vs baseline: 1.2438x; 1.0645x over previous
//
#include <hip/hip_runtime.h>
#include <hip/hip_bf16.h>

#define N_NODES 6144
#define NQ_ 3072
#define D 128
#define H 4
#define C 32
#define F_IN 10
#define L_LAYERS 4
#define E_EDGES 393216
#define E_TOT (E_EDGES + N_NODES)
#define SPLITS 4
#define KV_PER (N_NODES / SPLITS)  // 1536 keys per split = 48 tiles of 32
#define LOG2E 1.4426950408889634f

typedef __attribute__((ext_vector_type(8))) short bf16x8;
typedef __attribute__((ext_vector_type(4))) float f32x4;
typedef __attribute__((ext_vector_type(16))) float f32x16;

__device__ __forceinline__ unsigned short f2bf(float f) {
  unsigned u = __float_as_uint(f);
  unsigned r = (u + 0x7fffu + ((u >> 16) & 1u)) >> 16;
  return (unsigned short)r;
}

__device__ __forceinline__ float bf2f(unsigned short s) {
  return __uint_as_float(((unsigned)s) << 16);
}

__device__ __forceinline__ unsigned cvtpk(float lo, float hi) {
  unsigned r;
  asm volatile("v_cvt_pk_bf16_f32 %0, %1, %2" : "=v"(r) : "v"(lo), "v"(hi));
  return r;
}

// vdst-high(lanes 32-63) <-> src0-low(lanes 0-31)
#define P32SWAP(a, b) asm volatile("v_permlane32_swap_b32 %0, %1" : "+v"(a), "+v"(b))

// ---------- helpers ----------
__device__ __forceinline__ float red128_sum(float v, float* tmp2, int tid) {
#pragma unroll
  for (int m = 1; m < 64; m <<= 1) v += __shfl_xor(v, m, 64);
  __syncthreads();                 // protect tmp2 reuse across calls
  if ((tid & 63) == 0) tmp2[tid >> 6] = v;
  __syncthreads();
  return tmp2[0] + tmp2[1];
}

// ---------- CSR build ----------
__global__ void k_zero(int* cnt, int* cur, float* pooled) {
  int i = blockIdx.x * blockDim.x + threadIdx.x;
  if (i < N_NODES) { cnt[i] = 0; cur[i] = 0; }
  if (i < D) pooled[i] = 0.f;
}

__global__ void k_hist(const int* __restrict__ dst, int* __restrict__ cnt) {
  for (int i = blockIdx.x * blockDim.x + threadIdx.x; i < E_EDGES; i += gridDim.x * blockDim.x)
    atomicAdd(&cnt[dst[i]], 1);
}

__global__ void k_scan(const int* __restrict__ cnt, int* __restrict__ indptr) {
  __shared__ int ps[256];
  int tid = threadIdx.x;
  const int CH = N_NODES / 256;  // 24
  int base = tid * CH;
  int loc[CH];
  int s = 0;
#pragma unroll
  for (int i = 0; i < CH; i++) { loc[i] = cnt[base + i] + 1; s += loc[i]; }  // +1 self loop
  ps[tid] = s;
  __syncthreads();
  for (int off = 1; off < 256; off <<= 1) {
    int v = (tid >= off) ? ps[tid - off] : 0;
    __syncthreads();
    ps[tid] += v;
    __syncthreads();
  }
  int run = (tid == 0) ? 0 : ps[tid - 1];
#pragma unroll
  for (int i = 0; i < CH; i++) { indptr[base + i] = run; run += loc[i]; }
  if (tid == 255) indptr[N_NODES] = run;
}

__global__ void k_scatter(const int* __restrict__ src, const int* __restrict__ dst,
                          const int* __restrict__ indptr, int* __restrict__ cur,
                          int* __restrict__ sorted) {
  for (int i = blockIdx.x * blockDim.x + threadIdx.x; i < E_TOT; i += gridDim.x * blockDim.x) {
    if (i < E_EDGES) {
      int d = dst[i];
      int p = atomicAdd(&cur[d], 1);
      sorted[indptr[d] + p] = src[i];
    } else {
      int n = i - E_EDGES;
      int p = atomicAdd(&cur[n], 1);
      sorted[indptr[n] + p] = n;
    }
  }
}

// ---------- embedding ----------
__global__ __launch_bounds__(128) void k_embed(const float* __restrict__ nf,
                                               const float* __restrict__ W,
                                               const float* __restrict__ b,
                                               const float* __restrict__ g,
                                               const float* __restrict__ bb,
                                               float* __restrict__ x) {
  int n = blockIdx.x, j = threadIdx.x;
  __shared__ float f[F_IN];
  __shared__ float tmp2[2];
  if (j < F_IN) f[j] = nf[n * F_IN + j];
  __syncthreads();
  float acc = b[j];
#pragma unroll
  for (int k = 0; k < F_IN; k++) acc += f[k] * W[k * D + j];
  float s1 = red128_sum(acc, tmp2, j);
  float s2 = red128_sum(acc * acc, tmp2, j);
  float mean = s1 * (1.f / D);
  float var = s2 * (1.f / D) - mean * mean;
  float y = (acc - mean) * rsqrtf(var + 1e-5f) * g[j] + bb[j];
  x[n * D + j] = fmaxf(y, 0.f);
}

// ---------- GAT: h = x@W (bf16 out), a_s, a_d (pre-scaled by log2e) ----------
__global__ __launch_bounds__(128) void k_gat_gemm(const float* __restrict__ x,
                                                  const float* __restrict__ W,
                                                  const float* __restrict__ asrc,
                                                  const float* __restrict__ adst,
                                                  unsigned short* __restrict__ hbf,
                                                  float* __restrict__ a_s,
                                                  float* __restrict__ a_d) {
  int tid = threadIdx.x;
  int r0 = blockIdx.x * 8;
  __shared__ float xs[8][D];
#pragma unroll
  for (int r = 0; r < 8; r++) xs[r][tid] = x[(r0 + r) * D + tid];
  __syncthreads();
  float acc[8];
#pragma unroll
  for (int r = 0; r < 8; r++) acc[r] = 0.f;
  for (int k = 0; k < D; k++) {
    float w = W[k * D + tid];
#pragma unroll
    for (int r = 0; r < 8; r++) acc[r] += xs[r][k] * w;
  }
  float av = asrc[tid], dv = adst[tid];
  int head = tid >> 5;
#pragma unroll
  for (int r = 0; r < 8; r++) {
    hbf[(r0 + r) * D + tid] = f2bf(acc[r]);
    float p = acc[r] * av;
    float q = acc[r] * dv;
#pragma unroll
    for (int m = 1; m < 32; m <<= 1) { p += __shfl_xor(p, m, 64); q += __shfl_xor(q, m, 64); }
    if ((tid & 31) == 0) {
      a_s[(r0 + r) * H + head] = p * LOG2E;
      a_d[(r0 + r) * H + head] = q * LOG2E;
    }
  }
}

__device__ __forceinline__ float leaky(float v) { return v > 0.f ? v : 0.2f * v; }

// ---------- GAT aggregation (single pass, no max) + residual + LN ----------
__global__ __launch_bounds__(128) void k_gat_agg(const unsigned short* __restrict__ hbf,
                                                 const float* __restrict__ a_s,
                                                 const float* __restrict__ a_d,
                                                 const int* __restrict__ indptr,
                                                 const int* __restrict__ sorted,
                                                 const float* __restrict__ gb,
                                                 const float* __restrict__ g,
                                                 const float* __restrict__ bb,
                                                 float* __restrict__ x) {
  int n = blockIdx.x, tid = threadIdx.x;
  int beg = indptr[n], end = indptr[n + 1];
  __shared__ int s_src[128];
  __shared__ float s_ex[128 * 4];
  __shared__ float tmp2[2];
  float4 ad = *(const float4*)&a_d[n * H];
  int hd = tid >> 5;
  float acc = 0.f;
  float d0 = 0.f, d1 = 0.f, d2 = 0.f, d3 = 0.f;

  for (int c0 = beg; c0 < end; c0 += 128) {
    __syncthreads();
    int e = c0 + tid;
    if (e < end) {
      int s = sorted[e];
      s_src[tid] = s;
      float4 as = *(const float4*)&a_s[s * H];
      float e0 = exp2f(leaky(as.x + ad.x));
      float e1 = exp2f(leaky(as.y + ad.y));
      float e2 = exp2f(leaky(as.z + ad.z));
      float e3 = exp2f(leaky(as.w + ad.w));
      s_ex[tid * 4 + 0] = e0;
      s_ex[tid * 4 + 1] = e1;
      s_ex[tid * 4 + 2] = e2;
      s_ex[tid * 4 + 3] = e3;
      d0 += e0; d1 += e1; d2 += e2; d3 += e3;
    }
    __syncthreads();
    int nc = min(128, end - c0);
#pragma unroll 4
    for (int i = 0; i < nc; i++) {
      acc += s_ex[i * 4 + hd] * bf2f(hbf[s_src[i] * D + tid]);
    }
  }
  // reduce per-head denominators across the block
  float t0 = red128_sum(d0, tmp2, tid);
  float t1 = red128_sum(d1, tmp2, tid);
  float t2 = red128_sum(d2, tmp2, tid);
  float t3 = red128_sum(d3, tmp2, tid);
  float dd = (hd == 0) ? t0 : (hd == 1) ? t1 : (hd == 2) ? t2 : t3;
  float out = acc * (1.f / (dd + 1e-16f)) + gb[tid];
  // epilogue: relu, residual, LN
  float y = x[n * D + tid] + fmaxf(out, 0.f);
  float s1 = red128_sum(y, tmp2, tid);
  float s2 = red128_sum(y * y, tmp2, tid);
  float mean = s1 * (1.f / D);
  float var = s2 * (1.f / D) - mean * mean;
  x[n * D + tid] = (y - mean) * rsqrtf(var + 1e-5f) * g[tid] + bb[tid];
}

// ---------- q/k/v projections -> bf16 q (scale*log2e folded), bf16 K, bf16 V^T ----------
__global__ __launch_bounds__(128) void k_qkv(const float* __restrict__ x,
                                             const float* __restrict__ pe,
                                             const float* __restrict__ Wq,
                                             const float* __restrict__ Wk,
                                             const float* __restrict__ Wv,
                                             const float* __restrict__ bq,
                                             const float* __restrict__ bk,
                                             const float* __restrict__ bv,
                                             unsigned short* __restrict__ qbf,
                                             unsigned short* __restrict__ kbf,
                                             unsigned short* __restrict__ vtb) {
  int tid = threadIdx.x, r0 = blockIdx.x * 8;
  __shared__ float xs[8][D], ps[8][D];
#pragma unroll
  for (int r = 0; r < 8; r++) {
    xs[r][tid] = x[(r0 + r) * D + tid];
    ps[r][tid] = pe[(r0 + r) * D + tid];
  }
  __syncthreads();
  float aq[8], ak[8], av[8];
#pragma unroll
  for (int r = 0; r < 8; r++) { aq[r] = 0.f; ak[r] = 0.f; av[r] = 0.f; }
  for (int kk = 0; kk < D; kk++) {
    float wq = Wq[kk * D + tid], wk = Wk[kk * D + tid], wv = Wv[kk * D + tid];
#pragma unroll
    for (int r = 0; r < 8; r++) {
      aq[r] += xs[r][kk] * wq;
      ak[r] += ps[r][kk] * wk;
      av[r] += ps[r][kk] * wv;
    }
  }
  // 1/sqrt(32) * log2(e) folded into q -> softmax runs in exp2 domain
  const float sc = 0.25503491f;
  float bqv = bq[tid], bkv = bk[tid], bvv = bv[tid];
#pragma unroll
  for (int r = 0; r < 8; r++) {
    qbf[(r0 + r) * D + tid] = f2bf((aq[r] + bqv) * sc);
    kbf[(r0 + r) * D + tid] = f2bf(ak[r] + bkv);
  }
  // V^T: thread tid owns channel tid for rows r0..r0+7 -> one 16B store
  unsigned u0 = (unsigned)f2bf(av[0] + bvv) | ((unsigned)f2bf(av[1] + bvv) << 16);
  unsigned u1 = (unsigned)f2bf(av[2] + bvv) | ((unsigned)f2bf(av[3] + bvv) << 16);
  unsigned u2 = (unsigned)f2bf(av[4] + bvv) | ((unsigned)f2bf(av[5] + bvv) << 16);
  unsigned u3 = (unsigned)f2bf(av[6] + bvv) | ((unsigned)f2bf(av[7] + bvv) << 16);
  uint4 uu = make_uint4(u0, u1, u2, u3);
  *(uint4*)(vtb + (size_t)tid * N_NODES + r0) = uu;
}

// ---------- flash attention: swapped-operand 32x32 MFMA, no-max softmax ----------
#define MFMA32(A, B, CIN) __builtin_amdgcn_mfma_f32_32x32x16_bf16(A, B, CIN, 0, 0, 0)

// load K A-frags (2 chan-halves) and V^T frags (2 key-halves) for a 32-key tile
#define ALOAD(KA0, KA1, VB0_, VB1_, KT0) do { \
  const unsigned short* kp_ = kB + (size_t)(KT0) * D; \
  KA0 = *(const bf16x8*)(kp_); \
  KA1 = *(const bf16x8*)(kp_ + 16); \
  VB0_ = *(const bf16x8*)(vB + (KT0)); \
  VB1_ = *(const bf16x8*)(vB + (KT0) + 16); \
} while (0)

#define TILE32(KA0, KA1, VB0_, VB1_) do { \
  f32x16 s = MFMA32(KA0, qa0, zz16); \
  s = MFMA32(KA1, qa1, s); \
  float p0 = __builtin_amdgcn_exp2f(s[0]), p1 = __builtin_amdgcn_exp2f(s[1]); \
  float p2 = __builtin_amdgcn_exp2f(s[2]), p3 = __builtin_amdgcn_exp2f(s[3]); \
  float p4 = __builtin_amdgcn_exp2f(s[4]), p5 = __builtin_amdgcn_exp2f(s[5]); \
  float p6 = __builtin_amdgcn_exp2f(s[6]), p7 = __builtin_amdgcn_exp2f(s[7]); \
  float p8 = __builtin_amdgcn_exp2f(s[8]), p9 = __builtin_amdgcn_exp2f(s[9]); \
  float pa = __builtin_amdgcn_exp2f(s[10]), pc = __builtin_amdgcn_exp2f(s[11]); \
  float pd = __builtin_amdgcn_exp2f(s[12]), pe_ = __builtin_amdgcn_exp2f(s[13]); \
  float pf = __builtin_amdgcn_exp2f(s[14]), pg = __builtin_amdgcn_exp2f(s[15]); \
  lsum += (((p0 + p1) + (p2 + p3)) + ((p4 + p5) + (p6 + p7))) + \
          (((p8 + p9) + (pa + pc)) + ((pd + pe_) + (pf + pg))); \
  unsigned x0_ = cvtpk(p0, p1), x1_ = cvtpk(p2, p3); \
  unsigned y0_ = cvtpk(p4, p5), y1_ = cvtpk(p6, p7); \
  P32SWAP(x0_, y0_); P32SWAP(x1_, y1_); \
  unsigned x2_ = cvtpk(p8, p9), x3_ = cvtpk(pa, pc); \
  unsigned y2_ = cvtpk(pd, pe_), y3_ = cvtpk(pf, pg); \
  P32SWAP(x2_, y2_); P32SWAP(x3_, y3_); \
  union { unsigned u[4]; bf16x8 v; } fa_, fb_; \
  fa_.u[0] = x0_; fa_.u[1] = x1_; fa_.u[2] = y0_; fa_.u[3] = y1_; \
  fb_.u[0] = x2_; fb_.u[1] = x3_; fb_.u[2] = y2_; fb_.u[3] = y3_; \
  o = MFMA32(VB0_, fa_.v, o); \
  o = MFMA32(VB1_, fb_.v, o); \
} while (0)

__global__ __launch_bounds__(256) void k_attn_split(const unsigned short* __restrict__ qbf,
                                                    const unsigned short* __restrict__ kbf,
                                                    const unsigned short* __restrict__ vtb,
                                                    float* __restrict__ po,
                                                    float* __restrict__ pl) {
  int hh = blockIdx.y;
  int sp = blockIdx.z;
  int t = threadIdx.x;
  int wid = t >> 6, l = t & 63;
  int qc = l & 31, hi = l >> 5;
  int q0w = blockIdx.x * 128 + wid * 32;

  const f32x16 zz16 = {0.f};

  // Q^T B-frags (loop-invariant): lane l -> Q[q0w+qc][hh*32 + hi*8 + (0|16) + j]
  const unsigned short* qp = qbf + (size_t)(q0w + qc) * D + hh * 32 + hi * 8;
  bf16x8 qa0 = *(const bf16x8*)(qp);
  bf16x8 qa1 = *(const bf16x8*)(qp + 16);

  // K A-frag base: lane l -> K[key base + qc][chans hi*8(+16)]
  const unsigned short* kB = kbf + (size_t)(sp * KV_PER + qc) * D + hh * 32 + hi * 8;
  // V^T A-frag base: lane l -> V^T[chan hh*32+qc][sp*KV_PER + hi*8 + key]
  const unsigned short* vB = vtb + (size_t)(hh * 32 + qc) * N_NODES + sp * KV_PER + hi * 8;

  f32x16 o = {0.f};
  float lsum = 0.f;

  bf16x8 ka0, ka1, va0, va1, kb0r, kb1r, vb0r, vb1r;
  ALOAD(ka0, ka1, va0, va1, 0);
  const int NT = KV_PER / 32;  // 48 tiles
  for (int it = 0; it < NT; it += 2) {
    ALOAD(kb0r, kb1r, vb0r, vb1r, (it + 1) * 32);
    TILE32(ka0, ka1, va0, va1);
    if (it + 2 < NT) ALOAD(ka0, ka1, va0, va1, (it + 2) * 32);
    TILE32(kb0r, kb1r, vb0r, vb1r);
  }

  // lane l holds O^T[chan = (r&3)+8*(r>>2)+4*hi][q = qc] (unnormalized)
  float lt = lsum + __shfl_xor(lsum, 32, 64);
  size_t pbase = (size_t)(sp * H + hh) * N_NODES + q0w + qc;
  float* pop = po + pbase * 32 + 4 * hi;
  *(float4*)(pop)      = make_float4(o[0], o[1], o[2], o[3]);
  *(float4*)(pop + 8)  = make_float4(o[4], o[5], o[6], o[7]);
  *(float4*)(pop + 16) = make_float4(o[8], o[9], o[10], o[11]);
  *(float4*)(pop + 24) = make_float4(o[12], o[13], o[14], o[15]);
  if (l < 32) {
    pl[pbase] = lt;
  }
}

__global__ __launch_bounds__(256) void k_attn_combine(const float* __restrict__ po,
                                                      const float* __restrict__ pl,
                                                      float* __restrict__ xa) {
  int t = blockIdx.x * 256 + threadIdx.x;  // N*128 total
  int q = t >> 7, hc = t & 127, hh = hc >> 5, c = hc & 31;
  int base = hh * N_NODES + q;
  const int SN = H * N_NODES;
  float ll = pl[base] + pl[SN + base] + pl[2 * SN + base] + pl[3 * SN + base];
  size_t ob = (size_t)base * 32 + c;
  size_t st = (size_t)SN * 32;
  float o = po[ob] + po[st + ob] + po[2 * st + ob] + po[3 * st + ob];
  xa[(size_t)q * D + hh * 32 + c] = o / ll;
}

// ---------- Wo + residual + LN + pooled partial ----------
__global__ __launch_bounds__(128) void k_ca(const float* __restrict__ xa,
                                            const float* __restrict__ Wo,
                                            const float* __restrict__ bo,
                                            const float* __restrict__ g,
                                            const float* __restrict__ bb,
                                            float* __restrict__ x, float* __restrict__ pooled,
                                            float* __restrict__ outx) {
  int tid = threadIdx.x, r0 = blockIdx.x * 8;
  __shared__ float xs[8][D];
  __shared__ float tmp2[2];
#pragma unroll
  for (int r = 0; r < 8; r++) xs[r][tid] = xa[(r0 + r) * D + tid];
  __syncthreads();
  float acc[8];
#pragma unroll
  for (int r = 0; r < 8; r++) acc[r] = bo[tid];
  for (int kk = 0; kk < D; kk++) {
    float w = Wo[kk * D + tid];
#pragma unroll
    for (int r = 0; r < 8; r++) acc[r] += xs[r][kk] * w;
  }
  float gv = g[tid], bv = bb[tid];
  float psum = 0.f;
#pragma unroll
  for (int r = 0; r < 8; r++) {
    float y = x[(r0 + r) * D + tid] + acc[r];
    float t1 = red128_sum(y, tmp2, tid);
    float t2 = red128_sum(y * y, tmp2, tid);
    float mean = t1 * (1.f / D);
    float var = t2 * (1.f / D) - mean * mean;
    float o = (y - mean) * rsqrtf(var + 1e-5f) * gv + bv;
    x[(r0 + r) * D + tid] = o;
    outx[(r0 + r) * D + tid] = o;
    psum += o;
  }
  atomicAdd(&pooled[tid], psum);
}

// ---------- policy head (block per query node) ----------
__global__ __launch_bounds__(128) void k_policy(const float* __restrict__ x,
                                                const float* __restrict__ W1,
                                                const float* __restrict__ b1,
                                                const float* __restrict__ W2,
                                                const float* __restrict__ b2,
                                                const float* __restrict__ W3,
                                                const float* __restrict__ b3,
                                                float* __restrict__ logits) {
  int n = blockIdx.x, tid = threadIdx.x;
  __shared__ float xs[D], h1[D], h2[64];
  xs[tid] = x[n * D + tid];
  __syncthreads();
  float a = b1[tid];
  for (int kk = 0; kk < D; kk++) a += xs[kk] * W1[kk * D + tid];
  h1[tid] = fmaxf(a, 0.f);
  __syncthreads();
  if (tid < 64) {
    float a2 = b2[tid];
    for (int kk = 0; kk < D; kk++) a2 += h1[kk] * W2[kk * 64 + tid];
    h2[tid] = fmaxf(a2, 0.f);
  }
  __syncthreads();
  float p0 = 0.f, p1 = 0.f;
  if (tid < 64) { p0 = h2[tid] * W3[tid * 2]; p1 = h2[tid] * W3[tid * 2 + 1]; }
#pragma unroll
  for (int m = 1; m < 64; m <<= 1) { p0 += __shfl_xor(p0, m, 64); p1 += __shfl_xor(p1, m, 64); }
  if (tid == 0) {
    logits[n * 2] = p0 + b3[0];
    logits[n * 2 + 1] = p1 + b3[1];
  }
}

// ---------- value head (single block) ----------
__global__ __launch_bounds__(128) void k_value(const float* __restrict__ pooled,
                                               const float* __restrict__ W1,
                                               const float* __restrict__ b1,
                                               const float* __restrict__ W2,
                                               const float* __restrict__ b2,
                                               const float* __restrict__ W3,
                                               const float* __restrict__ b3,
                                               float* __restrict__ val) {
  int tid = threadIdx.x;
  __shared__ float ps[D], v1[D], v2[64];
  ps[tid] = pooled[tid] * (1.f / N_NODES);
  __syncthreads();
  float a = b1[tid];
  for (int kk = 0; kk < D; kk++) a += ps[kk] * W1[kk * D + tid];
  v1[tid] = fmaxf(a, 0.f);
  __syncthreads();
  if (tid < 64) {
    float a2 = b2[tid];
    for (int kk = 0; kk < D; kk++) a2 += v1[kk] * W2[kk * 64 + tid];
    v2[tid] = fmaxf(a2, 0.f);
  }
  __syncthreads();
  float p = (tid < 64) ? v2[tid] * W3[tid] : 0.f;
#pragma unroll
  for (int m = 1; m < 64; m <<= 1) p += __shfl_xor(p, m, 64);
  if (tid == 0) val[0] = p + b3[0];
}

extern "C" void kernel_launch(void* const* d_in, const int* in_sizes, int n_in,
                              void* d_out, int out_size, void* d_ws, size_t ws_size,
                              hipStream_t stream) {
  const float* nf   = (const float*)d_in[0];
  const int*   ei   = (const int*)d_in[1];
  const float* pe   = (const float*)d_in[2];
  const float* embW = (const float*)d_in[3];
  const float* embB = (const float*)d_in[4];
  const float* elng = (const float*)d_in[5];
  const float* elnb = (const float*)d_in[6];
  const float* gatW = (const float*)d_in[7];
  const float* aS   = (const float*)d_in[8];
  const float* aD   = (const float*)d_in[9];
  const float* gatB = (const float*)d_in[10];
  const float* lng  = (const float*)d_in[11];
  const float* lnb  = (const float*)d_in[12];
  const float* Wq   = (const float*)d_in[13];
  const float* Wk   = (const float*)d_in[14];
  const float* Wv   = (const float*)d_in[15];
  const float* Wo   = (const float*)d_in[16];
  const float* bq   = (const float*)d_in[17];
  const float* bk   = (const float*)d_in[18];
  const float* bv   = (const float*)d_in[19];
  const float* bo   = (const float*)d_in[20];
  const float* cag  = (const float*)d_in[21];
  const float* cab  = (const float*)d_in[22];
  const float* pW1  = (const float*)d_in[23];
  const float* pb1  = (const float*)d_in[24];
  const float* pW2  = (const float*)d_in[25];
  const float* pb2  = (const float*)d_in[26];
  const float* pW3  = (const float*)d_in[27];
  const float* pb3  = (const float*)d_in[28];
  const float* vW1  = (const float*)d_in[29];
  const float* vb1  = (const float*)d_in[30];
  const float* vW2  = (const float*)d_in[31];
  const float* vb2  = (const float*)d_in[32];
  const float* vW3  = (const float*)d_in[33];
  const float* vb3  = (const float*)d_in[34];

  // workspace layout: fp32 buffers, then bf16 buffers, then attn partials, then int CSR arrays
  float* fw = (float*)d_ws;
  float* x      = fw; fw += N_NODES * D;
  float* hbuf   = fw; fw += N_NODES * D;   // bf16 h during GAT; fp32 xa after attention
  float* a_s    = fw; fw += N_NODES * H;
  float* a_d    = fw; fw += N_NODES * H;
  float* pooled = fw; fw += 128;
  float* po     = fw; fw += (size_t)SPLITS * H * N_NODES * 32;
  float* pl     = fw; fw += SPLITS * H * N_NODES;
  unsigned short* ub = (unsigned short*)fw;
  unsigned short* qbf = ub; ub += N_NODES * D;
  unsigned short* kbf = ub; ub += N_NODES * D;
  unsigned short* vtb = ub; ub += N_NODES * D;
  int* ib     = (int*)ub;
  int* cnt    = ib; ib += N_NODES;
  int* cur    = ib; ib += N_NODES;
  int* indptr = ib; ib += N_NODES + 16;
  int* sorted = ib;

  unsigned short* hbf = (unsigned short*)hbuf;  // bf16 alias (first half of hbuf)

  float* out    = (float*)d_out;
  float* logits = out;
  float* val    = out + NQ_ * 2;
  float* outx   = out + NQ_ * 2 + 1;

  const int* esrc = ei;
  const int* edst = ei + E_EDGES;

  hipLaunchKernelGGL(k_zero, dim3(24), dim3(256), 0, stream, cnt, cur, pooled);
  hipLaunchKernelGGL(k_hist, dim3(512), dim3(256), 0, stream, edst, cnt);
  hipLaunchKernelGGL(k_scan, dim3(1), dim3(256), 0, stream, cnt, indptr);
  hipLaunchKernelGGL(k_scatter, dim3(512), dim3(256), 0, stream, esrc, edst, indptr, cur, sorted);
  hipLaunchKernelGGL(k_embed, dim3(N_NODES), dim3(128), 0, stream, nf, embW, embB, elng, elnb, x);
  for (int l = 0; l < L_LAYERS; l++) {
    hipLaunchKernelGGL(k_gat_gemm, dim3(N_NODES / 8), dim3(128), 0, stream,
                       x, gatW + l * D * D, aS + l * D, aD + l * D, hbf, a_s, a_d);
    hipLaunchKernelGGL(k_gat_agg, dim3(N_NODES), dim3(128), 0, stream,
                       hbf, a_s, a_d, indptr, sorted, gatB + l * D, lng + l * D, lnb + l * D, x);
  }
  hipLaunchKernelGGL(k_qkv, dim3(N_NODES / 8), dim3(128), 0, stream,
                     x, pe, Wq, Wk, Wv, bq, bk, bv, qbf, kbf, vtb);
  hipLaunchKernelGGL(k_attn_split, dim3(N_NODES / 128, H, SPLITS), dim3(256), 0, stream,
                     qbf, kbf, vtb, po, pl);
  hipLaunchKernelGGL(k_attn_combine, dim3(N_NODES * D / 256), dim3(256), 0, stream,
                     po, pl, hbuf);
  hipLaunchKernelGGL(k_ca, dim3(N_NODES / 8), dim3(128), 0, stream,
                     hbuf, Wo, bo, cag, cab, x, pooled, outx);
  hipLaunchKernelGGL(k_policy, dim3(NQ_), dim3(128), 0, stream,
                     x, pW1, pb1, pW2, pb2, pW3, pb3, logits);
  hipLaunchKernelGGL(k_value, dim3(1), dim3(128), 0, stream,
                     pooled, vW1, vb1, vW2, vb2, vW3, vb3, val);
}

// Round 7
// 340.160 us; speedup vs baseline: 1.3304x; 1.0696x over previous
//
#include <hip/hip_runtime.h>
#include <hip/hip_bf16.h>

#define N_NODES 6144
#define NQ_ 3072
#define D 128
#define H 4
#define C 32
#define F_IN 10
#define L_LAYERS 4
#define E_EDGES 393216
#define E_TOT (E_EDGES + N_NODES)
#define SPLITS 8
#define KV_PER (N_NODES / SPLITS)  // 768 keys per split = 24 tiles of 32
#define LOG2E 1.4426950408889634f

typedef __attribute__((ext_vector_type(8))) short bf16x8;
typedef __attribute__((ext_vector_type(4))) float f32x4;
typedef __attribute__((ext_vector_type(16))) float f32x16;

__device__ __forceinline__ unsigned short f2bf(float f) {
  unsigned u = __float_as_uint(f);
  unsigned r = (u + 0x7fffu + ((u >> 16) & 1u)) >> 16;
  return (unsigned short)r;
}

__device__ __forceinline__ float bf2f(unsigned short s) {
  return __uint_as_float(((unsigned)s) << 16);
}

__device__ __forceinline__ unsigned cvtpk(float lo, float hi) {
  unsigned r;
  asm volatile("v_cvt_pk_bf16_f32 %0, %1, %2" : "=v"(r) : "v"(lo), "v"(hi));
  return r;
}

// vdst-high(lanes 32-63) <-> src0-low(lanes 0-31)
#define P32SWAP(a, b) asm volatile("v_permlane32_swap_b32 %0, %1" : "+v"(a), "+v"(b))

// ---------- helpers ----------
__device__ __forceinline__ float red128_sum(float v, float* tmp2, int tid) {
#pragma unroll
  for (int m = 1; m < 64; m <<= 1) v += __shfl_xor(v, m, 64);
  __syncthreads();                 // protect tmp2 reuse across calls
  if ((tid & 63) == 0) tmp2[tid >> 6] = v;
  __syncthreads();
  return tmp2[0] + tmp2[1];
}

// ---------- CSR build ----------
__global__ void k_zero(int* cnt, int* cur, float* pooled) {
  int i = blockIdx.x * blockDim.x + threadIdx.x;
  if (i < N_NODES) { cnt[i] = 0; cur[i] = 0; }
  if (i < D) pooled[i] = 0.f;
}

__global__ void k_hist(const int* __restrict__ dst, int* __restrict__ cnt) {
  for (int i = blockIdx.x * blockDim.x + threadIdx.x; i < E_EDGES; i += gridDim.x * blockDim.x)
    atomicAdd(&cnt[dst[i]], 1);
}

__global__ void k_scan(const int* __restrict__ cnt, int* __restrict__ indptr) {
  __shared__ int ps[256];
  int tid = threadIdx.x;
  const int CH = N_NODES / 256;  // 24
  int base = tid * CH;
  int loc[CH];
  int s = 0;
#pragma unroll
  for (int i = 0; i < CH; i++) { loc[i] = cnt[base + i] + 1; s += loc[i]; }  // +1 self loop
  ps[tid] = s;
  __syncthreads();
  for (int off = 1; off < 256; off <<= 1) {
    int v = (tid >= off) ? ps[tid - off] : 0;
    __syncthreads();
    ps[tid] += v;
    __syncthreads();
  }
  int run = (tid == 0) ? 0 : ps[tid - 1];
#pragma unroll
  for (int i = 0; i < CH; i++) { indptr[base + i] = run; run += loc[i]; }
  if (tid == 255) indptr[N_NODES] = run;
}

__global__ void k_scatter(const int* __restrict__ src, const int* __restrict__ dst,
                          const int* __restrict__ indptr, int* __restrict__ cur,
                          int* __restrict__ sorted) {
  for (int i = blockIdx.x * blockDim.x + threadIdx.x; i < E_TOT; i += gridDim.x * blockDim.x) {
    if (i < E_EDGES) {
      int d = dst[i];
      int p = atomicAdd(&cur[d], 1);
      sorted[indptr[d] + p] = src[i];
    } else {
      int n = i - E_EDGES;
      int p = atomicAdd(&cur[n], 1);
      sorted[indptr[n] + p] = n;
    }
  }
}

// ---------- embedding ----------
__global__ __launch_bounds__(128) void k_embed(const float* __restrict__ nf,
                                               const float* __restrict__ W,
                                               const float* __restrict__ b,
                                               const float* __restrict__ g,
                                               const float* __restrict__ bb,
                                               float* __restrict__ x,
                                               unsigned short* __restrict__ xbf) {
  int n = blockIdx.x, j = threadIdx.x;
  __shared__ float f[F_IN];
  __shared__ float tmp2[2];
  if (j < F_IN) f[j] = nf[n * F_IN + j];
  __syncthreads();
  float acc = b[j];
#pragma unroll
  for (int k = 0; k < F_IN; k++) acc += f[k] * W[k * D + j];
  float s1 = red128_sum(acc, tmp2, j);
  float s2 = red128_sum(acc * acc, tmp2, j);
  float mean = s1 * (1.f / D);
  float var = s2 * (1.f / D) - mean * mean;
  float y = (acc - mean) * rsqrtf(var + 1e-5f) * g[j] + bb[j];
  y = fmaxf(y, 0.f);
  x[n * D + j] = y;
  xbf[n * D + j] = f2bf(y);
}

// ---------- W -> W^T bf16 (all layers, one-shot) ----------
__global__ void k_wprep(const float* __restrict__ W, unsigned short* __restrict__ wt) {
  int i = blockIdx.x * 256 + threadIdx.x;  // 4*128*128 = 65536
  int l = i >> 14, rem = i & 16383, j = rem >> 7, k = rem & 127;
  wt[i] = f2bf(W[l * 16384 + k * 128 + j]);
}

#define MFMA32(A, B, CIN) __builtin_amdgcn_mfma_f32_32x32x16_bf16(A, B, CIN, 0, 0, 0)

// ---------- GAT: H = X@W via MFMA (bf16 in/out) ----------
__global__ __launch_bounds__(256) void k_gat_gemm(const unsigned short* __restrict__ xbf,
                                                  const unsigned short* __restrict__ wt,
                                                  unsigned short* __restrict__ hbf) {
  int t = threadIdx.x;
  int w = t >> 6, l = t & 63, qc = l & 31, hi = l >> 5;
  int tile = blockIdx.x * 4 + w;           // 768 tiles = (N/32)*(D/32)
  int row0 = (tile >> 2) * 32, col0 = (tile & 3) * 32;
  const unsigned short* ap = xbf + (size_t)(row0 + qc) * D + hi * 8;
  const unsigned short* bp = wt + (size_t)(col0 + qc) * D + hi * 8;
  f32x16 o = {0.f};
#pragma unroll
  for (int kk = 0; kk < 8; kk++) {
    bf16x8 a = *(const bf16x8*)(ap + kk * 16);
    bf16x8 b = *(const bf16x8*)(bp + kk * 16);
    o = MFMA32(a, b, o);
  }
  // lane holds D[row=(r&3)+8*(r>>2)+4*hi][col=qc]
#pragma unroll
  for (int r = 0; r < 16; r++) {
    int rr = (r & 3) + 8 * (r >> 2) + 4 * hi;
    hbf[(size_t)(row0 + rr) * D + col0 + qc] = f2bf(o[r]);
  }
}

// ---------- GAT: a_s, a_d from h (pre-scaled by log2e) ----------
__global__ __launch_bounds__(128) void k_gat_attn(const unsigned short* __restrict__ hbf,
                                                  const float* __restrict__ asrc,
                                                  const float* __restrict__ adst,
                                                  float* __restrict__ a_s,
                                                  float* __restrict__ a_d) {
  int t = threadIdx.x;
  int ni = t >> 4, j = t & 15;
  int n = blockIdx.x * 8 + ni;
  const unsigned short* hp = hbf + (size_t)n * D + j * 8;
  float p = 0.f, q = 0.f;
#pragma unroll
  for (int c = 0; c < 8; c++) {
    float hv = bf2f(hp[c]);
    p += hv * asrc[j * 8 + c];
    q += hv * adst[j * 8 + c];
  }
  p += __shfl_xor(p, 1); p += __shfl_xor(p, 2);
  q += __shfl_xor(q, 1); q += __shfl_xor(q, 2);
  if ((j & 3) == 0) {
    int head = j >> 2;
    a_s[n * H + head] = p * LOG2E;
    a_d[n * H + head] = q * LOG2E;
  }
}

__device__ __forceinline__ float leaky(float v) { return v > 0.f ? v : 0.2f * v; }

// ---------- GAT aggregation (single pass, no max) + residual + LN ----------
__global__ __launch_bounds__(128) void k_gat_agg(const unsigned short* __restrict__ hbf,
                                                 const float* __restrict__ a_s,
                                                 const float* __restrict__ a_d,
                                                 const int* __restrict__ indptr,
                                                 const int* __restrict__ sorted,
                                                 const float* __restrict__ gb,
                                                 const float* __restrict__ g,
                                                 const float* __restrict__ bb,
                                                 float* __restrict__ x,
                                                 unsigned short* __restrict__ xbf) {
  int n = blockIdx.x, tid = threadIdx.x;
  int beg = indptr[n], end = indptr[n + 1];
  __shared__ int s_src[128];
  __shared__ float s_ex[128 * 4];
  __shared__ float tmp2[2];
  float4 ad = *(const float4*)&a_d[n * H];
  int hd = tid >> 5;
  float acc = 0.f;
  float d0 = 0.f, d1 = 0.f, d2 = 0.f, d3 = 0.f;

  for (int c0 = beg; c0 < end; c0 += 128) {
    __syncthreads();
    int e = c0 + tid;
    if (e < end) {
      int s = sorted[e];
      s_src[tid] = s;
      float4 as = *(const float4*)&a_s[s * H];
      float e0 = exp2f(leaky(as.x + ad.x));
      float e1 = exp2f(leaky(as.y + ad.y));
      float e2 = exp2f(leaky(as.z + ad.z));
      float e3 = exp2f(leaky(as.w + ad.w));
      s_ex[tid * 4 + 0] = e0;
      s_ex[tid * 4 + 1] = e1;
      s_ex[tid * 4 + 2] = e2;
      s_ex[tid * 4 + 3] = e3;
      d0 += e0; d1 += e1; d2 += e2; d3 += e3;
    }
    __syncthreads();
    int nc = min(128, end - c0);
#pragma unroll 4
    for (int i = 0; i < nc; i++) {
      acc += s_ex[i * 4 + hd] * bf2f(hbf[s_src[i] * D + tid]);
    }
  }
  // reduce per-head denominators across the block
  float t0 = red128_sum(d0, tmp2, tid);
  float t1 = red128_sum(d1, tmp2, tid);
  float t2 = red128_sum(d2, tmp2, tid);
  float t3 = red128_sum(d3, tmp2, tid);
  float dd = (hd == 0) ? t0 : (hd == 1) ? t1 : (hd == 2) ? t2 : t3;
  float out = acc * (1.f / (dd + 1e-16f)) + gb[tid];
  // epilogue: relu, residual, LN
  float y = x[n * D + tid] + fmaxf(out, 0.f);
  float s1 = red128_sum(y, tmp2, tid);
  float s2 = red128_sum(y * y, tmp2, tid);
  float mean = s1 * (1.f / D);
  float var = s2 * (1.f / D) - mean * mean;
  float o = (y - mean) * rsqrtf(var + 1e-5f) * g[tid] + bb[tid];
  x[n * D + tid] = o;
  xbf[n * D + tid] = f2bf(o);
}

// ---------- q/k/v projections -> bf16 q (scale*log2e folded), bf16 K, bf16 V^T ----------
__global__ __launch_bounds__(128) void k_qkv(const float* __restrict__ x,
                                             const float* __restrict__ pe,
                                             const float* __restrict__ Wq,
                                             const float* __restrict__ Wk,
                                             const float* __restrict__ Wv,
                                             const float* __restrict__ bq,
                                             const float* __restrict__ bk,
                                             const float* __restrict__ bv,
                                             unsigned short* __restrict__ qbf,
                                             unsigned short* __restrict__ kbf,
                                             unsigned short* __restrict__ vtb) {
  int tid = threadIdx.x, r0 = blockIdx.x * 8;
  __shared__ float xs[8][D], ps[8][D];
#pragma unroll
  for (int r = 0; r < 8; r++) {
    xs[r][tid] = x[(r0 + r) * D + tid];
    ps[r][tid] = pe[(r0 + r) * D + tid];
  }
  __syncthreads();
  float aq[8], ak[8], av[8];
#pragma unroll
  for (int r = 0; r < 8; r++) { aq[r] = 0.f; ak[r] = 0.f; av[r] = 0.f; }
  for (int kk = 0; kk < D; kk++) {
    float wq = Wq[kk * D + tid], wk = Wk[kk * D + tid], wv = Wv[kk * D + tid];
#pragma unroll
    for (int r = 0; r < 8; r++) {
      aq[r] += xs[r][kk] * wq;
      ak[r] += ps[r][kk] * wk;
      av[r] += ps[r][kk] * wv;
    }
  }
  // 1/sqrt(32) * log2(e) folded into q -> softmax runs in exp2 domain
  const float sc = 0.25503491f;
  float bqv = bq[tid], bkv = bk[tid], bvv = bv[tid];
#pragma unroll
  for (int r = 0; r < 8; r++) {
    qbf[(r0 + r) * D + tid] = f2bf((aq[r] + bqv) * sc);
    kbf[(r0 + r) * D + tid] = f2bf(ak[r] + bkv);
  }
  // V^T: thread tid owns channel tid for rows r0..r0+7 -> one 16B store
  unsigned u0 = (unsigned)f2bf(av[0] + bvv) | ((unsigned)f2bf(av[1] + bvv) << 16);
  unsigned u1 = (unsigned)f2bf(av[2] + bvv) | ((unsigned)f2bf(av[3] + bvv) << 16);
  unsigned u2 = (unsigned)f2bf(av[4] + bvv) | ((unsigned)f2bf(av[5] + bvv) << 16);
  unsigned u3 = (unsigned)f2bf(av[6] + bvv) | ((unsigned)f2bf(av[7] + bvv) << 16);
  uint4 uu = make_uint4(u0, u1, u2, u3);
  *(uint4*)(vtb + (size_t)tid * N_NODES + r0) = uu;
}

// ---------- flash attention: swapped-operand 32x32 MFMA, no-max softmax, dual acc ----------
// load K A-frags (2 chan-halves) and V^T frags (2 key-halves) for a 32-key tile
#define ALOAD(KA0, KA1, VB0_, VB1_, KT0) do { \
  const unsigned short* kp_ = kB + (size_t)(KT0) * D; \
  KA0 = *(const bf16x8*)(kp_); \
  KA1 = *(const bf16x8*)(kp_ + 16); \
  VB0_ = *(const bf16x8*)(vB + (KT0)); \
  VB1_ = *(const bf16x8*)(vB + (KT0) + 16); \
} while (0)

#define TILE32(KA0, KA1, VB0_, VB1_, O, LS) do { \
  f32x16 s = MFMA32(KA0, qa0, zz16); \
  s = MFMA32(KA1, qa1, s); \
  float p0 = __builtin_amdgcn_exp2f(s[0]), p1 = __builtin_amdgcn_exp2f(s[1]); \
  float p2 = __builtin_amdgcn_exp2f(s[2]), p3 = __builtin_amdgcn_exp2f(s[3]); \
  float p4 = __builtin_amdgcn_exp2f(s[4]), p5 = __builtin_amdgcn_exp2f(s[5]); \
  float p6 = __builtin_amdgcn_exp2f(s[6]), p7 = __builtin_amdgcn_exp2f(s[7]); \
  float p8 = __builtin_amdgcn_exp2f(s[8]), p9 = __builtin_amdgcn_exp2f(s[9]); \
  float pa = __builtin_amdgcn_exp2f(s[10]), pc = __builtin_amdgcn_exp2f(s[11]); \
  float pd = __builtin_amdgcn_exp2f(s[12]), pe_ = __builtin_amdgcn_exp2f(s[13]); \
  float pf = __builtin_amdgcn_exp2f(s[14]), pg = __builtin_amdgcn_exp2f(s[15]); \
  LS += (((p0 + p1) + (p2 + p3)) + ((p4 + p5) + (p6 + p7))) + \
        (((p8 + p9) + (pa + pc)) + ((pd + pe_) + (pf + pg))); \
  unsigned x0_ = cvtpk(p0, p1), x1_ = cvtpk(p2, p3); \
  unsigned y0_ = cvtpk(p4, p5), y1_ = cvtpk(p6, p7); \
  P32SWAP(x0_, y0_); P32SWAP(x1_, y1_); \
  unsigned x2_ = cvtpk(p8, p9), x3_ = cvtpk(pa, pc); \
  unsigned y2_ = cvtpk(pd, pe_), y3_ = cvtpk(pf, pg); \
  P32SWAP(x2_, y2_); P32SWAP(x3_, y3_); \
  union { unsigned u[4]; bf16x8 v; } fa_, fb_; \
  fa_.u[0] = x0_; fa_.u[1] = x1_; fa_.u[2] = y0_; fa_.u[3] = y1_; \
  fb_.u[0] = x2_; fb_.u[1] = x3_; fb_.u[2] = y2_; fb_.u[3] = y3_; \
  O = MFMA32(VB0_, fa_.v, O); \
  O = MFMA32(VB1_, fb_.v, O); \
} while (0)

__global__ __launch_bounds__(256) void k_attn_split(const unsigned short* __restrict__ qbf,
                                                    const unsigned short* __restrict__ kbf,
                                                    const unsigned short* __restrict__ vtb,
                                                    unsigned short* __restrict__ po,
                                                    float* __restrict__ pl) {
  int hh = blockIdx.y;
  int sp = blockIdx.z;
  int t = threadIdx.x;
  int wid = t >> 6, l = t & 63;
  int qc = l & 31, hi = l >> 5;
  int q0w = blockIdx.x * 128 + wid * 32;

  const f32x16 zz16 = {0.f};

  // Q^T B-frags (loop-invariant): lane l -> Q[q0w+qc][hh*32 + hi*8 + (0|16) + j]
  const unsigned short* qp = qbf + (size_t)(q0w + qc) * D + hh * 32 + hi * 8;
  bf16x8 qa0 = *(const bf16x8*)(qp);
  bf16x8 qa1 = *(const bf16x8*)(qp + 16);

  // K A-frag base: lane l -> K[key base + qc][chans hi*8(+16)]
  const unsigned short* kB = kbf + (size_t)(sp * KV_PER + qc) * D + hh * 32 + hi * 8;
  // V^T A-frag base: lane l -> V^T[chan hh*32+qc][sp*KV_PER + hi*8 + key]
  const unsigned short* vB = vtb + (size_t)(hh * 32 + qc) * N_NODES + sp * KV_PER + hi * 8;

  f32x16 oA = {0.f}, oB = {0.f};
  float lsA = 0.f, lsB = 0.f;

  bf16x8 ka0, ka1, va0, va1, kb0r, kb1r, vb0r, vb1r;
  ALOAD(ka0, ka1, va0, va1, 0);
  const int NT = KV_PER / 32;  // 24 tiles
  for (int it = 0; it < NT; it += 2) {
    ALOAD(kb0r, kb1r, vb0r, vb1r, (it + 1) * 32);
    TILE32(ka0, ka1, va0, va1, oA, lsA);
    if (it + 2 < NT) ALOAD(ka0, ka1, va0, va1, (it + 2) * 32);
    TILE32(kb0r, kb1r, vb0r, vb1r, oB, lsB);
  }

  f32x16 o = oA + oB;
  float lsum = lsA + lsB;
  // lane l holds O^T[chan = (r&3)+8*(r>>2)+4*hi][q = qc] (unnormalized)
  float lt = lsum + __shfl_xor(lsum, 32, 64);
  size_t pbase = (size_t)(sp * H + hh) * N_NODES + q0w + qc;
  unsigned short* pop = po + pbase * 32 + 4 * hi;
  uint2 v0, v1, v2, v3;
  v0.x = cvtpk(o[0], o[1]);   v0.y = cvtpk(o[2], o[3]);
  v1.x = cvtpk(o[4], o[5]);   v1.y = cvtpk(o[6], o[7]);
  v2.x = cvtpk(o[8], o[9]);   v2.y = cvtpk(o[10], o[11]);
  v3.x = cvtpk(o[12], o[13]); v3.y = cvtpk(o[14], o[15]);
  *(uint2*)(pop)      = v0;
  *(uint2*)(pop + 8)  = v1;
  *(uint2*)(pop + 16) = v2;
  *(uint2*)(pop + 24) = v3;
  if (l < 32) {
    pl[pbase] = lt;
  }
}

__global__ __launch_bounds__(256) void k_attn_combine(const unsigned short* __restrict__ po,
                                                      const float* __restrict__ pl,
                                                      float* __restrict__ xa) {
  int t = blockIdx.x * 256 + threadIdx.x;  // N*D/2 threads, 2 chans each
  int q = t >> 6, cp = t & 63;
  int c2 = cp * 2, hh = c2 >> 5, c = c2 & 31;
  int base = hh * N_NODES + q;
  const int SN = H * N_NODES;
  float ll = 0.f, olo = 0.f, ohi = 0.f;
#pragma unroll
  for (int s = 0; s < SPLITS; s++) {
    ll += pl[s * SN + base];
    unsigned dw = *(const unsigned*)(po + ((size_t)(s * SN + base)) * 32 + c);
    olo += bf2f((unsigned short)(dw & 0xffff));
    ohi += bf2f((unsigned short)(dw >> 16));
  }
  float inv = 1.f / ll;
  float* op = xa + (size_t)q * D + hh * 32 + c;
  op[0] = olo * inv;
  op[1] = ohi * inv;
}

// ---------- Wo + residual + LN + pooled partial ----------
__global__ __launch_bounds__(128) void k_ca(const float* __restrict__ xa,
                                            const float* __restrict__ Wo,
                                            const float* __restrict__ bo,
                                            const float* __restrict__ g,
                                            const float* __restrict__ bb,
                                            float* __restrict__ x, float* __restrict__ pooled,
                                            float* __restrict__ outx) {
  int tid = threadIdx.x, r0 = blockIdx.x * 8;
  __shared__ float xs[8][D];
  __shared__ float tmp2[2];
#pragma unroll
  for (int r = 0; r < 8; r++) xs[r][tid] = xa[(r0 + r) * D + tid];
  __syncthreads();
  float acc[8];
#pragma unroll
  for (int r = 0; r < 8; r++) acc[r] = bo[tid];
  for (int kk = 0; kk < D; kk++) {
    float w = Wo[kk * D + tid];
#pragma unroll
    for (int r = 0; r < 8; r++) acc[r] += xs[r][kk] * w;
  }
  float gv = g[tid], bv = bb[tid];
  float psum = 0.f;
#pragma unroll
  for (int r = 0; r < 8; r++) {
    float y = x[(r0 + r) * D + tid] + acc[r];
    float t1 = red128_sum(y, tmp2, tid);
    float t2 = red128_sum(y * y, tmp2, tid);
    float mean = t1 * (1.f / D);
    float var = t2 * (1.f / D) - mean * mean;
    float o = (y - mean) * rsqrtf(var + 1e-5f) * gv + bv;
    x[(r0 + r) * D + tid] = o;
    outx[(r0 + r) * D + tid] = o;
    psum += o;
  }
  atomicAdd(&pooled[tid], psum);
}

// ---------- policy head (block per query node) ----------
__global__ __launch_bounds__(128) void k_policy(const float* __restrict__ x,
                                                const float* __restrict__ W1,
                                                const float* __restrict__ b1,
                                                const float* __restrict__ W2,
                                                const float* __restrict__ b2,
                                                const float* __restrict__ W3,
                                                const float* __restrict__ b3,
                                                float* __restrict__ logits) {
  int n = blockIdx.x, tid = threadIdx.x;
  __shared__ float xs[D], h1[D], h2[64];
  xs[tid] = x[n * D + tid];
  __syncthreads();
  float a = b1[tid];
  for (int kk = 0; kk < D; kk++) a += xs[kk] * W1[kk * D + tid];
  h1[tid] = fmaxf(a, 0.f);
  __syncthreads();
  if (tid < 64) {
    float a2 = b2[tid];
    for (int kk = 0; kk < D; kk++) a2 += h1[kk] * W2[kk * 64 + tid];
    h2[tid] = fmaxf(a2, 0.f);
  }
  __syncthreads();
  float p0 = 0.f, p1 = 0.f;
  if (tid < 64) { p0 = h2[tid] * W3[tid * 2]; p1 = h2[tid] * W3[tid * 2 + 1]; }
#pragma unroll
  for (int m = 1; m < 64; m <<= 1) { p0 += __shfl_xor(p0, m, 64); p1 += __shfl_xor(p1, m, 64); }
  if (tid == 0) {
    logits[n * 2] = p0 + b3[0];
    logits[n * 2 + 1] = p1 + b3[1];
  }
}

// ---------- value head (single block) ----------
__global__ __launch_bounds__(128) void k_value(const float* __restrict__ pooled,
                                               const float* __restrict__ W1,
                                               const float* __restrict__ b1,
                                               const float* __restrict__ W2,
                                               const float* __restrict__ b2,
                                               const float* __restrict__ W3,
                                               const float* __restrict__ b3,
                                               float* __restrict__ val) {
  int tid = threadIdx.x;
  __shared__ float ps[D], v1[D], v2[64];
  ps[tid] = pooled[tid] * (1.f / N_NODES);
  __syncthreads();
  float a = b1[tid];
  for (int kk = 0; kk < D; kk++) a += ps[kk] * W1[kk * D + tid];
  v1[tid] = fmaxf(a, 0.f);
  __syncthreads();
  if (tid < 64) {
    float a2 = b2[tid];
    for (int kk = 0; kk < D; kk++) a2 += v1[kk] * W2[kk * 64 + tid];
    v2[tid] = fmaxf(a2, 0.f);
  }
  __syncthreads();
  float p = (tid < 64) ? v2[tid] * W3[tid] : 0.f;
#pragma unroll
  for (int m = 1; m < 64; m <<= 1) p += __shfl_xor(p, m, 64);
  if (tid == 0) val[0] = p + b3[0];
}

extern "C" void kernel_launch(void* const* d_in, const int* in_sizes, int n_in,
                              void* d_out, int out_size, void* d_ws, size_t ws_size,
                              hipStream_t stream) {
  const float* nf   = (const float*)d_in[0];
  const int*   ei   = (const int*)d_in[1];
  const float* pe   = (const float*)d_in[2];
  const float* embW = (const float*)d_in[3];
  const float* embB = (const float*)d_in[4];
  const float* elng = (const float*)d_in[5];
  const float* elnb = (const float*)d_in[6];
  const float* gatW = (const float*)d_in[7];
  const float* aS   = (const float*)d_in[8];
  const float* aD   = (const float*)d_in[9];
  const float* gatB = (const float*)d_in[10];
  const float* lng  = (const float*)d_in[11];
  const float* lnb  = (const float*)d_in[12];
  const float* Wq   = (const float*)d_in[13];
  const float* Wk   = (const float*)d_in[14];
  const float* Wv   = (const float*)d_in[15];
  const float* Wo   = (const float*)d_in[16];
  const float* bq   = (const float*)d_in[17];
  const float* bk   = (const float*)d_in[18];
  const float* bv   = (const float*)d_in[19];
  const float* bo   = (const float*)d_in[20];
  const float* cag  = (const float*)d_in[21];
  const float* cab  = (const float*)d_in[22];
  const float* pW1  = (const float*)d_in[23];
  const float* pb1  = (const float*)d_in[24];
  const float* pW2  = (const float*)d_in[25];
  const float* pb2  = (const float*)d_in[26];
  const float* pW3  = (const float*)d_in[27];
  const float* pb3  = (const float*)d_in[28];
  const float* vW1  = (const float*)d_in[29];
  const float* vb1  = (const float*)d_in[30];
  const float* vW2  = (const float*)d_in[31];
  const float* vb2  = (const float*)d_in[32];
  const float* vW3  = (const float*)d_in[33];
  const float* vb3  = (const float*)d_in[34];

  // workspace layout
  float* fw = (float*)d_ws;
  float* x      = fw; fw += N_NODES * D;
  float* hbuf   = fw; fw += N_NODES * D;   // bf16 h during GAT; fp32 xa after attention
  float* a_s    = fw; fw += N_NODES * H;
  float* a_d    = fw; fw += N_NODES * H;
  float* pooled = fw; fw += 128;
  float* pl     = fw; fw += SPLITS * H * N_NODES;
  unsigned short* ub = (unsigned short*)fw;
  unsigned short* po  = ub; ub += (size_t)SPLITS * H * N_NODES * 32;
  unsigned short* qbf = ub; ub += N_NODES * D;
  unsigned short* kbf = ub; ub += N_NODES * D;
  unsigned short* vtb = ub; ub += N_NODES * D;
  unsigned short* xbf = ub; ub += N_NODES * D;
  unsigned short* wtb = ub; ub += L_LAYERS * D * D;
  int* ib     = (int*)ub;
  int* cnt    = ib; ib += N_NODES;
  int* cur    = ib; ib += N_NODES;
  int* indptr = ib; ib += N_NODES + 16;
  int* sorted = ib;

  unsigned short* hbf = (unsigned short*)hbuf;  // bf16 alias (first half of hbuf)

  float* out    = (float*)d_out;
  float* logits = out;
  float* val    = out + NQ_ * 2;
  float* outx   = out + NQ_ * 2 + 1;

  const int* esrc = ei;
  const int* edst = ei + E_EDGES;

  hipLaunchKernelGGL(k_zero, dim3(24), dim3(256), 0, stream, cnt, cur, pooled);
  hipLaunchKernelGGL(k_hist, dim3(512), dim3(256), 0, stream, edst, cnt);
  hipLaunchKernelGGL(k_scan, dim3(1), dim3(256), 0, stream, cnt, indptr);
  hipLaunchKernelGGL(k_scatter, dim3(512), dim3(256), 0, stream, esrc, edst, indptr, cur, sorted);
  hipLaunchKernelGGL(k_embed, dim3(N_NODES), dim3(128), 0, stream, nf, embW, embB, elng, elnb, x, xbf);
  hipLaunchKernelGGL(k_wprep, dim3(L_LAYERS * D * D / 256), dim3(256), 0, stream, gatW, wtb);
  for (int l = 0; l < L_LAYERS; l++) {
    hipLaunchKernelGGL(k_gat_gemm, dim3(N_NODES / 32), dim3(256), 0, stream,
                       xbf, wtb + l * D * D, hbf);
    hipLaunchKernelGGL(k_gat_attn, dim3(N_NODES / 8), dim3(128), 0, stream,
                       hbf, aS + l * D, aD + l * D, a_s, a_d);
    hipLaunchKernelGGL(k_gat_agg, dim3(N_NODES), dim3(128), 0, stream,
                       hbf, a_s, a_d, indptr, sorted, gatB + l * D, lng + l * D, lnb + l * D, x, xbf);
  }
  hipLaunchKernelGGL(k_qkv, dim3(N_NODES / 8), dim3(128), 0, stream,
                     x, pe, Wq, Wk, Wv, bq, bk, bv, qbf, kbf, vtb);
  hipLaunchKernelGGL(k_attn_split, dim3(N_NODES / 128, H, SPLITS), dim3(256), 0, stream,
                     qbf, kbf, vtb, po, pl);
  hipLaunchKernelGGL(k_attn_combine, dim3(N_NODES * D / 512), dim3(256), 0, stream,
                     po, pl, hbuf);
  hipLaunchKernelGGL(k_ca, dim3(N_NODES / 8), dim3(128), 0, stream,
                     hbuf, Wo, bo, cag, cab, x, pooled, outx);
  hipLaunchKernelGGL(k_policy, dim3(NQ_), dim3(128), 0, stream,
                     x, pW1, pb1, pW2, pb2, pW3, pb3, logits);
  hipLaunchKernelGGL(k_value, dim3(1), dim3(128), 0, stream,
                     pooled, vW1, vb1, vW2, vb2, vW3, vb3, val);
}

// Round 8
// 306.578 us; speedup vs baseline: 1.4762x; 1.1095x over previous
//
#include <hip/hip_runtime.h>
#include <hip/hip_bf16.h>

#define N_NODES 6144
#define NQ_ 3072
#define D 128
#define H 4
#define C 32
#define F_IN 10
#define L_LAYERS 4
#define E_EDGES 393216
#define E_TOT (E_EDGES + N_NODES)
#define SPLITS 8
#define KV_PER (N_NODES / SPLITS)  // 768 keys per split = 24 tiles of 32
#define NT_TOT (N_NODES / 32)      // 192 tiles total
#define LOG2E 1.4426950408889634f

typedef __attribute__((ext_vector_type(8))) short bf16x8;
typedef __attribute__((ext_vector_type(4))) float f32x4;
typedef __attribute__((ext_vector_type(16))) float f32x16;

__device__ __forceinline__ unsigned short f2bf(float f) {
  unsigned u = __float_as_uint(f);
  unsigned r = (u + 0x7fffu + ((u >> 16) & 1u)) >> 16;
  return (unsigned short)r;
}

__device__ __forceinline__ float bf2f(unsigned short s) {
  return __uint_as_float(((unsigned)s) << 16);
}

__device__ __forceinline__ unsigned cvtpk(float lo, float hi) {
  unsigned r;
  asm volatile("v_cvt_pk_bf16_f32 %0, %1, %2" : "=v"(r) : "v"(lo), "v"(hi));
  return r;
}

// vdst-high(lanes 32-63) <-> src0-low(lanes 0-31)
#define P32SWAP(a, b) asm volatile("v_permlane32_swap_b32 %0, %1" : "+v"(a), "+v"(b))

// ---------- helpers ----------
__device__ __forceinline__ float red128_sum(float v, float* tmp2, int tid) {
#pragma unroll
  for (int m = 1; m < 64; m <<= 1) v += __shfl_xor(v, m, 64);
  __syncthreads();                 // protect tmp2 reuse across calls
  if ((tid & 63) == 0) tmp2[tid >> 6] = v;
  __syncthreads();
  return tmp2[0] + tmp2[1];
}

// ---------- CSR build ----------
__global__ void k_zero(int* cnt, int* cur, float* pooled) {
  int i = blockIdx.x * blockDim.x + threadIdx.x;
  if (i < N_NODES) { cnt[i] = 0; cur[i] = 0; }
  if (i < D) pooled[i] = 0.f;
}

__global__ void k_hist(const int* __restrict__ dst, int* __restrict__ cnt) {
  for (int i = blockIdx.x * blockDim.x + threadIdx.x; i < E_EDGES; i += gridDim.x * blockDim.x)
    atomicAdd(&cnt[dst[i]], 1);
}

__global__ void k_scan(const int* __restrict__ cnt, int* __restrict__ indptr) {
  __shared__ int ps[256];
  int tid = threadIdx.x;
  const int CH = N_NODES / 256;  // 24
  int base = tid * CH;
  int loc[CH];
  int s = 0;
#pragma unroll
  for (int i = 0; i < CH; i++) { loc[i] = cnt[base + i] + 1; s += loc[i]; }  // +1 self loop
  ps[tid] = s;
  __syncthreads();
  for (int off = 1; off < 256; off <<= 1) {
    int v = (tid >= off) ? ps[tid - off] : 0;
    __syncthreads();
    ps[tid] += v;
    __syncthreads();
  }
  int run = (tid == 0) ? 0 : ps[tid - 1];
#pragma unroll
  for (int i = 0; i < CH; i++) { indptr[base + i] = run; run += loc[i]; }
  if (tid == 255) indptr[N_NODES] = run;
}

__global__ void k_scatter(const int* __restrict__ src, const int* __restrict__ dst,
                          const int* __restrict__ indptr, int* __restrict__ cur,
                          int* __restrict__ sorted) {
  for (int i = blockIdx.x * blockDim.x + threadIdx.x; i < E_TOT; i += gridDim.x * blockDim.x) {
    if (i < E_EDGES) {
      int d = dst[i];
      int p = atomicAdd(&cur[d], 1);
      sorted[indptr[d] + p] = src[i];
    } else {
      int n = i - E_EDGES;
      int p = atomicAdd(&cur[n], 1);
      sorted[indptr[n] + p] = n;
    }
  }
}

// ---------- embedding ----------
__global__ __launch_bounds__(128) void k_embed(const float* __restrict__ nf,
                                               const float* __restrict__ W,
                                               const float* __restrict__ b,
                                               const float* __restrict__ g,
                                               const float* __restrict__ bb,
                                               float* __restrict__ x,
                                               unsigned short* __restrict__ xbf) {
  int n = blockIdx.x, j = threadIdx.x;
  __shared__ float f[F_IN];
  __shared__ float tmp2[2];
  if (j < F_IN) f[j] = nf[n * F_IN + j];
  __syncthreads();
  float acc = b[j];
#pragma unroll
  for (int k = 0; k < F_IN; k++) acc += f[k] * W[k * D + j];
  float s1 = red128_sum(acc, tmp2, j);
  float s2 = red128_sum(acc * acc, tmp2, j);
  float mean = s1 * (1.f / D);
  float var = s2 * (1.f / D) - mean * mean;
  float y = (acc - mean) * rsqrtf(var + 1e-5f) * g[j] + bb[j];
  y = fmaxf(y, 0.f);
  x[n * D + j] = y;
  xbf[n * D + j] = f2bf(y);
}

// ---------- W -> W^T bf16 (all layers, one-shot) ----------
__global__ void k_wprep(const float* __restrict__ W, unsigned short* __restrict__ wt) {
  int i = blockIdx.x * 256 + threadIdx.x;  // 4*128*128 = 65536
  int l = i >> 14, rem = i & 16383, j = rem >> 7, k = rem & 127;
  wt[i] = f2bf(W[l * 16384 + k * 128 + j]);
}

#define MFMA32(A, B, CIN) __builtin_amdgcn_mfma_f32_32x32x16_bf16(A, B, CIN, 0, 0, 0)

// ---------- GAT: H = X@W via MFMA (bf16 in/out) ----------
__global__ __launch_bounds__(256) void k_gat_gemm(const unsigned short* __restrict__ xbf,
                                                  const unsigned short* __restrict__ wt,
                                                  unsigned short* __restrict__ hbf) {
  int t = threadIdx.x;
  int w = t >> 6, l = t & 63, qc = l & 31, hi = l >> 5;
  int tile = blockIdx.x * 4 + w;           // 768 tiles = (N/32)*(D/32)
  int row0 = (tile >> 2) * 32, col0 = (tile & 3) * 32;
  const unsigned short* ap = xbf + (size_t)(row0 + qc) * D + hi * 8;
  const unsigned short* bp = wt + (size_t)(col0 + qc) * D + hi * 8;
  f32x16 o = {0.f};
#pragma unroll
  for (int kk = 0; kk < 8; kk++) {
    bf16x8 a = *(const bf16x8*)(ap + kk * 16);
    bf16x8 b = *(const bf16x8*)(bp + kk * 16);
    o = MFMA32(a, b, o);
  }
  // lane holds D[row=(r&3)+8*(r>>2)+4*hi][col=qc]
#pragma unroll
  for (int r = 0; r < 16; r++) {
    int rr = (r & 3) + 8 * (r >> 2) + 4 * hi;
    hbf[(size_t)(row0 + rr) * D + col0 + qc] = f2bf(o[r]);
  }
}

// ---------- GAT: a_s, a_d from h (pre-scaled by log2e) ----------
__global__ __launch_bounds__(128) void k_gat_attn(const unsigned short* __restrict__ hbf,
                                                  const float* __restrict__ asrc,
                                                  const float* __restrict__ adst,
                                                  float* __restrict__ a_s,
                                                  float* __restrict__ a_d) {
  int t = threadIdx.x;
  int ni = t >> 4, j = t & 15;
  int n = blockIdx.x * 8 + ni;
  const unsigned short* hp = hbf + (size_t)n * D + j * 8;
  float p = 0.f, q = 0.f;
#pragma unroll
  for (int c = 0; c < 8; c++) {
    float hv = bf2f(hp[c]);
    p += hv * asrc[j * 8 + c];
    q += hv * adst[j * 8 + c];
  }
  p += __shfl_xor(p, 1); p += __shfl_xor(p, 2);
  q += __shfl_xor(q, 1); q += __shfl_xor(q, 2);
  if ((j & 3) == 0) {
    int head = j >> 2;
    a_s[n * H + head] = p * LOG2E;
    a_d[n * H + head] = q * LOG2E;
  }
}

__device__ __forceinline__ float leaky(float v) { return v > 0.f ? v : 0.2f * v; }

// ---------- GAT aggregation (single pass, no max) + residual + LN ----------
__global__ __launch_bounds__(128) void k_gat_agg(const unsigned short* __restrict__ hbf,
                                                 const float* __restrict__ a_s,
                                                 const float* __restrict__ a_d,
                                                 const int* __restrict__ indptr,
                                                 const int* __restrict__ sorted,
                                                 const float* __restrict__ gb,
                                                 const float* __restrict__ g,
                                                 const float* __restrict__ bb,
                                                 float* __restrict__ x,
                                                 unsigned short* __restrict__ xbf) {
  int n = blockIdx.x, tid = threadIdx.x;
  int beg = indptr[n], end = indptr[n + 1];
  __shared__ int s_src[128];
  __shared__ float s_ex[128 * 4];
  __shared__ float tmp2[2];
  float4 ad = *(const float4*)&a_d[n * H];
  int hd = tid >> 5;
  float acc = 0.f;
  float d0 = 0.f, d1 = 0.f, d2 = 0.f, d3 = 0.f;

  for (int c0 = beg; c0 < end; c0 += 128) {
    __syncthreads();
    int e = c0 + tid;
    if (e < end) {
      int s = sorted[e];
      s_src[tid] = s;
      float4 as = *(const float4*)&a_s[s * H];
      float e0 = exp2f(leaky(as.x + ad.x));
      float e1 = exp2f(leaky(as.y + ad.y));
      float e2 = exp2f(leaky(as.z + ad.z));
      float e3 = exp2f(leaky(as.w + ad.w));
      s_ex[tid * 4 + 0] = e0;
      s_ex[tid * 4 + 1] = e1;
      s_ex[tid * 4 + 2] = e2;
      s_ex[tid * 4 + 3] = e3;
      d0 += e0; d1 += e1; d2 += e2; d3 += e3;
    }
    __syncthreads();
    int nc = min(128, end - c0);
#pragma unroll 4
    for (int i = 0; i < nc; i++) {
      acc += s_ex[i * 4 + hd] * bf2f(hbf[s_src[i] * D + tid]);
    }
  }
  // reduce per-head denominators across the block
  float t0 = red128_sum(d0, tmp2, tid);
  float t1 = red128_sum(d1, tmp2, tid);
  float t2 = red128_sum(d2, tmp2, tid);
  float t3 = red128_sum(d3, tmp2, tid);
  float dd = (hd == 0) ? t0 : (hd == 1) ? t1 : (hd == 2) ? t2 : t3;
  float out = acc * (1.f / (dd + 1e-16f)) + gb[tid];
  // epilogue: relu, residual, LN
  float y = x[n * D + tid] + fmaxf(out, 0.f);
  float s1 = red128_sum(y, tmp2, tid);
  float s2 = red128_sum(y * y, tmp2, tid);
  float mean = s1 * (1.f / D);
  float var = s2 * (1.f / D) - mean * mean;
  float o = (y - mean) * rsqrtf(var + 1e-5f) * g[tid] + bb[tid];
  x[n * D + tid] = o;
  xbf[n * D + tid] = f2bf(o);
}

// ---------- q/k/v projections -> bf16 q row-major; K,V packed in MFMA fragment order ----------
// K pack index for (node n, chan c): hh=c>>5, cw=c&31, frag=(cw>>4)&1, hi=(cw>>3)&1, j=cw&7
//   kpk[(((hh*NT_TOT + n/32)*2 + frag)*64 + hi*32 + (n&31))*8 + j]
// V pack index for (key n, chan c): hh=c>>5, qc=c&31, kk=n&31, frag=(kk>>4)&1, hi=(kk>>3)&1, j=kk&7
//   vpk[(((hh*NT_TOT + n/32)*2 + frag)*64 + hi*32 + qc)*8 + j]
__global__ __launch_bounds__(128) void k_qkv(const float* __restrict__ x,
                                             const float* __restrict__ pe,
                                             const float* __restrict__ Wq,
                                             const float* __restrict__ Wk,
                                             const float* __restrict__ Wv,
                                             const float* __restrict__ bq,
                                             const float* __restrict__ bk,
                                             const float* __restrict__ bv,
                                             unsigned short* __restrict__ qbf,
                                             unsigned short* __restrict__ kpk,
                                             unsigned short* __restrict__ vpk) {
  int tid = threadIdx.x, r0 = blockIdx.x * 8;
  __shared__ float xs[8][D], ps[8][D];
#pragma unroll
  for (int r = 0; r < 8; r++) {
    xs[r][tid] = x[(r0 + r) * D + tid];
    ps[r][tid] = pe[(r0 + r) * D + tid];
  }
  __syncthreads();
  float aq[8], ak[8], av[8];
#pragma unroll
  for (int r = 0; r < 8; r++) { aq[r] = 0.f; ak[r] = 0.f; av[r] = 0.f; }
  for (int kk = 0; kk < D; kk++) {
    float wq = Wq[kk * D + tid], wk = Wk[kk * D + tid], wv = Wv[kk * D + tid];
#pragma unroll
    for (int r = 0; r < 8; r++) {
      aq[r] += xs[r][kk] * wq;
      ak[r] += ps[r][kk] * wk;
      av[r] += ps[r][kk] * wv;
    }
  }
  // 1/sqrt(32) * log2(e) folded into q -> softmax runs in exp2 domain
  const float sc = 0.25503491f;
  float bqv = bq[tid], bkv = bk[tid], bvv = bv[tid];
  int hh = tid >> 5, cw = tid & 31;
  int kfrag = (cw >> 4) & 1, khi = (cw >> 3) & 1, kj = cw & 7;
#pragma unroll
  for (int r = 0; r < 8; r++) {
    int n = r0 + r;
    int kt = n >> 5, qn = n & 31;
    qbf[(size_t)n * D + tid] = f2bf((aq[r] + bqv) * sc);
    // K packed
    kpk[((((size_t)hh * NT_TOT + kt) * 2 + kfrag) * 64 + khi * 32 + qn) * 8 + kj] = f2bf(ak[r] + bkv);
    // V packed (key n, channel tid)
    int vfrag = (qn >> 4) & 1, vhi = (qn >> 3) & 1, vj = qn & 7;
    vpk[((((size_t)hh * NT_TOT + kt) * 2 + vfrag) * 64 + vhi * 32 + cw) * 8 + vj] = f2bf(av[r] + bvv);
  }
}

// ---------- flash attention: swapped-operand 32x32 MFMA, no-max softmax, dual acc ----------
// packed fragment loads: one contiguous 1KB block per instruction
#define ALOAD(KA0, KA1, VB0_, VB1_, TI) do { \
  const unsigned short* kp_ = kB + (size_t)(TI) * 1024 + l8; \
  const unsigned short* vp_ = vB + (size_t)(TI) * 1024 + l8; \
  KA0 = *(const bf16x8*)(kp_); \
  KA1 = *(const bf16x8*)(kp_ + 512); \
  VB0_ = *(const bf16x8*)(vp_); \
  VB1_ = *(const bf16x8*)(vp_ + 512); \
} while (0)

#define TILE32(KA0, KA1, VB0_, VB1_, O, LS) do { \
  f32x16 s = MFMA32(KA0, qa0, zz16); \
  s = MFMA32(KA1, qa1, s); \
  float p0 = __builtin_amdgcn_exp2f(s[0]), p1 = __builtin_amdgcn_exp2f(s[1]); \
  float p2 = __builtin_amdgcn_exp2f(s[2]), p3 = __builtin_amdgcn_exp2f(s[3]); \
  float p4 = __builtin_amdgcn_exp2f(s[4]), p5 = __builtin_amdgcn_exp2f(s[5]); \
  float p6 = __builtin_amdgcn_exp2f(s[6]), p7 = __builtin_amdgcn_exp2f(s[7]); \
  float p8 = __builtin_amdgcn_exp2f(s[8]), p9 = __builtin_amdgcn_exp2f(s[9]); \
  float pa = __builtin_amdgcn_exp2f(s[10]), pc = __builtin_amdgcn_exp2f(s[11]); \
  float pd = __builtin_amdgcn_exp2f(s[12]), pe_ = __builtin_amdgcn_exp2f(s[13]); \
  float pf = __builtin_amdgcn_exp2f(s[14]), pg = __builtin_amdgcn_exp2f(s[15]); \
  LS += (((p0 + p1) + (p2 + p3)) + ((p4 + p5) + (p6 + p7))) + \
        (((p8 + p9) + (pa + pc)) + ((pd + pe_) + (pf + pg))); \
  unsigned x0_ = cvtpk(p0, p1), x1_ = cvtpk(p2, p3); \
  unsigned y0_ = cvtpk(p4, p5), y1_ = cvtpk(p6, p7); \
  P32SWAP(x0_, y0_); P32SWAP(x1_, y1_); \
  unsigned x2_ = cvtpk(p8, p9), x3_ = cvtpk(pa, pc); \
  unsigned y2_ = cvtpk(pd, pe_), y3_ = cvtpk(pf, pg); \
  P32SWAP(x2_, y2_); P32SWAP(x3_, y3_); \
  union { unsigned u[4]; bf16x8 v; } fa_, fb_; \
  fa_.u[0] = x0_; fa_.u[1] = x1_; fa_.u[2] = y0_; fa_.u[3] = y1_; \
  fb_.u[0] = x2_; fb_.u[1] = x3_; fb_.u[2] = y2_; fb_.u[3] = y3_; \
  O = MFMA32(VB0_, fa_.v, O); \
  O = MFMA32(VB1_, fb_.v, O); \
} while (0)

__global__ __launch_bounds__(256) void k_attn_split(const unsigned short* __restrict__ qbf,
                                                    const unsigned short* __restrict__ kpk,
                                                    const unsigned short* __restrict__ vpk,
                                                    unsigned short* __restrict__ po,
                                                    float* __restrict__ pl) {
  int hh = blockIdx.y;
  int sp = blockIdx.z;
  int t = threadIdx.x;
  int wid = t >> 6, l = t & 63;
  int qc = l & 31, hi = l >> 5;
  int l8 = l * 8;
  int q0w = blockIdx.x * 128 + wid * 32;

  const f32x16 zz16 = {0.f};

  // Q^T B-frags (loop-invariant): lane l -> Q[q0w+qc][hh*32 + hi*8 + (0|16) + j]
  const unsigned short* qp = qbf + (size_t)(q0w + qc) * D + hh * 32 + hi * 8;
  bf16x8 qa0 = *(const bf16x8*)(qp);
  bf16x8 qa1 = *(const bf16x8*)(qp + 16);

  // packed K/V bases for this head+split (tile stride = 1024 shorts)
  const unsigned short* kB = kpk + ((size_t)hh * NT_TOT + sp * (KV_PER / 32)) * 1024;
  const unsigned short* vB = vpk + ((size_t)hh * NT_TOT + sp * (KV_PER / 32)) * 1024;

  f32x16 oA = {0.f}, oB = {0.f};
  float lsA = 0.f, lsB = 0.f;

  bf16x8 ka0, ka1, va0, va1, kb0r, kb1r, vb0r, vb1r;
  ALOAD(ka0, ka1, va0, va1, 0);
  const int NT = KV_PER / 32;  // 24 tiles
  for (int it = 0; it < NT; it += 2) {
    ALOAD(kb0r, kb1r, vb0r, vb1r, it + 1);
    TILE32(ka0, ka1, va0, va1, oA, lsA);
    if (it + 2 < NT) ALOAD(ka0, ka1, va0, va1, it + 2);
    TILE32(kb0r, kb1r, vb0r, vb1r, oB, lsB);
  }

  f32x16 o = oA + oB;
  float lsum = lsA + lsB;
  // lane l holds O^T[chan = (r&3)+8*(r>>2)+4*hi][q = qc] (unnormalized)
  float lt = lsum + __shfl_xor(lsum, 32, 64);
  size_t pbase = (size_t)(sp * H + hh) * N_NODES + q0w + qc;
  unsigned short* pop = po + pbase * 32 + 4 * hi;
  uint2 v0, v1, v2, v3;
  v0.x = cvtpk(o[0], o[1]);   v0.y = cvtpk(o[2], o[3]);
  v1.x = cvtpk(o[4], o[5]);   v1.y = cvtpk(o[6], o[7]);
  v2.x = cvtpk(o[8], o[9]);   v2.y = cvtpk(o[10], o[11]);
  v3.x = cvtpk(o[12], o[13]); v3.y = cvtpk(o[14], o[15]);
  *(uint2*)(pop)      = v0;
  *(uint2*)(pop + 8)  = v1;
  *(uint2*)(pop + 16) = v2;
  *(uint2*)(pop + 24) = v3;
  if (l < 32) {
    pl[pbase] = lt;
  }
}

__global__ __launch_bounds__(256) void k_attn_combine(const unsigned short* __restrict__ po,
                                                      const float* __restrict__ pl,
                                                      float* __restrict__ xa) {
  int t = blockIdx.x * 256 + threadIdx.x;  // N*D/2 threads, 2 chans each
  int q = t >> 6, cp = t & 63;
  int c2 = cp * 2, hh = c2 >> 5, c = c2 & 31;
  int base = hh * N_NODES + q;
  const int SN = H * N_NODES;
  float ll = 0.f, olo = 0.f, ohi = 0.f;
#pragma unroll
  for (int s = 0; s < SPLITS; s++) {
    ll += pl[s * SN + base];
    unsigned dw = *(const unsigned*)(po + ((size_t)(s * SN + base)) * 32 + c);
    olo += bf2f((unsigned short)(dw & 0xffff));
    ohi += bf2f((unsigned short)(dw >> 16));
  }
  float inv = 1.f / ll;
  float* op = xa + (size_t)q * D + hh * 32 + c;
  op[0] = olo * inv;
  op[1] = ohi * inv;
}

// ---------- Wo + residual + LN + pooled partial ----------
__global__ __launch_bounds__(128) void k_ca(const float* __restrict__ xa,
                                            const float* __restrict__ Wo,
                                            const float* __restrict__ bo,
                                            const float* __restrict__ g,
                                            const float* __restrict__ bb,
                                            float* __restrict__ x, float* __restrict__ pooled,
                                            float* __restrict__ outx) {
  int tid = threadIdx.x, r0 = blockIdx.x * 8;
  __shared__ float xs[8][D];
  __shared__ float tmp2[2];
#pragma unroll
  for (int r = 0; r < 8; r++) xs[r][tid] = xa[(r0 + r) * D + tid];
  __syncthreads();
  float acc[8];
#pragma unroll
  for (int r = 0; r < 8; r++) acc[r] = bo[tid];
  for (int kk = 0; kk < D; kk++) {
    float w = Wo[kk * D + tid];
#pragma unroll
    for (int r = 0; r < 8; r++) acc[r] += xs[r][kk] * w;
  }
  float gv = g[tid], bv = bb[tid];
  float psum = 0.f;
#pragma unroll
  for (int r = 0; r < 8; r++) {
    float y = x[(r0 + r) * D + tid] + acc[r];
    float t1 = red128_sum(y, tmp2, tid);
    float t2 = red128_sum(y * y, tmp2, tid);
    float mean = t1 * (1.f / D);
    float var = t2 * (1.f / D) - mean * mean;
    float o = (y - mean) * rsqrtf(var + 1e-5f) * gv + bv;
    x[(r0 + r) * D + tid] = o;
    outx[(r0 + r) * D + tid] = o;
    psum += o;
  }
  atomicAdd(&pooled[tid], psum);
}

// ---------- policy head (block per query node) ----------
__global__ __launch_bounds__(128) void k_policy(const float* __restrict__ x,
                                                const float* __restrict__ W1,
                                                const float* __restrict__ b1,
                                                const float* __restrict__ W2,
                                                const float* __restrict__ b2,
                                                const float* __restrict__ W3,
                                                const float* __restrict__ b3,
                                                float* __restrict__ logits) {
  int n = blockIdx.x, tid = threadIdx.x;
  __shared__ float xs[D], h1[D], h2[64];
  xs[tid] = x[n * D + tid];
  __syncthreads();
  float a = b1[tid];
  for (int kk = 0; kk < D; kk++) a += xs[kk] * W1[kk * D + tid];
  h1[tid] = fmaxf(a, 0.f);
  __syncthreads();
  if (tid < 64) {
    float a2 = b2[tid];
    for (int kk = 0; kk < D; kk++) a2 += h1[kk] * W2[kk * 64 + tid];
    h2[tid] = fmaxf(a2, 0.f);
  }
  __syncthreads();
  float p0 = 0.f, p1 = 0.f;
  if (tid < 64) { p0 = h2[tid] * W3[tid * 2]; p1 = h2[tid] * W3[tid * 2 + 1]; }
#pragma unroll
  for (int m = 1; m < 64; m <<= 1) { p0 += __shfl_xor(p0, m, 64); p1 += __shfl_xor(p1, m, 64); }
  if (tid == 0) {
    logits[n * 2] = p0 + b3[0];
    logits[n * 2 + 1] = p1 + b3[1];
  }
}

// ---------- value head (single block) ----------
__global__ __launch_bounds__(128) void k_value(const float* __restrict__ pooled,
                                               const float* __restrict__ W1,
                                               const float* __restrict__ b1,
                                               const float* __restrict__ W2,
                                               const float* __restrict__ b2,
                                               const float* __restrict__ W3,
                                               const float* __restrict__ b3,
                                               float* __restrict__ val) {
  int tid = threadIdx.x;
  __shared__ float ps[D], v1[D], v2[64];
  ps[tid] = pooled[tid] * (1.f / N_NODES);
  __syncthreads();
  float a = b1[tid];
  for (int kk = 0; kk < D; kk++) a += ps[kk] * W1[kk * D + tid];
  v1[tid] = fmaxf(a, 0.f);
  __syncthreads();
  if (tid < 64) {
    float a2 = b2[tid];
    for (int kk = 0; kk < D; kk++) a2 += v1[kk] * W2[kk * 64 + tid];
    v2[tid] = fmaxf(a2, 0.f);
  }
  __syncthreads();
  float p = (tid < 64) ? v2[tid] * W3[tid] : 0.f;
#pragma unroll
  for (int m = 1; m < 64; m <<= 1) p += __shfl_xor(p, m, 64);
  if (tid == 0) val[0] = p + b3[0];
}

extern "C" void kernel_launch(void* const* d_in, const int* in_sizes, int n_in,
                              void* d_out, int out_size, void* d_ws, size_t ws_size,
                              hipStream_t stream) {
  const float* nf   = (const float*)d_in[0];
  const int*   ei   = (const int*)d_in[1];
  const float* pe   = (const float*)d_in[2];
  const float* embW = (const float*)d_in[3];
  const float* embB = (const float*)d_in[4];
  const float* elng = (const float*)d_in[5];
  const float* elnb = (const float*)d_in[6];
  const float* gatW = (const float*)d_in[7];
  const float* aS   = (const float*)d_in[8];
  const float* aD   = (const float*)d_in[9];
  const float* gatB = (const float*)d_in[10];
  const float* lng  = (const float*)d_in[11];
  const float* lnb  = (const float*)d_in[12];
  const float* Wq   = (const float*)d_in[13];
  const float* Wk   = (const float*)d_in[14];
  const float* Wv   = (const float*)d_in[15];
  const float* Wo   = (const float*)d_in[16];
  const float* bq   = (const float*)d_in[17];
  const float* bk   = (const float*)d_in[18];
  const float* bv   = (const float*)d_in[19];
  const float* bo   = (const float*)d_in[20];
  const float* cag  = (const float*)d_in[21];
  const float* cab  = (const float*)d_in[22];
  const float* pW1  = (const float*)d_in[23];
  const float* pb1  = (const float*)d_in[24];
  const float* pW2  = (const float*)d_in[25];
  const float* pb2  = (const float*)d_in[26];
  const float* pW3  = (const float*)d_in[27];
  const float* pb3  = (const float*)d_in[28];
  const float* vW1  = (const float*)d_in[29];
  const float* vb1  = (const float*)d_in[30];
  const float* vW2  = (const float*)d_in[31];
  const float* vb2  = (const float*)d_in[32];
  const float* vW3  = (const float*)d_in[33];
  const float* vb3  = (const float*)d_in[34];

  // workspace layout
  float* fw = (float*)d_ws;
  float* x      = fw; fw += N_NODES * D;
  float* hbuf   = fw; fw += N_NODES * D;   // bf16 h during GAT; fp32 xa after attention
  float* a_s    = fw; fw += N_NODES * H;
  float* a_d    = fw; fw += N_NODES * H;
  float* pooled = fw; fw += 128;
  float* pl     = fw; fw += SPLITS * H * N_NODES;
  unsigned short* ub = (unsigned short*)fw;
  unsigned short* po  = ub; ub += (size_t)SPLITS * H * N_NODES * 32;
  unsigned short* qbf = ub; ub += N_NODES * D;
  unsigned short* kpk = ub; ub += N_NODES * D;
  unsigned short* vpk = ub; ub += N_NODES * D;
  unsigned short* xbf = ub; ub += N_NODES * D;
  unsigned short* wtb = ub; ub += L_LAYERS * D * D;
  int* ib     = (int*)ub;
  int* cnt    = ib; ib += N_NODES;
  int* cur    = ib; ib += N_NODES;
  int* indptr = ib; ib += N_NODES + 16;
  int* sorted = ib;

  unsigned short* hbf = (unsigned short*)hbuf;  // bf16 alias (first half of hbuf)

  float* out    = (float*)d_out;
  float* logits = out;
  float* val    = out + NQ_ * 2;
  float* outx   = out + NQ_ * 2 + 1;

  const int* esrc = ei;
  const int* edst = ei + E_EDGES;

  hipLaunchKernelGGL(k_zero, dim3(24), dim3(256), 0, stream, cnt, cur, pooled);
  hipLaunchKernelGGL(k_hist, dim3(512), dim3(256), 0, stream, edst, cnt);
  hipLaunchKernelGGL(k_scan, dim3(1), dim3(256), 0, stream, cnt, indptr);
  hipLaunchKernelGGL(k_scatter, dim3(512), dim3(256), 0, stream, esrc, edst, indptr, cur, sorted);
  hipLaunchKernelGGL(k_embed, dim3(N_NODES), dim3(128), 0, stream, nf, embW, embB, elng, elnb, x, xbf);
  hipLaunchKernelGGL(k_wprep, dim3(L_LAYERS * D * D / 256), dim3(256), 0, stream, gatW, wtb);
  for (int l = 0; l < L_LAYERS; l++) {
    hipLaunchKernelGGL(k_gat_gemm, dim3(N_NODES / 32), dim3(256), 0, stream,
                       xbf, wtb + l * D * D, hbf);
    hipLaunchKernelGGL(k_gat_attn, dim3(N_NODES / 8), dim3(128), 0, stream,
                       hbf, aS + l * D, aD + l * D, a_s, a_d);
    hipLaunchKernelGGL(k_gat_agg, dim3(N_NODES), dim3(128), 0, stream,
                       hbf, a_s, a_d, indptr, sorted, gatB + l * D, lng + l * D, lnb + l * D, x, xbf);
  }
  hipLaunchKernelGGL(k_qkv, dim3(N_NODES / 8), dim3(128), 0, stream,
                     x, pe, Wq, Wk, Wv, bq, bk, bv, qbf, kpk, vpk);
  hipLaunchKernelGGL(k_attn_split, dim3(N_NODES / 128, H, SPLITS), dim3(256), 0, stream,
                     qbf, kpk, vpk, po, pl);
  hipLaunchKernelGGL(k_attn_combine, dim3(N_NODES * D / 512), dim3(256), 0, stream,
                     po, pl, hbuf);
  hipLaunchKernelGGL(k_ca, dim3(N_NODES / 8), dim3(128), 0, stream,
                     hbuf, Wo, bo, cag, cab, x, pooled, outx);
  hipLaunchKernelGGL(k_policy, dim3(NQ_), dim3(128), 0, stream,
                     x, pW1, pb1, pW2, pb2, pW3, pb3, logits);
  hipLaunchKernelGGL(k_value, dim3(1), dim3(128), 0, stream,
                     pooled, vW1, vb1, vW2, vb2, vW3, vb3, val);
}

// Round 9
// 273.865 us; speedup vs baseline: 1.6525x; 1.1194x over previous
//
#include <hip/hip_runtime.h>
#include <hip/hip_bf16.h>

#define N_NODES 6144
#define NQ_ 3072
#define D 128
#define H 4
#define C 32
#define F_IN 10
#define L_LAYERS 4
#define E_EDGES 393216
#define E_TOT (E_EDGES + N_NODES)
#define SPLITS 8
#define KV_PER (N_NODES / SPLITS)  // 768 keys per split = 24 tiles of 32
#define NT_TOT (N_NODES / 32)      // 192 tiles total
#define LOG2E 1.4426950408889634f

typedef __attribute__((ext_vector_type(8))) short bf16x8;
typedef __attribute__((ext_vector_type(4))) float f32x4;
typedef __attribute__((ext_vector_type(16))) float f32x16;

__device__ __forceinline__ unsigned short f2bf(float f) {
  unsigned u = __float_as_uint(f);
  unsigned r = (u + 0x7fffu + ((u >> 16) & 1u)) >> 16;
  return (unsigned short)r;
}

__device__ __forceinline__ float bf2f(unsigned short s) {
  return __uint_as_float(((unsigned)s) << 16);
}

__device__ __forceinline__ unsigned cvtpk(float lo, float hi) {
  unsigned r;
  asm volatile("v_cvt_pk_bf16_f32 %0, %1, %2" : "=v"(r) : "v"(lo), "v"(hi));
  return r;
}

// vdst-high(lanes 32-63) <-> src0-low(lanes 0-31)
#define P32SWAP(a, b) asm volatile("v_permlane32_swap_b32 %0, %1" : "+v"(a), "+v"(b))

#define MFMA32(A, B, CIN) __builtin_amdgcn_mfma_f32_32x32x16_bf16(A, B, CIN, 0, 0, 0)

// ---------- helpers ----------
__device__ __forceinline__ float red128_sum(float v, float* tmp2, int tid) {
#pragma unroll
  for (int m = 1; m < 64; m <<= 1) v += __shfl_xor(v, m, 64);
  __syncthreads();                 // protect tmp2 reuse across calls
  if ((tid & 63) == 0) tmp2[tid >> 6] = v;
  __syncthreads();
  return tmp2[0] + tmp2[1];
}

// 32x32 output tile of A(rows x 128) @ B^T(cols x 128), both bf16 row-major.
// lane holds D[row=(r&3)+8*(r>>2)+4*hi][col=qc]  (verified fragment map)
__device__ __forceinline__ f32x16 tile_gemm128(const unsigned short* __restrict__ A,
                                               const unsigned short* __restrict__ Bt,
                                               int row0, int col0, int qc, int hi) {
  const unsigned short* ap = A + (size_t)(row0 + qc) * 128 + hi * 8;
  const unsigned short* bp = Bt + (size_t)(col0 + qc) * 128 + hi * 8;
  f32x16 o = {0.f};
#pragma unroll
  for (int kk = 0; kk < 8; kk++) {
    bf16x8 a = *(const bf16x8*)(ap + kk * 16);
    bf16x8 b = *(const bf16x8*)(bp + kk * 16);
    o = MFMA32(a, b, o);
  }
  return o;
}

// ---------- CSR build ----------
__global__ void k_zero(int* cnt, int* cur, float* pooled) {
  int i = blockIdx.x * blockDim.x + threadIdx.x;
  if (i < N_NODES) { cnt[i] = 0; cur[i] = 0; }
  if (i < D) pooled[i] = 0.f;
}

__global__ void k_hist(const int* __restrict__ dst, int* __restrict__ cnt) {
  for (int i = blockIdx.x * blockDim.x + threadIdx.x; i < E_EDGES; i += gridDim.x * blockDim.x)
    atomicAdd(&cnt[dst[i]], 1);
}

__global__ void k_scan(const int* __restrict__ cnt, int* __restrict__ indptr) {
  __shared__ int ps[256];
  int tid = threadIdx.x;
  const int CH = N_NODES / 256;  // 24
  int base = tid * CH;
  int loc[CH];
  int s = 0;
#pragma unroll
  for (int i = 0; i < CH; i++) { loc[i] = cnt[base + i] + 1; s += loc[i]; }  // +1 self loop
  ps[tid] = s;
  __syncthreads();
  for (int off = 1; off < 256; off <<= 1) {
    int v = (tid >= off) ? ps[tid - off] : 0;
    __syncthreads();
    ps[tid] += v;
    __syncthreads();
  }
  int run = (tid == 0) ? 0 : ps[tid - 1];
#pragma unroll
  for (int i = 0; i < CH; i++) { indptr[base + i] = run; run += loc[i]; }
  if (tid == 255) indptr[N_NODES] = run;
}

__global__ void k_scatter(const int* __restrict__ src, const int* __restrict__ dst,
                          const int* __restrict__ indptr, int* __restrict__ cur,
                          int* __restrict__ sorted) {
  for (int i = blockIdx.x * blockDim.x + threadIdx.x; i < E_TOT; i += gridDim.x * blockDim.x) {
    if (i < E_EDGES) {
      int d = dst[i];
      int p = atomicAdd(&cur[d], 1);
      sorted[indptr[d] + p] = src[i];
    } else {
      int n = i - E_EDGES;
      int p = atomicAdd(&cur[n], 1);
      sorted[indptr[n] + p] = n;
    }
  }
}

// ---------- embedding ----------
__global__ __launch_bounds__(128) void k_embed(const float* __restrict__ nf,
                                               const float* __restrict__ W,
                                               const float* __restrict__ b,
                                               const float* __restrict__ g,
                                               const float* __restrict__ bb,
                                               float* __restrict__ x,
                                               unsigned short* __restrict__ xbf) {
  int n = blockIdx.x, j = threadIdx.x;
  __shared__ float f[F_IN];
  __shared__ float tmp2[2];
  if (j < F_IN) f[j] = nf[n * F_IN + j];
  __syncthreads();
  float acc = b[j];
#pragma unroll
  for (int k = 0; k < F_IN; k++) acc += f[k] * W[k * D + j];
  float s1 = red128_sum(acc, tmp2, j);
  float s2 = red128_sum(acc * acc, tmp2, j);
  float mean = s1 * (1.f / D);
  float var = s2 * (1.f / D) - mean * mean;
  float y = (acc - mean) * rsqrtf(var + 1e-5f) * g[j] + bb[j];
  y = fmaxf(y, 0.f);
  x[n * D + j] = y;
  xbf[n * D + j] = f2bf(y);
}

// ---------- GAT W -> W^T bf16 (all layers, one-shot) ----------
__global__ void k_wprep(const float* __restrict__ W, unsigned short* __restrict__ wt) {
  int i = blockIdx.x * 256 + threadIdx.x;  // 4*128*128 = 65536
  int l = i >> 14, rem = i & 16383, j = rem >> 7, k = rem & 127;
  wt[i] = f2bf(W[l * 16384 + k * 128 + j]);
}

// ---------- qkv/mlp weight prep: transpose + bf16 ----------
__global__ void k_wqkvprep(const float* __restrict__ Wq, const float* __restrict__ Wk,
                           const float* __restrict__ Wv, const float* __restrict__ W1,
                           const float* __restrict__ W2, const float* __restrict__ Wo,
                           unsigned short* __restrict__ wqt, unsigned short* __restrict__ wkt,
                           unsigned short* __restrict__ wvt, unsigned short* __restrict__ w1t,
                           unsigned short* __restrict__ w2t, unsigned short* __restrict__ wot) {
  int i = blockIdx.x * 256 + threadIdx.x;  // 90112 total
  if (i < 65536) {
    int m = i >> 14, loc = i & 16383, j = loc >> 7, k = loc & 127;
    const float* src = (m == 0) ? Wq : (m == 1) ? Wk : (m == 2) ? Wv : W1;
    unsigned short* dst = (m == 0) ? wqt : (m == 1) ? wkt : (m == 2) ? wvt : w1t;
    dst[loc] = f2bf(src[k * 128 + j]);
  } else if (i < 73728) {
    int loc = i - 65536, j = loc >> 7, k = loc & 127;  // j<64
    w2t[loc] = f2bf(W2[k * 64 + j]);
  } else if (i < 90112) {
    int loc = i - 73728, j = loc >> 7, k = loc & 127;
    wot[loc] = f2bf(Wo[k * 128 + j]);
  }
}

// ---------- pe -> bf16 ----------
__global__ void k_pebf(const float* __restrict__ pe, unsigned short* __restrict__ pebf) {
  int i = blockIdx.x * 256 + threadIdx.x;  // N*D/4
  float4 v = *(const float4*)(pe + (size_t)i * 4);
  unsigned lo = (unsigned)f2bf(v.x) | ((unsigned)f2bf(v.y) << 16);
  unsigned hi = (unsigned)f2bf(v.z) | ((unsigned)f2bf(v.w) << 16);
  *(uint2*)(pebf + (size_t)i * 4) = make_uint2(lo, hi);
}

// ---------- GAT: H = X@W via MFMA (bf16 in/out) ----------
__global__ __launch_bounds__(256) void k_gat_gemm(const unsigned short* __restrict__ xbf,
                                                  const unsigned short* __restrict__ wt,
                                                  unsigned short* __restrict__ hbf) {
  int t = threadIdx.x;
  int w = t >> 6, l = t & 63, qc = l & 31, hi = l >> 5;
  int tile = blockIdx.x * 4 + w;           // 768 tiles = (N/32)*(D/32)
  int row0 = (tile >> 2) * 32, col0 = (tile & 3) * 32;
  f32x16 o = tile_gemm128(xbf, wt, row0, col0, qc, hi);
#pragma unroll
  for (int r = 0; r < 16; r++) {
    int rr = (r & 3) + 8 * (r >> 2) + 4 * hi;
    hbf[(size_t)(row0 + rr) * D + col0 + qc] = f2bf(o[r]);
  }
}

// ---------- GAT: a_s, a_d from h (pre-scaled by log2e) ----------
__global__ __launch_bounds__(128) void k_gat_attn(const unsigned short* __restrict__ hbf,
                                                  const float* __restrict__ asrc,
                                                  const float* __restrict__ adst,
                                                  float* __restrict__ a_s,
                                                  float* __restrict__ a_d) {
  int t = threadIdx.x;
  int ni = t >> 4, j = t & 15;
  int n = blockIdx.x * 8 + ni;
  const unsigned short* hp = hbf + (size_t)n * D + j * 8;
  float p = 0.f, q = 0.f;
#pragma unroll
  for (int c = 0; c < 8; c++) {
    float hv = bf2f(hp[c]);
    p += hv * asrc[j * 8 + c];
    q += hv * adst[j * 8 + c];
  }
  p += __shfl_xor(p, 1); p += __shfl_xor(p, 2);
  q += __shfl_xor(q, 1); q += __shfl_xor(q, 2);
  if ((j & 3) == 0) {
    int head = j >> 2;
    a_s[n * H + head] = p * LOG2E;
    a_d[n * H + head] = q * LOG2E;
  }
}

__device__ __forceinline__ float leaky(float v) { return v > 0.f ? v : 0.2f * v; }

// ---------- GAT aggregation (single pass, no max) + residual + LN ----------
__global__ __launch_bounds__(128) void k_gat_agg(const unsigned short* __restrict__ hbf,
                                                 const float* __restrict__ a_s,
                                                 const float* __restrict__ a_d,
                                                 const int* __restrict__ indptr,
                                                 const int* __restrict__ sorted,
                                                 const float* __restrict__ gb,
                                                 const float* __restrict__ g,
                                                 const float* __restrict__ bb,
                                                 float* __restrict__ x,
                                                 unsigned short* __restrict__ xbf) {
  int n = blockIdx.x, tid = threadIdx.x;
  int beg = indptr[n], end = indptr[n + 1];
  __shared__ int s_src[128];
  __shared__ float s_ex[128 * 4];
  __shared__ float tmp2[2];
  float4 ad = *(const float4*)&a_d[n * H];
  int hd = tid >> 5;
  float acc = 0.f;
  float d0 = 0.f, d1 = 0.f, d2 = 0.f, d3 = 0.f;

  for (int c0 = beg; c0 < end; c0 += 128) {
    __syncthreads();
    int e = c0 + tid;
    if (e < end) {
      int s = sorted[e];
      s_src[tid] = s;
      float4 as = *(const float4*)&a_s[s * H];
      float e0 = exp2f(leaky(as.x + ad.x));
      float e1 = exp2f(leaky(as.y + ad.y));
      float e2 = exp2f(leaky(as.z + ad.z));
      float e3 = exp2f(leaky(as.w + ad.w));
      s_ex[tid * 4 + 0] = e0;
      s_ex[tid * 4 + 1] = e1;
      s_ex[tid * 4 + 2] = e2;
      s_ex[tid * 4 + 3] = e3;
      d0 += e0; d1 += e1; d2 += e2; d3 += e3;
    }
    __syncthreads();
    int nc = min(128, end - c0);
#pragma unroll 4
    for (int i = 0; i < nc; i++) {
      acc += s_ex[i * 4 + hd] * bf2f(hbf[s_src[i] * D + tid]);
    }
  }
  // reduce per-head denominators across the block
  float t0 = red128_sum(d0, tmp2, tid);
  float t1 = red128_sum(d1, tmp2, tid);
  float t2 = red128_sum(d2, tmp2, tid);
  float t3 = red128_sum(d3, tmp2, tid);
  float dd = (hd == 0) ? t0 : (hd == 1) ? t1 : (hd == 2) ? t2 : t3;
  float out = acc * (1.f / (dd + 1e-16f)) + gb[tid];
  // epilogue: relu, residual, LN
  float y = x[n * D + tid] + fmaxf(out, 0.f);
  float s1 = red128_sum(y, tmp2, tid);
  float s2 = red128_sum(y * y, tmp2, tid);
  float mean = s1 * (1.f / D);
  float var = s2 * (1.f / D) - mean * mean;
  float o = (y - mean) * rsqrtf(var + 1e-5f) * g[tid] + bb[tid];
  x[n * D + tid] = o;
  xbf[n * D + tid] = f2bf(o);
}

// ---------- q/k/v via MFMA -> q row-major bf16 (scaled); K,V packed fragment order ----------
__global__ __launch_bounds__(256) void k_qkv_mfma(const unsigned short* __restrict__ xbf,
                                                  const unsigned short* __restrict__ pebf,
                                                  const unsigned short* __restrict__ wqt,
                                                  const unsigned short* __restrict__ wkt,
                                                  const unsigned short* __restrict__ wvt,
                                                  const float* __restrict__ bq,
                                                  const float* __restrict__ bk,
                                                  const float* __restrict__ bv,
                                                  unsigned short* __restrict__ qbf,
                                                  unsigned short* __restrict__ kpk,
                                                  unsigned short* __restrict__ vpk) {
  int t = threadIdx.x;
  int w = t >> 6, l = t & 63, qc = l & 31, hi = l >> 5;
  int m = blockIdx.y;
  int row0 = blockIdx.x * 32, col0 = w * 32;
  const unsigned short* A = (m == 0) ? xbf : pebf;
  const unsigned short* Bt = (m == 0) ? wqt : (m == 1) ? wkt : wvt;
  f32x16 o = tile_gemm128(A, Bt, row0, col0, qc, hi);
  int c = col0 + qc;
  int hh = col0 >> 5;
  int kt = row0 >> 5;
  if (m == 0) {
    const float sc = 0.25503491f;  // 1/sqrt(32)*log2e
    float bias = bq[c];
#pragma unroll
    for (int r = 0; r < 16; r++) {
      int rr = (r & 3) + 8 * (r >> 2) + 4 * hi;
      qbf[(size_t)(row0 + rr) * D + c] = f2bf((o[r] + bias) * sc);
    }
  } else if (m == 1) {
    float bias = bk[c];
    int kfrag = (qc >> 4) & 1, khi = (qc >> 3) & 1, kj = qc & 7;
    unsigned short* base = kpk + ((((size_t)hh * NT_TOT + kt) * 2 + kfrag) * 64 + khi * 32) * 8 + kj;
#pragma unroll
    for (int r = 0; r < 16; r++) {
      int rr = (r & 3) + 8 * (r >> 2) + 4 * hi;
      base[rr * 8] = f2bf(o[r] + bias);
    }
  } else {
    float bias = bv[c];
#pragma unroll
    for (int r = 0; r < 16; r++) {
      int rr = (r & 3) + 8 * (r >> 2) + 4 * hi;
      int vfrag = (rr >> 4) & 1, vhi = (rr >> 3) & 1, vj = rr & 7;
      vpk[((((size_t)hh * NT_TOT + kt) * 2 + vfrag) * 64 + vhi * 32 + qc) * 8 + vj] =
          f2bf(o[r] + bias);
    }
  }
}

// ---------- flash attention: swapped-operand 32x32 MFMA, no-max softmax, dual acc ----------
#define ALOAD(KA0, KA1, VB0_, VB1_, TI) do { \
  const unsigned short* kp_ = kB + (size_t)(TI) * 1024 + l8; \
  const unsigned short* vp_ = vB + (size_t)(TI) * 1024 + l8; \
  KA0 = *(const bf16x8*)(kp_); \
  KA1 = *(const bf16x8*)(kp_ + 512); \
  VB0_ = *(const bf16x8*)(vp_); \
  VB1_ = *(const bf16x8*)(vp_ + 512); \
} while (0)

#define TILE32(KA0, KA1, VB0_, VB1_, O, LS) do { \
  f32x16 s = MFMA32(KA0, qa0, zz16); \
  s = MFMA32(KA1, qa1, s); \
  float p0 = __builtin_amdgcn_exp2f(s[0]), p1 = __builtin_amdgcn_exp2f(s[1]); \
  float p2 = __builtin_amdgcn_exp2f(s[2]), p3 = __builtin_amdgcn_exp2f(s[3]); \
  float p4 = __builtin_amdgcn_exp2f(s[4]), p5 = __builtin_amdgcn_exp2f(s[5]); \
  float p6 = __builtin_amdgcn_exp2f(s[6]), p7 = __builtin_amdgcn_exp2f(s[7]); \
  float p8 = __builtin_amdgcn_exp2f(s[8]), p9 = __builtin_amdgcn_exp2f(s[9]); \
  float pa = __builtin_amdgcn_exp2f(s[10]), pc = __builtin_amdgcn_exp2f(s[11]); \
  float pd = __builtin_amdgcn_exp2f(s[12]), pe_ = __builtin_amdgcn_exp2f(s[13]); \
  float pf = __builtin_amdgcn_exp2f(s[14]), pg = __builtin_amdgcn_exp2f(s[15]); \
  LS += (((p0 + p1) + (p2 + p3)) + ((p4 + p5) + (p6 + p7))) + \
        (((p8 + p9) + (pa + pc)) + ((pd + pe_) + (pf + pg))); \
  unsigned x0_ = cvtpk(p0, p1), x1_ = cvtpk(p2, p3); \
  unsigned y0_ = cvtpk(p4, p5), y1_ = cvtpk(p6, p7); \
  P32SWAP(x0_, y0_); P32SWAP(x1_, y1_); \
  unsigned x2_ = cvtpk(p8, p9), x3_ = cvtpk(pa, pc); \
  unsigned y2_ = cvtpk(pd, pe_), y3_ = cvtpk(pf, pg); \
  P32SWAP(x2_, y2_); P32SWAP(x3_, y3_); \
  union { unsigned u[4]; bf16x8 v; } fa_, fb_; \
  fa_.u[0] = x0_; fa_.u[1] = x1_; fa_.u[2] = y0_; fa_.u[3] = y1_; \
  fb_.u[0] = x2_; fb_.u[1] = x3_; fb_.u[2] = y2_; fb_.u[3] = y3_; \
  O = MFMA32(VB0_, fa_.v, O); \
  O = MFMA32(VB1_, fb_.v, O); \
} while (0)

__global__ __launch_bounds__(256) void k_attn_split(const unsigned short* __restrict__ qbf,
                                                    const unsigned short* __restrict__ kpk,
                                                    const unsigned short* __restrict__ vpk,
                                                    unsigned short* __restrict__ po,
                                                    float* __restrict__ pl) {
  int hh = blockIdx.y;
  int sp = blockIdx.z;
  int t = threadIdx.x;
  int wid = t >> 6, l = t & 63;
  int qc = l & 31, hi = l >> 5;
  int l8 = l * 8;
  int q0w = blockIdx.x * 128 + wid * 32;

  const f32x16 zz16 = {0.f};

  const unsigned short* qp = qbf + (size_t)(q0w + qc) * D + hh * 32 + hi * 8;
  bf16x8 qa0 = *(const bf16x8*)(qp);
  bf16x8 qa1 = *(const bf16x8*)(qp + 16);

  const unsigned short* kB = kpk + ((size_t)hh * NT_TOT + sp * (KV_PER / 32)) * 1024;
  const unsigned short* vB = vpk + ((size_t)hh * NT_TOT + sp * (KV_PER / 32)) * 1024;

  f32x16 oA = {0.f}, oB = {0.f};
  float lsA = 0.f, lsB = 0.f;

  bf16x8 ka0, ka1, va0, va1, kb0r, kb1r, vb0r, vb1r;
  ALOAD(ka0, ka1, va0, va1, 0);
  const int NT = KV_PER / 32;  // 24 tiles
  for (int it = 0; it < NT; it += 2) {
    ALOAD(kb0r, kb1r, vb0r, vb1r, it + 1);
    TILE32(ka0, ka1, va0, va1, oA, lsA);
    if (it + 2 < NT) ALOAD(ka0, ka1, va0, va1, it + 2);
    TILE32(kb0r, kb1r, vb0r, vb1r, oB, lsB);
  }

  f32x16 o = oA + oB;
  float lsum = lsA + lsB;
  float lt = lsum + __shfl_xor(lsum, 32, 64);
  size_t pbase = (size_t)(sp * H + hh) * N_NODES + q0w + qc;
  unsigned short* pop = po + pbase * 32 + 4 * hi;
  uint2 v0, v1, v2, v3;
  v0.x = cvtpk(o[0], o[1]);   v0.y = cvtpk(o[2], o[3]);
  v1.x = cvtpk(o[4], o[5]);   v1.y = cvtpk(o[6], o[7]);
  v2.x = cvtpk(o[8], o[9]);   v2.y = cvtpk(o[10], o[11]);
  v3.x = cvtpk(o[12], o[13]); v3.y = cvtpk(o[14], o[15]);
  *(uint2*)(pop)      = v0;
  *(uint2*)(pop + 8)  = v1;
  *(uint2*)(pop + 16) = v2;
  *(uint2*)(pop + 24) = v3;
  if (l < 32) {
    pl[pbase] = lt;
  }
}

__global__ __launch_bounds__(256) void k_attn_combine(const unsigned short* __restrict__ po,
                                                      const float* __restrict__ pl,
                                                      unsigned short* __restrict__ xabf) {
  int t = blockIdx.x * 256 + threadIdx.x;  // N*D/2 threads, 2 chans each
  int q = t >> 6, cp = t & 63;
  int c2 = cp * 2, hh = c2 >> 5, c = c2 & 31;
  int base = hh * N_NODES + q;
  const int SN = H * N_NODES;
  float ll = 0.f, olo = 0.f, ohi = 0.f;
#pragma unroll
  for (int s = 0; s < SPLITS; s++) {
    ll += pl[s * SN + base];
    unsigned dw = *(const unsigned*)(po + ((size_t)(s * SN + base)) * 32 + c);
    olo += bf2f((unsigned short)(dw & 0xffff));
    ohi += bf2f((unsigned short)(dw >> 16));
  }
  float inv = 1.f / ll;
  *(unsigned*)(xabf + (size_t)q * D + c2) = cvtpk(olo * inv, ohi * inv);
}

// ---------- Wo GEMM via MFMA ----------
__global__ __launch_bounds__(256) void k_ca_gemm(const unsigned short* __restrict__ xabf,
                                                 const unsigned short* __restrict__ wot,
                                                 const float* __restrict__ bo,
                                                 float* __restrict__ yb) {
  int t = threadIdx.x;
  int w = t >> 6, l = t & 63, qc = l & 31, hi = l >> 5;
  int row0 = blockIdx.x * 32, col0 = w * 32;
  f32x16 o = tile_gemm128(xabf, wot, row0, col0, qc, hi);
  float bias = bo[col0 + qc];
#pragma unroll
  for (int r = 0; r < 16; r++) {
    int rr = (r & 3) + 8 * (r >> 2) + 4 * hi;
    yb[(size_t)(row0 + rr) * D + col0 + qc] = o[r] + bias;
  }
}

// ---------- residual + LN + pooled + outputs ----------
__global__ __launch_bounds__(128) void k_ca_ln(const float* __restrict__ yb,
                                               const float* __restrict__ g,
                                               const float* __restrict__ bb,
                                               float* __restrict__ x,
                                               unsigned short* __restrict__ xbf,
                                               float* __restrict__ pooled,
                                               float* __restrict__ outx) {
  int tid = threadIdx.x, r0 = blockIdx.x * 8;
  __shared__ float tmp2[2];
  float gv = g[tid], bv = bb[tid];
  float psum = 0.f;
#pragma unroll
  for (int r = 0; r < 8; r++) {
    int n = r0 + r;
    float y = x[n * D + tid] + yb[n * D + tid];
    float t1 = red128_sum(y, tmp2, tid);
    float t2 = red128_sum(y * y, tmp2, tid);
    float mean = t1 * (1.f / D);
    float var = t2 * (1.f / D) - mean * mean;
    float o = (y - mean) * rsqrtf(var + 1e-5f) * gv + bv;
    x[n * D + tid] = o;
    xbf[n * D + tid] = f2bf(o);
    outx[n * D + tid] = o;
    psum += o;
  }
  atomicAdd(&pooled[tid], psum);
}

// ---------- policy head: stage1/stage2 MFMA, stage3 wave-reduce ----------
__global__ __launch_bounds__(256) void k_policy1(const unsigned short* __restrict__ xbf,
                                                 const unsigned short* __restrict__ w1t,
                                                 const float* __restrict__ b1,
                                                 unsigned short* __restrict__ h1) {
  int t = threadIdx.x;
  int w = t >> 6, l = t & 63, qc = l & 31, hi = l >> 5;
  int row0 = blockIdx.x * 32, col0 = w * 32;
  f32x16 o = tile_gemm128(xbf, w1t, row0, col0, qc, hi);
  float bias = b1[col0 + qc];
#pragma unroll
  for (int r = 0; r < 16; r++) {
    int rr = (r & 3) + 8 * (r >> 2) + 4 * hi;
    h1[(size_t)(row0 + rr) * D + col0 + qc] = f2bf(fmaxf(o[r] + bias, 0.f));
  }
}

__global__ __launch_bounds__(128) void k_policy2(const unsigned short* __restrict__ h1,
                                                 const unsigned short* __restrict__ w2t,
                                                 const float* __restrict__ b2,
                                                 unsigned short* __restrict__ h2) {
  int t = threadIdx.x;
  int w = t >> 6, l = t & 63, qc = l & 31, hi = l >> 5;
  int row0 = blockIdx.x * 32, col0 = w * 32;
  f32x16 o = tile_gemm128(h1, w2t, row0, col0, qc, hi);
  float bias = b2[col0 + qc];
#pragma unroll
  for (int r = 0; r < 16; r++) {
    int rr = (r & 3) + 8 * (r >> 2) + 4 * hi;
    h2[(size_t)(row0 + rr) * 64 + col0 + qc] = f2bf(fmaxf(o[r] + bias, 0.f));
  }
}

__global__ __launch_bounds__(256) void k_policy3(const unsigned short* __restrict__ h2,
                                                 const float* __restrict__ W3,
                                                 const float* __restrict__ b3,
                                                 float* __restrict__ logits) {
  int t = threadIdx.x;
  int wv = t >> 6, l = t & 63;
  int n = blockIdx.x * 4 + wv;
  float h = bf2f(h2[(size_t)n * 64 + l]);
  float p0 = h * W3[l * 2];
  float p1 = h * W3[l * 2 + 1];
#pragma unroll
  for (int m = 1; m < 64; m <<= 1) { p0 += __shfl_xor(p0, m, 64); p1 += __shfl_xor(p1, m, 64); }
  if (l == 0) {
    logits[n * 2] = p0 + b3[0];
    logits[n * 2 + 1] = p1 + b3[1];
  }
}

// ---------- value head (single block) ----------
__global__ __launch_bounds__(128) void k_value(const float* __restrict__ pooled,
                                               const float* __restrict__ W1,
                                               const float* __restrict__ b1,
                                               const float* __restrict__ W2,
                                               const float* __restrict__ b2,
                                               const float* __restrict__ W3,
                                               const float* __restrict__ b3,
                                               float* __restrict__ val) {
  int tid = threadIdx.x;
  __shared__ float ps[D], v1[D], v2[64];
  ps[tid] = pooled[tid] * (1.f / N_NODES);
  __syncthreads();
  float a = b1[tid];
  for (int kk = 0; kk < D; kk++) a += ps[kk] * W1[kk * D + tid];
  v1[tid] = fmaxf(a, 0.f);
  __syncthreads();
  if (tid < 64) {
    float a2 = b2[tid];
    for (int kk = 0; kk < D; kk++) a2 += v1[kk] * W2[kk * 64 + tid];
    v2[tid] = fmaxf(a2, 0.f);
  }
  __syncthreads();
  float p = (tid < 64) ? v2[tid] * W3[tid] : 0.f;
#pragma unroll
  for (int m = 1; m < 64; m <<= 1) p += __shfl_xor(p, m, 64);
  if (tid == 0) val[0] = p + b3[0];
}

extern "C" void kernel_launch(void* const* d_in, const int* in_sizes, int n_in,
                              void* d_out, int out_size, void* d_ws, size_t ws_size,
                              hipStream_t stream) {
  const float* nf   = (const float*)d_in[0];
  const int*   ei   = (const int*)d_in[1];
  const float* pe   = (const float*)d_in[2];
  const float* embW = (const float*)d_in[3];
  const float* embB = (const float*)d_in[4];
  const float* elng = (const float*)d_in[5];
  const float* elnb = (const float*)d_in[6];
  const float* gatW = (const float*)d_in[7];
  const float* aS   = (const float*)d_in[8];
  const float* aD   = (const float*)d_in[9];
  const float* gatB = (const float*)d_in[10];
  const float* lng  = (const float*)d_in[11];
  const float* lnb  = (const float*)d_in[12];
  const float* Wq   = (const float*)d_in[13];
  const float* Wk   = (const float*)d_in[14];
  const float* Wv   = (const float*)d_in[15];
  const float* Wo   = (const float*)d_in[16];
  const float* bq   = (const float*)d_in[17];
  const float* bk   = (const float*)d_in[18];
  const float* bv   = (const float*)d_in[19];
  const float* bo   = (const float*)d_in[20];
  const float* cag  = (const float*)d_in[21];
  const float* cab  = (const float*)d_in[22];
  const float* pW1  = (const float*)d_in[23];
  const float* pb1  = (const float*)d_in[24];
  const float* pW2  = (const float*)d_in[25];
  const float* pb2  = (const float*)d_in[26];
  const float* pW3  = (const float*)d_in[27];
  const float* pb3  = (const float*)d_in[28];
  const float* vW1  = (const float*)d_in[29];
  const float* vb1  = (const float*)d_in[30];
  const float* vW2  = (const float*)d_in[31];
  const float* vb2  = (const float*)d_in[32];
  const float* vW3  = (const float*)d_in[33];
  const float* vb3  = (const float*)d_in[34];

  // workspace layout
  float* fw = (float*)d_ws;
  float* x      = fw; fw += N_NODES * D;
  float* hbuf   = fw; fw += N_NODES * D;   // bf16 h during GAT; fp32 yb for ca
  float* a_s    = fw; fw += N_NODES * H;
  float* a_d    = fw; fw += N_NODES * H;
  float* pooled = fw; fw += 128;
  float* pl     = fw; fw += SPLITS * H * N_NODES;
  unsigned short* ub = (unsigned short*)fw;
  unsigned short* po   = ub; ub += (size_t)SPLITS * H * N_NODES * 32;
  unsigned short* qbf  = ub; ub += N_NODES * D;   // reused as h1/h2 after attention
  unsigned short* kpk  = ub; ub += N_NODES * D;   // reused as xabf after attention
  unsigned short* vpk  = ub; ub += N_NODES * D;
  unsigned short* xbf  = ub; ub += N_NODES * D;
  unsigned short* pebf = ub; ub += N_NODES * D;
  unsigned short* wtb  = ub; ub += L_LAYERS * D * D;
  unsigned short* wqt  = ub; ub += D * D;
  unsigned short* wkt  = ub; ub += D * D;
  unsigned short* wvt  = ub; ub += D * D;
  unsigned short* w1t  = ub; ub += D * D;
  unsigned short* w2t  = ub; ub += 64 * D;
  unsigned short* wot  = ub; ub += D * D;
  int* ib     = (int*)ub;
  int* cnt    = ib; ib += N_NODES;
  int* cur    = ib; ib += N_NODES;
  int* indptr = ib; ib += N_NODES + 16;
  int* sorted = ib;

  unsigned short* hbf  = (unsigned short*)hbuf;  // bf16 alias during GAT
  float* yb            = hbuf;                   // fp32 alias for ca gemm out
  unsigned short* xabf = kpk;                    // kpk free after attn_split
  unsigned short* h1   = qbf;                    // qbf free after attn_split
  unsigned short* h2   = qbf + (size_t)NQ_ * D;

  float* out    = (float*)d_out;
  float* logits = out;
  float* val    = out + NQ_ * 2;
  float* outx   = out + NQ_ * 2 + 1;

  const int* esrc = ei;
  const int* edst = ei + E_EDGES;

  hipLaunchKernelGGL(k_zero, dim3(24), dim3(256), 0, stream, cnt, cur, pooled);
  hipLaunchKernelGGL(k_hist, dim3(512), dim3(256), 0, stream, edst, cnt);
  hipLaunchKernelGGL(k_scan, dim3(1), dim3(256), 0, stream, cnt, indptr);
  hipLaunchKernelGGL(k_scatter, dim3(512), dim3(256), 0, stream, esrc, edst, indptr, cur, sorted);
  hipLaunchKernelGGL(k_embed, dim3(N_NODES), dim3(128), 0, stream, nf, embW, embB, elng, elnb, x, xbf);
  hipLaunchKernelGGL(k_wprep, dim3(L_LAYERS * D * D / 256), dim3(256), 0, stream, gatW, wtb);
  hipLaunchKernelGGL(k_wqkvprep, dim3(352), dim3(256), 0, stream,
                     Wq, Wk, Wv, pW1, pW2, Wo, wqt, wkt, wvt, w1t, w2t, wot);
  hipLaunchKernelGGL(k_pebf, dim3(N_NODES * D / 1024), dim3(256), 0, stream, pe, pebf);
  for (int l = 0; l < L_LAYERS; l++) {
    hipLaunchKernelGGL(k_gat_gemm, dim3(N_NODES / 32), dim3(256), 0, stream,
                       xbf, wtb + l * D * D, hbf);
    hipLaunchKernelGGL(k_gat_attn, dim3(N_NODES / 8), dim3(128), 0, stream,
                       hbf, aS + l * D, aD + l * D, a_s, a_d);
    hipLaunchKernelGGL(k_gat_agg, dim3(N_NODES), dim3(128), 0, stream,
                       hbf, a_s, a_d, indptr, sorted, gatB + l * D, lng + l * D, lnb + l * D, x, xbf);
  }
  hipLaunchKernelGGL(k_qkv_mfma, dim3(N_NODES / 32, 3), dim3(256), 0, stream,
                     xbf, pebf, wqt, wkt, wvt, bq, bk, bv, qbf, kpk, vpk);
  hipLaunchKernelGGL(k_attn_split, dim3(N_NODES / 128, H, SPLITS), dim3(256), 0, stream,
                     qbf, kpk, vpk, po, pl);
  hipLaunchKernelGGL(k_attn_combine, dim3(N_NODES * D / 512), dim3(256), 0, stream,
                     po, pl, xabf);
  hipLaunchKernelGGL(k_ca_gemm, dim3(N_NODES / 32), dim3(256), 0, stream, xabf, wot, bo, yb);
  hipLaunchKernelGGL(k_ca_ln, dim3(N_NODES / 8), dim3(128), 0, stream,
                     yb, cag, cab, x, xbf, pooled, outx);
  hipLaunchKernelGGL(k_policy1, dim3(NQ_ / 32), dim3(256), 0, stream, xbf, w1t, pb1, h1);
  hipLaunchKernelGGL(k_policy2, dim3(NQ_ / 32), dim3(128), 0, stream, h1, w2t, pb2, h2);
  hipLaunchKernelGGL(k_policy3, dim3(NQ_ / 4), dim3(256), 0, stream, h2, pW3, pb3, logits);
  hipLaunchKernelGGL(k_value, dim3(1), dim3(128), 0, stream,
                     pooled, vW1, vb1, vW2, vb2, vW3, vb3, val);
}

// Round 10
// 268.653 us; speedup vs baseline: 1.6846x; 1.0194x over previous
//
#include <hip/hip_runtime.h>
#include <hip/hip_bf16.h>

#define N_NODES 6144
#define NQ_ 3072
#define D 128
#define H 4
#define C 32
#define F_IN 10
#define L_LAYERS 4
#define E_EDGES 393216
#define E_TOT (E_EDGES + N_NODES)
#define SPLITS 8
#define KV_PER (N_NODES / SPLITS)  // 768 keys per split = 24 tiles of 32
#define NT_TOT (N_NODES / 32)      // 192 tiles total
#define LOG2E 1.4426950408889634f

typedef __attribute__((ext_vector_type(8))) short bf16x8;
typedef __attribute__((ext_vector_type(4))) float f32x4;
typedef __attribute__((ext_vector_type(16))) float f32x16;

__device__ __forceinline__ unsigned short f2bf(float f) {
  unsigned u = __float_as_uint(f);
  unsigned r = (u + 0x7fffu + ((u >> 16) & 1u)) >> 16;
  return (unsigned short)r;
}

__device__ __forceinline__ float bf2f(unsigned short s) {
  return __uint_as_float(((unsigned)s) << 16);
}

__device__ __forceinline__ unsigned cvtpk(float lo, float hi) {
  unsigned r;
  asm volatile("v_cvt_pk_bf16_f32 %0, %1, %2" : "=v"(r) : "v"(lo), "v"(hi));
  return r;
}

// vdst-high(lanes 32-63) <-> src0-low(lanes 0-31)
#define P32SWAP(a, b) asm volatile("v_permlane32_swap_b32 %0, %1" : "+v"(a), "+v"(b))

#define MFMA32(A, B, CIN) __builtin_amdgcn_mfma_f32_32x32x16_bf16(A, B, CIN, 0, 0, 0)

// ---------- helpers ----------
__device__ __forceinline__ float red128_sum(float v, float* tmp2, int tid) {
#pragma unroll
  for (int m = 1; m < 64; m <<= 1) v += __shfl_xor(v, m, 64);
  __syncthreads();
  if ((tid & 63) == 0) tmp2[tid >> 6] = v;
  __syncthreads();
  return tmp2[0] + tmp2[1];
}

// dual reduction for 128-thread blocks: a and b summed in one interleaved tree
__device__ __forceinline__ void red128_sum2(float& a, float& b, float* tmp4, int tid) {
#pragma unroll
  for (int m = 1; m < 64; m <<= 1) {
    a += __shfl_xor(a, m, 64);
    b += __shfl_xor(b, m, 64);
  }
  __syncthreads();
  if ((tid & 63) == 0) {
    tmp4[(tid >> 6) * 2]     = a;
    tmp4[(tid >> 6) * 2 + 1] = b;
  }
  __syncthreads();
  a = tmp4[0] + tmp4[2];
  b = tmp4[1] + tmp4[3];
}

// 32x32 output tile of A(rows x 128) @ B^T(cols x 128), both bf16 row-major.
// lane holds D[row=(r&3)+8*(r>>2)+4*hi][col=qc]  (verified fragment map)
__device__ __forceinline__ f32x16 tile_gemm128(const unsigned short* __restrict__ A,
                                               const unsigned short* __restrict__ Bt,
                                               int row0, int col0, int qc, int hi) {
  const unsigned short* ap = A + (size_t)(row0 + qc) * 128 + hi * 8;
  const unsigned short* bp = Bt + (size_t)(col0 + qc) * 128 + hi * 8;
  f32x16 o = {0.f};
#pragma unroll
  for (int kk = 0; kk < 8; kk++) {
    bf16x8 a = *(const bf16x8*)(ap + kk * 16);
    bf16x8 b = *(const bf16x8*)(bp + kk * 16);
    o = MFMA32(a, b, o);
  }
  return o;
}

// ---------- CSR build ----------
__global__ void k_zero(int* cnt, int* cur, float* pooled) {
  int i = blockIdx.x * blockDim.x + threadIdx.x;
  if (i < N_NODES) { cnt[i] = 0; cur[i] = 0; }
  if (i < D) pooled[i] = 0.f;
}

__global__ void k_hist(const int* __restrict__ dst, int* __restrict__ cnt) {
  for (int i = blockIdx.x * blockDim.x + threadIdx.x; i < E_EDGES; i += gridDim.x * blockDim.x)
    atomicAdd(&cnt[dst[i]], 1);
}

__global__ void k_scan(const int* __restrict__ cnt, int* __restrict__ indptr) {
  __shared__ int ps[256];
  int tid = threadIdx.x;
  const int CH = N_NODES / 256;  // 24
  int base = tid * CH;
  int loc[CH];
  int s = 0;
#pragma unroll
  for (int i = 0; i < CH; i++) { loc[i] = cnt[base + i] + 1; s += loc[i]; }  // +1 self loop
  ps[tid] = s;
  __syncthreads();
  for (int off = 1; off < 256; off <<= 1) {
    int v = (tid >= off) ? ps[tid - off] : 0;
    __syncthreads();
    ps[tid] += v;
    __syncthreads();
  }
  int run = (tid == 0) ? 0 : ps[tid - 1];
#pragma unroll
  for (int i = 0; i < CH; i++) { indptr[base + i] = run; run += loc[i]; }
  if (tid == 255) indptr[N_NODES] = run;
}

__global__ void k_scatter(const int* __restrict__ src, const int* __restrict__ dst,
                          const int* __restrict__ indptr, int* __restrict__ cur,
                          int* __restrict__ sorted) {
  for (int i = blockIdx.x * blockDim.x + threadIdx.x; i < E_TOT; i += gridDim.x * blockDim.x) {
    if (i < E_EDGES) {
      int d = dst[i];
      int p = atomicAdd(&cur[d], 1);
      sorted[indptr[d] + p] = src[i];
    } else {
      int n = i - E_EDGES;
      int p = atomicAdd(&cur[n], 1);
      sorted[indptr[n] + p] = n;
    }
  }
}

// ---------- embedding ----------
__global__ __launch_bounds__(128) void k_embed(const float* __restrict__ nf,
                                               const float* __restrict__ W,
                                               const float* __restrict__ b,
                                               const float* __restrict__ g,
                                               const float* __restrict__ bb,
                                               float* __restrict__ x,
                                               unsigned short* __restrict__ xbf) {
  int n = blockIdx.x, j = threadIdx.x;
  __shared__ float f[F_IN];
  __shared__ float tmp4[4];
  if (j < F_IN) f[j] = nf[n * F_IN + j];
  __syncthreads();
  float acc = b[j];
#pragma unroll
  for (int k = 0; k < F_IN; k++) acc += f[k] * W[k * D + j];
  float s1 = acc, s2 = acc * acc;
  red128_sum2(s1, s2, tmp4, j);
  float mean = s1 * (1.f / D);
  float var = s2 * (1.f / D) - mean * mean;
  float y = (acc - mean) * rsqrtf(var + 1e-5f) * g[j] + bb[j];
  y = fmaxf(y, 0.f);
  x[n * D + j] = y;
  xbf[n * D + j] = f2bf(y);
}

// ---------- GAT W -> W^T bf16 (all layers, one-shot) ----------
__global__ void k_wprep(const float* __restrict__ W, unsigned short* __restrict__ wt) {
  int i = blockIdx.x * 256 + threadIdx.x;  // 4*128*128 = 65536
  int l = i >> 14, rem = i & 16383, j = rem >> 7, k = rem & 127;
  wt[i] = f2bf(W[l * 16384 + k * 128 + j]);
}

// ---------- qkv/mlp weight prep: transpose + bf16 ----------
__global__ void k_wqkvprep(const float* __restrict__ Wq, const float* __restrict__ Wk,
                           const float* __restrict__ Wv, const float* __restrict__ W1,
                           const float* __restrict__ W2, const float* __restrict__ Wo,
                           unsigned short* __restrict__ wqt, unsigned short* __restrict__ wkt,
                           unsigned short* __restrict__ wvt, unsigned short* __restrict__ w1t,
                           unsigned short* __restrict__ w2t, unsigned short* __restrict__ wot) {
  int i = blockIdx.x * 256 + threadIdx.x;  // 90112 total
  if (i < 65536) {
    int m = i >> 14, loc = i & 16383, j = loc >> 7, k = loc & 127;
    const float* src = (m == 0) ? Wq : (m == 1) ? Wk : (m == 2) ? Wv : W1;
    unsigned short* dst = (m == 0) ? wqt : (m == 1) ? wkt : (m == 2) ? wvt : w1t;
    dst[loc] = f2bf(src[k * 128 + j]);
  } else if (i < 73728) {
    int loc = i - 65536, j = loc >> 7, k = loc & 127;  // j<64
    w2t[loc] = f2bf(W2[k * 64 + j]);
  } else if (i < 90112) {
    int loc = i - 73728, j = loc >> 7, k = loc & 127;
    wot[loc] = f2bf(Wo[k * 128 + j]);
  }
}

// ---------- pe -> bf16 ----------
__global__ void k_pebf(const float* __restrict__ pe, unsigned short* __restrict__ pebf) {
  int i = blockIdx.x * 256 + threadIdx.x;  // N*D/4
  float4 v = *(const float4*)(pe + (size_t)i * 4);
  unsigned lo = (unsigned)f2bf(v.x) | ((unsigned)f2bf(v.y) << 16);
  unsigned hi = (unsigned)f2bf(v.z) | ((unsigned)f2bf(v.w) << 16);
  *(uint2*)(pebf + (size_t)i * 4) = make_uint2(lo, hi);
}

// ---------- GAT: H = X@W via MFMA (bf16 in/out) ----------
__global__ __launch_bounds__(256) void k_gat_gemm(const unsigned short* __restrict__ xbf,
                                                  const unsigned short* __restrict__ wt,
                                                  unsigned short* __restrict__ hbf) {
  int t = threadIdx.x;
  int w = t >> 6, l = t & 63, qc = l & 31, hi = l >> 5;
  int tile = blockIdx.x * 4 + w;           // 768 tiles = (N/32)*(D/32)
  int row0 = (tile >> 2) * 32, col0 = (tile & 3) * 32;
  f32x16 o = tile_gemm128(xbf, wt, row0, col0, qc, hi);
#pragma unroll
  for (int r = 0; r < 16; r++) {
    int rr = (r & 3) + 8 * (r >> 2) + 4 * hi;
    hbf[(size_t)(row0 + rr) * D + col0 + qc] = f2bf(o[r]);
  }
}

// ---------- GAT: a_s, a_d from h (pre-scaled by log2e) ----------
__global__ __launch_bounds__(128) void k_gat_attn(const unsigned short* __restrict__ hbf,
                                                  const float* __restrict__ asrc,
                                                  const float* __restrict__ adst,
                                                  float* __restrict__ a_s,
                                                  float* __restrict__ a_d) {
  int t = threadIdx.x;
  int ni = t >> 4, j = t & 15;
  int n = blockIdx.x * 8 + ni;
  const unsigned short* hp = hbf + (size_t)n * D + j * 8;
  float p = 0.f, q = 0.f;
#pragma unroll
  for (int c = 0; c < 8; c++) {
    float hv = bf2f(hp[c]);
    p += hv * asrc[j * 8 + c];
    q += hv * adst[j * 8 + c];
  }
  p += __shfl_xor(p, 1); p += __shfl_xor(p, 2);
  q += __shfl_xor(q, 1); q += __shfl_xor(q, 2);
  if ((j & 3) == 0) {
    int head = j >> 2;
    a_s[n * H + head] = p * LOG2E;
    a_d[n * H + head] = q * LOG2E;
  }
}

__device__ __forceinline__ float leaky(float v) { return v > 0.f ? v : 0.2f * v; }

// ---------- GAT aggregation: wave-per-edge, 2ch/lane, single-pass reductions ----------
__global__ __launch_bounds__(256) void k_gat_agg(const unsigned short* __restrict__ hbf,
                                                 const float* __restrict__ a_s,
                                                 const float* __restrict__ a_d,
                                                 const int* __restrict__ indptr,
                                                 const int* __restrict__ sorted,
                                                 const float* __restrict__ gb,
                                                 const float* __restrict__ g,
                                                 const float* __restrict__ bb,
                                                 float* __restrict__ x,
                                                 unsigned short* __restrict__ xbf) {
  int n = blockIdx.x, tid = threadIdx.x;
  int wv = tid >> 6, l = tid & 63;
  int beg = indptr[n], end = indptr[n + 1];
  __shared__ int s_src[256];
  __shared__ float s_ex[256 * 4];
  __shared__ float2 red2[4][64];
  __shared__ float rtmp[16];
  __shared__ float tmp8[8];
  float4 ad = *(const float4*)&a_d[n * H];
  int hsel = l >> 4;  // head of channels 2l, 2l+1
  float accx = 0.f, accy = 0.f;
  float d0 = 0.f, d1 = 0.f, d2 = 0.f, d3 = 0.f;

  for (int c0 = beg; c0 < end; c0 += 256) {
    __syncthreads();
    int e = c0 + tid;
    if (e < end) {
      int s = sorted[e];
      s_src[tid] = s;
      float4 as = *(const float4*)&a_s[s * H];
      float e0 = exp2f(leaky(as.x + ad.x));
      float e1 = exp2f(leaky(as.y + ad.y));
      float e2 = exp2f(leaky(as.z + ad.z));
      float e3 = exp2f(leaky(as.w + ad.w));
      s_ex[tid * 4 + 0] = e0;
      s_ex[tid * 4 + 1] = e1;
      s_ex[tid * 4 + 2] = e2;
      s_ex[tid * 4 + 3] = e3;
      d0 += e0; d1 += e1; d2 += e2; d3 += e3;
    }
    __syncthreads();
    int nc = min(256, end - c0);
    // wave wv processes edges wv, wv+4, ... each edge = full 256B row, uint per lane
#pragma unroll 4
    for (int i = wv; i < nc; i += 4) {
      float al = s_ex[i * 4 + hsel];
      int s = s_src[i];
      unsigned dw = *(const unsigned*)(hbf + (size_t)s * D + l * 2);
      accx += al * bf2f((unsigned short)(dw & 0xffff));
      accy += al * bf2f((unsigned short)(dw >> 16));
    }
  }
  red2[wv][l] = make_float2(accx, accy);
  // reduce 4 denominators in one interleaved wave tree
#pragma unroll
  for (int m = 1; m < 64; m <<= 1) {
    d0 += __shfl_xor(d0, m, 64);
    d1 += __shfl_xor(d1, m, 64);
    d2 += __shfl_xor(d2, m, 64);
    d3 += __shfl_xor(d3, m, 64);
  }
  if (l == 0) {
    rtmp[wv * 4 + 0] = d0; rtmp[wv * 4 + 1] = d1;
    rtmp[wv * 4 + 2] = d2; rtmp[wv * 4 + 3] = d3;
  }
  __syncthreads();

  float y = 0.f;
  int c = tid;
  if (tid < 128) {
    const float* rp0 = (const float*)&red2[0][c >> 1];
    const float* rp1 = (const float*)&red2[1][c >> 1];
    const float* rp2 = (const float*)&red2[2][c >> 1];
    const float* rp3 = (const float*)&red2[3][c >> 1];
    int par = c & 1;
    float sum = rp0[par] + rp1[par] + rp2[par] + rp3[par];
    int hd = c >> 5;
    float dd = rtmp[hd] + rtmp[4 + hd] + rtmp[8 + hd] + rtmp[12 + hd];
    float outv = sum * (1.f / (dd + 1e-16f)) + gb[c];
    y = x[n * D + c] + fmaxf(outv, 0.f);
  }
  // dual LN reduction across all 4 waves (y=0 for tid>=128)
  float sy = y, syy = y * y;
#pragma unroll
  for (int m = 1; m < 64; m <<= 1) {
    sy += __shfl_xor(sy, m, 64);
    syy += __shfl_xor(syy, m, 64);
  }
  if (l == 0) { tmp8[wv * 2] = sy; tmp8[wv * 2 + 1] = syy; }
  __syncthreads();
  if (tid < 128) {
    float s1 = tmp8[0] + tmp8[2] + tmp8[4] + tmp8[6];
    float s2 = tmp8[1] + tmp8[3] + tmp8[5] + tmp8[7];
    float mean = s1 * (1.f / D);
    float var = s2 * (1.f / D) - mean * mean;
    float o = (y - mean) * rsqrtf(var + 1e-5f) * g[c] + bb[c];
    x[n * D + c] = o;
    xbf[n * D + c] = f2bf(o);
  }
}

// ---------- q/k/v via MFMA -> q row-major bf16 (scaled); K,V packed fragment order ----------
__global__ __launch_bounds__(256) void k_qkv_mfma(const unsigned short* __restrict__ xbf,
                                                  const unsigned short* __restrict__ pebf,
                                                  const unsigned short* __restrict__ wqt,
                                                  const unsigned short* __restrict__ wkt,
                                                  const unsigned short* __restrict__ wvt,
                                                  const float* __restrict__ bq,
                                                  const float* __restrict__ bk,
                                                  const float* __restrict__ bv,
                                                  unsigned short* __restrict__ qbf,
                                                  unsigned short* __restrict__ kpk,
                                                  unsigned short* __restrict__ vpk) {
  int t = threadIdx.x;
  int w = t >> 6, l = t & 63, qc = l & 31, hi = l >> 5;
  int m = blockIdx.y;
  int row0 = blockIdx.x * 32, col0 = w * 32;
  const unsigned short* A = (m == 0) ? xbf : pebf;
  const unsigned short* Bt = (m == 0) ? wqt : (m == 1) ? wkt : wvt;
  f32x16 o = tile_gemm128(A, Bt, row0, col0, qc, hi);
  int c = col0 + qc;
  int hh = col0 >> 5;
  int kt = row0 >> 5;
  if (m == 0) {
    const float sc = 0.25503491f;  // 1/sqrt(32)*log2e
    float bias = bq[c];
#pragma unroll
    for (int r = 0; r < 16; r++) {
      int rr = (r & 3) + 8 * (r >> 2) + 4 * hi;
      qbf[(size_t)(row0 + rr) * D + c] = f2bf((o[r] + bias) * sc);
    }
  } else if (m == 1) {
    float bias = bk[c];
    int kfrag = (qc >> 4) & 1, khi = (qc >> 3) & 1, kj = qc & 7;
    unsigned short* base = kpk + ((((size_t)hh * NT_TOT + kt) * 2 + kfrag) * 64 + khi * 32) * 8 + kj;
#pragma unroll
    for (int r = 0; r < 16; r++) {
      int rr = (r & 3) + 8 * (r >> 2) + 4 * hi;
      base[rr * 8] = f2bf(o[r] + bias);
    }
  } else {
    float bias = bv[c];
#pragma unroll
    for (int r = 0; r < 16; r++) {
      int rr = (r & 3) + 8 * (r >> 2) + 4 * hi;
      int vfrag = (rr >> 4) & 1, vhi = (rr >> 3) & 1, vj = rr & 7;
      vpk[((((size_t)hh * NT_TOT + kt) * 2 + vfrag) * 64 + vhi * 32 + qc) * 8 + vj] =
          f2bf(o[r] + bias);
    }
  }
}

// ---------- flash attention: swapped-operand 32x32 MFMA, no-max softmax, dual acc ----------
#define ALOAD(KA0, KA1, VB0_, VB1_, TI) do { \
  const unsigned short* kp_ = kB + (size_t)(TI) * 1024 + l8; \
  const unsigned short* vp_ = vB + (size_t)(TI) * 1024 + l8; \
  KA0 = *(const bf16x8*)(kp_); \
  KA1 = *(const bf16x8*)(kp_ + 512); \
  VB0_ = *(const bf16x8*)(vp_); \
  VB1_ = *(const bf16x8*)(vp_ + 512); \
} while (0)

#define TILE32(KA0, KA1, VB0_, VB1_, O, LS) do { \
  f32x16 s = MFMA32(KA0, qa0, zz16); \
  s = MFMA32(KA1, qa1, s); \
  float p0 = __builtin_amdgcn_exp2f(s[0]), p1 = __builtin_amdgcn_exp2f(s[1]); \
  float p2 = __builtin_amdgcn_exp2f(s[2]), p3 = __builtin_amdgcn_exp2f(s[3]); \
  float p4 = __builtin_amdgcn_exp2f(s[4]), p5 = __builtin_amdgcn_exp2f(s[5]); \
  float p6 = __builtin_amdgcn_exp2f(s[6]), p7 = __builtin_amdgcn_exp2f(s[7]); \
  float p8 = __builtin_amdgcn_exp2f(s[8]), p9 = __builtin_amdgcn_exp2f(s[9]); \
  float pa = __builtin_amdgcn_exp2f(s[10]), pc = __builtin_amdgcn_exp2f(s[11]); \
  float pd = __builtin_amdgcn_exp2f(s[12]), pe_ = __builtin_amdgcn_exp2f(s[13]); \
  float pf = __builtin_amdgcn_exp2f(s[14]), pg = __builtin_amdgcn_exp2f(s[15]); \
  LS += (((p0 + p1) + (p2 + p3)) + ((p4 + p5) + (p6 + p7))) + \
        (((p8 + p9) + (pa + pc)) + ((pd + pe_) + (pf + pg))); \
  unsigned x0_ = cvtpk(p0, p1), x1_ = cvtpk(p2, p3); \
  unsigned y0_ = cvtpk(p4, p5), y1_ = cvtpk(p6, p7); \
  P32SWAP(x0_, y0_); P32SWAP(x1_, y1_); \
  unsigned x2_ = cvtpk(p8, p9), x3_ = cvtpk(pa, pc); \
  unsigned y2_ = cvtpk(pd, pe_), y3_ = cvtpk(pf, pg); \
  P32SWAP(x2_, y2_); P32SWAP(x3_, y3_); \
  union { unsigned u[4]; bf16x8 v; } fa_, fb_; \
  fa_.u[0] = x0_; fa_.u[1] = x1_; fa_.u[2] = y0_; fa_.u[3] = y1_; \
  fb_.u[0] = x2_; fb_.u[1] = x3_; fb_.u[2] = y2_; fb_.u[3] = y3_; \
  O = MFMA32(VB0_, fa_.v, O); \
  O = MFMA32(VB1_, fb_.v, O); \
} while (0)

__global__ __launch_bounds__(256) void k_attn_split(const unsigned short* __restrict__ qbf,
                                                    const unsigned short* __restrict__ kpk,
                                                    const unsigned short* __restrict__ vpk,
                                                    unsigned short* __restrict__ po,
                                                    float* __restrict__ pl) {
  int hh = blockIdx.y;
  int sp = blockIdx.z;
  int t = threadIdx.x;
  int wid = t >> 6, l = t & 63;
  int qc = l & 31, hi = l >> 5;
  int l8 = l * 8;
  int q0w = blockIdx.x * 128 + wid * 32;

  const f32x16 zz16 = {0.f};

  const unsigned short* qp = qbf + (size_t)(q0w + qc) * D + hh * 32 + hi * 8;
  bf16x8 qa0 = *(const bf16x8*)(qp);
  bf16x8 qa1 = *(const bf16x8*)(qp + 16);

  const unsigned short* kB = kpk + ((size_t)hh * NT_TOT + sp * (KV_PER / 32)) * 1024;
  const unsigned short* vB = vpk + ((size_t)hh * NT_TOT + sp * (KV_PER / 32)) * 1024;

  f32x16 oA = {0.f}, oB = {0.f};
  float lsA = 0.f, lsB = 0.f;

  bf16x8 ka0, ka1, va0, va1, kb0r, kb1r, vb0r, vb1r;
  ALOAD(ka0, ka1, va0, va1, 0);
  const int NT = KV_PER / 32;  // 24 tiles
  for (int it = 0; it < NT; it += 2) {
    ALOAD(kb0r, kb1r, vb0r, vb1r, it + 1);
    TILE32(ka0, ka1, va0, va1, oA, lsA);
    if (it + 2 < NT) ALOAD(ka0, ka1, va0, va1, it + 2);
    TILE32(kb0r, kb1r, vb0r, vb1r, oB, lsB);
  }

  f32x16 o = oA + oB;
  float lsum = lsA + lsB;
  float lt = lsum + __shfl_xor(lsum, 32, 64);
  size_t pbase = (size_t)(sp * H + hh) * N_NODES + q0w + qc;
  unsigned short* pop = po + pbase * 32 + 4 * hi;
  uint2 v0, v1, v2, v3;
  v0.x = cvtpk(o[0], o[1]);   v0.y = cvtpk(o[2], o[3]);
  v1.x = cvtpk(o[4], o[5]);   v1.y = cvtpk(o[6], o[7]);
  v2.x = cvtpk(o[8], o[9]);   v2.y = cvtpk(o[10], o[11]);
  v3.x = cvtpk(o[12], o[13]); v3.y = cvtpk(o[14], o[15]);
  *(uint2*)(pop)      = v0;
  *(uint2*)(pop + 8)  = v1;
  *(uint2*)(pop + 16) = v2;
  *(uint2*)(pop + 24) = v3;
  if (l < 32) {
    pl[pbase] = lt;
  }
}

__global__ __launch_bounds__(256) void k_attn_combine(const unsigned short* __restrict__ po,
                                                      const float* __restrict__ pl,
                                                      unsigned short* __restrict__ xabf) {
  int t = blockIdx.x * 256 + threadIdx.x;  // N*D/2 threads, 2 chans each
  int q = t >> 6, cp = t & 63;
  int c2 = cp * 2, hh = c2 >> 5, c = c2 & 31;
  int base = hh * N_NODES + q;
  const int SN = H * N_NODES;
  float ll = 0.f, olo = 0.f, ohi = 0.f;
#pragma unroll
  for (int s = 0; s < SPLITS; s++) {
    ll += pl[s * SN + base];
    unsigned dw = *(const unsigned*)(po + ((size_t)(s * SN + base)) * 32 + c);
    olo += bf2f((unsigned short)(dw & 0xffff));
    ohi += bf2f((unsigned short)(dw >> 16));
  }
  float inv = 1.f / ll;
  *(unsigned*)(xabf + (size_t)q * D + c2) = cvtpk(olo * inv, ohi * inv);
}

// ---------- Wo GEMM via MFMA ----------
__global__ __launch_bounds__(256) void k_ca_gemm(const unsigned short* __restrict__ xabf,
                                                 const unsigned short* __restrict__ wot,
                                                 const float* __restrict__ bo,
                                                 float* __restrict__ yb) {
  int t = threadIdx.x;
  int w = t >> 6, l = t & 63, qc = l & 31, hi = l >> 5;
  int row0 = blockIdx.x * 32, col0 = w * 32;
  f32x16 o = tile_gemm128(xabf, wot, row0, col0, qc, hi);
  float bias = bo[col0 + qc];
#pragma unroll
  for (int r = 0; r < 16; r++) {
    int rr = (r & 3) + 8 * (r >> 2) + 4 * hi;
    yb[(size_t)(row0 + rr) * D + col0 + qc] = o[r] + bias;
  }
}

// ---------- residual + LN + pooled + outputs ----------
__global__ __launch_bounds__(128) void k_ca_ln(const float* __restrict__ yb,
                                               const float* __restrict__ g,
                                               const float* __restrict__ bb,
                                               float* __restrict__ x,
                                               unsigned short* __restrict__ xbf,
                                               float* __restrict__ pooled,
                                               float* __restrict__ outx) {
  int tid = threadIdx.x, r0 = blockIdx.x * 8;
  __shared__ float tmp4[4];
  float gv = g[tid], bv = bb[tid];
  float psum = 0.f;
#pragma unroll
  for (int r = 0; r < 8; r++) {
    int n = r0 + r;
    float y = x[n * D + tid] + yb[n * D + tid];
    float s1 = y, s2 = y * y;
    red128_sum2(s1, s2, tmp4, tid);
    float mean = s1 * (1.f / D);
    float var = s2 * (1.f / D) - mean * mean;
    float o = (y - mean) * rsqrtf(var + 1e-5f) * gv + bv;
    x[n * D + tid] = o;
    xbf[n * D + tid] = f2bf(o);
    outx[n * D + tid] = o;
    psum += o;
  }
  atomicAdd(&pooled[tid], psum);
}

// ---------- policy head: stage1/stage2 MFMA, stage3 wave-reduce ----------
__global__ __launch_bounds__(256) void k_policy1(const unsigned short* __restrict__ xbf,
                                                 const unsigned short* __restrict__ w1t,
                                                 const float* __restrict__ b1,
                                                 unsigned short* __restrict__ h1) {
  int t = threadIdx.x;
  int w = t >> 6, l = t & 63, qc = l & 31, hi = l >> 5;
  int row0 = blockIdx.x * 32, col0 = w * 32;
  f32x16 o = tile_gemm128(xbf, w1t, row0, col0, qc, hi);
  float bias = b1[col0 + qc];
#pragma unroll
  for (int r = 0; r < 16; r++) {
    int rr = (r & 3) + 8 * (r >> 2) + 4 * hi;
    h1[(size_t)(row0 + rr) * D + col0 + qc] = f2bf(fmaxf(o[r] + bias, 0.f));
  }
}

__global__ __launch_bounds__(128) void k_policy2(const unsigned short* __restrict__ h1,
                                                 const unsigned short* __restrict__ w2t,
                                                 const float* __restrict__ b2,
                                                 unsigned short* __restrict__ h2) {
  int t = threadIdx.x;
  int w = t >> 6, l = t & 63, qc = l & 31, hi = l >> 5;
  int row0 = blockIdx.x * 32, col0 = w * 32;
  f32x16 o = tile_gemm128(h1, w2t, row0, col0, qc, hi);
  float bias = b2[col0 + qc];
#pragma unroll
  for (int r = 0; r < 16; r++) {
    int rr = (r & 3) + 8 * (r >> 2) + 4 * hi;
    h2[(size_t)(row0 + rr) * 64 + col0 + qc] = f2bf(fmaxf(o[r] + bias, 0.f));
  }
}

__global__ __launch_bounds__(256) void k_policy3(const unsigned short* __restrict__ h2,
                                                 const float* __restrict__ W3,
                                                 const float* __restrict__ b3,
                                                 float* __restrict__ logits) {
  int t = threadIdx.x;
  int wv = t >> 6, l = t & 63;
  int n = blockIdx.x * 4 + wv;
  float h = bf2f(h2[(size_t)n * 64 + l]);
  float p0 = h * W3[l * 2];
  float p1 = h * W3[l * 2 + 1];
#pragma unroll
  for (int m = 1; m < 64; m <<= 1) { p0 += __shfl_xor(p0, m, 64); p1 += __shfl_xor(p1, m, 64); }
  if (l == 0) {
    logits[n * 2] = p0 + b3[0];
    logits[n * 2 + 1] = p1 + b3[1];
  }
}

// ---------- value head (single block) ----------
__global__ __launch_bounds__(128) void k_value(const float* __restrict__ pooled,
                                               const float* __restrict__ W1,
                                               const float* __restrict__ b1,
                                               const float* __restrict__ W2,
                                               const float* __restrict__ b2,
                                               const float* __restrict__ W3,
                                               const float* __restrict__ b3,
                                               float* __restrict__ val) {
  int tid = threadIdx.x;
  __shared__ float ps[D], v1[D], v2[64];
  ps[tid] = pooled[tid] * (1.f / N_NODES);
  __syncthreads();
  float a = b1[tid];
  for (int kk = 0; kk < D; kk++) a += ps[kk] * W1[kk * D + tid];
  v1[tid] = fmaxf(a, 0.f);
  __syncthreads();
  if (tid < 64) {
    float a2 = b2[tid];
    for (int kk = 0; kk < D; kk++) a2 += v1[kk] * W2[kk * 64 + tid];
    v2[tid] = fmaxf(a2, 0.f);
  }
  __syncthreads();
  float p = (tid < 64) ? v2[tid] * W3[tid] : 0.f;
#pragma unroll
  for (int m = 1; m < 64; m <<= 1) p += __shfl_xor(p, m, 64);
  if (tid == 0) val[0] = p + b3[0];
}

extern "C" void kernel_launch(void* const* d_in, const int* in_sizes, int n_in,
                              void* d_out, int out_size, void* d_ws, size_t ws_size,
                              hipStream_t stream) {
  const float* nf   = (const float*)d_in[0];
  const int*   ei   = (const int*)d_in[1];
  const float* pe   = (const float*)d_in[2];
  const float* embW = (const float*)d_in[3];
  const float* embB = (const float*)d_in[4];
  const float* elng = (const float*)d_in[5];
  const float* elnb = (const float*)d_in[6];
  const float* gatW = (const float*)d_in[7];
  const float* aS   = (const float*)d_in[8];
  const float* aD   = (const float*)d_in[9];
  const float* gatB = (const float*)d_in[10];
  const float* lng  = (const float*)d_in[11];
  const float* lnb  = (const float*)d_in[12];
  const float* Wq   = (const float*)d_in[13];
  const float* Wk   = (const float*)d_in[14];
  const float* Wv   = (const float*)d_in[15];
  const float* Wo   = (const float*)d_in[16];
  const float* bq   = (const float*)d_in[17];
  const float* bk   = (const float*)d_in[18];
  const float* bv   = (const float*)d_in[19];
  const float* bo   = (const float*)d_in[20];
  const float* cag  = (const float*)d_in[21];
  const float* cab  = (const float*)d_in[22];
  const float* pW1  = (const float*)d_in[23];
  const float* pb1  = (const float*)d_in[24];
  const float* pW2  = (const float*)d_in[25];
  const float* pb2  = (const float*)d_in[26];
  const float* pW3  = (const float*)d_in[27];
  const float* pb3  = (const float*)d_in[28];
  const float* vW1  = (const float*)d_in[29];
  const float* vb1  = (const float*)d_in[30];
  const float* vW2  = (const float*)d_in[31];
  const float* vb2  = (const float*)d_in[32];
  const float* vW3  = (const float*)d_in[33];
  const float* vb3  = (const float*)d_in[34];

  // workspace layout
  float* fw = (float*)d_ws;
  float* x      = fw; fw += N_NODES * D;
  float* hbuf   = fw; fw += N_NODES * D;   // bf16 h during GAT; fp32 yb for ca
  float* a_s    = fw; fw += N_NODES * H;
  float* a_d    = fw; fw += N_NODES * H;
  float* pooled = fw; fw += 128;
  float* pl     = fw; fw += SPLITS * H * N_NODES;
  unsigned short* ub = (unsigned short*)fw;
  unsigned short* po   = ub; ub += (size_t)SPLITS * H * N_NODES * 32;
  unsigned short* qbf  = ub; ub += N_NODES * D;   // reused as h1/h2 after attention
  unsigned short* kpk  = ub; ub += N_NODES * D;   // reused as xabf after attention
  unsigned short* vpk  = ub; ub += N_NODES * D;
  unsigned short* xbf  = ub; ub += N_NODES * D;
  unsigned short* pebf = ub; ub += N_NODES * D;
  unsigned short* wtb  = ub; ub += L_LAYERS * D * D;
  unsigned short* wqt  = ub; ub += D * D;
  unsigned short* wkt  = ub; ub += D * D;
  unsigned short* wvt  = ub; ub += D * D;
  unsigned short* w1t  = ub; ub += D * D;
  unsigned short* w2t  = ub; ub += 64 * D;
  unsigned short* wot  = ub; ub += D * D;
  int* ib     = (int*)ub;
  int* cnt    = ib; ib += N_NODES;
  int* cur    = ib; ib += N_NODES;
  int* indptr = ib; ib += N_NODES + 16;
  int* sorted = ib;

  unsigned short* hbf  = (unsigned short*)hbuf;  // bf16 alias during GAT
  float* yb            = hbuf;                   // fp32 alias for ca gemm out
  unsigned short* xabf = kpk;                    // kpk free after attn_split
  unsigned short* h1   = qbf;                    // qbf free after attn_split
  unsigned short* h2   = qbf + (size_t)NQ_ * D;

  float* out    = (float*)d_out;
  float* logits = out;
  float* val    = out + NQ_ * 2;
  float* outx   = out + NQ_ * 2 + 1;

  const int* esrc = ei;
  const int* edst = ei + E_EDGES;

  hipLaunchKernelGGL(k_zero, dim3(24), dim3(256), 0, stream, cnt, cur, pooled);
  hipLaunchKernelGGL(k_hist, dim3(512), dim3(256), 0, stream, edst, cnt);
  hipLaunchKernelGGL(k_scan, dim3(1), dim3(256), 0, stream, cnt, indptr);
  hipLaunchKernelGGL(k_scatter, dim3(512), dim3(256), 0, stream, esrc, edst, indptr, cur, sorted);
  hipLaunchKernelGGL(k_embed, dim3(N_NODES), dim3(128), 0, stream, nf, embW, embB, elng, elnb, x, xbf);
  hipLaunchKernelGGL(k_wprep, dim3(L_LAYERS * D * D / 256), dim3(256), 0, stream, gatW, wtb);
  hipLaunchKernelGGL(k_wqkvprep, dim3(352), dim3(256), 0, stream,
                     Wq, Wk, Wv, pW1, pW2, Wo, wqt, wkt, wvt, w1t, w2t, wot);
  hipLaunchKernelGGL(k_pebf, dim3(N_NODES * D / 1024), dim3(256), 0, stream, pe, pebf);
  for (int l = 0; l < L_LAYERS; l++) {
    hipLaunchKernelGGL(k_gat_gemm, dim3(N_NODES / 32), dim3(256), 0, stream,
                       xbf, wtb + l * D * D, hbf);
    hipLaunchKernelGGL(k_gat_attn, dim3(N_NODES / 8), dim3(128), 0, stream,
                       hbf, aS + l * D, aD + l * D, a_s, a_d);
    hipLaunchKernelGGL(k_gat_agg, dim3(N_NODES), dim3(256), 0, stream,
                       hbf, a_s, a_d, indptr, sorted, gatB + l * D, lng + l * D, lnb + l * D, x, xbf);
  }
  hipLaunchKernelGGL(k_qkv_mfma, dim3(N_NODES / 32, 3), dim3(256), 0, stream,
                     xbf, pebf, wqt, wkt, wvt, bq, bk, bv, qbf, kpk, vpk);
  hipLaunchKernelGGL(k_attn_split, dim3(N_NODES / 128, H, SPLITS), dim3(256), 0, stream,
                     qbf, kpk, vpk, po, pl);
  hipLaunchKernelGGL(k_attn_combine, dim3(N_NODES * D / 512), dim3(256), 0, stream,
                     po, pl, xabf);
  hipLaunchKernelGGL(k_ca_gemm, dim3(N_NODES / 32), dim3(256), 0, stream, xabf, wot, bo, yb);
  hipLaunchKernelGGL(k_ca_ln, dim3(N_NODES / 8), dim3(128), 0, stream,
                     yb, cag, cab, x, xbf, pooled, outx);
  hipLaunchKernelGGL(k_policy1, dim3(NQ_ / 32), dim3(256), 0, stream, xbf, w1t, pb1, h1);
  hipLaunchKernelGGL(k_policy2, dim3(NQ_ / 32), dim3(128), 0, stream, h1, w2t, pb2, h2);
  hipLaunchKernelGGL(k_policy3, dim3(NQ_ / 4), dim3(256), 0, stream, h2, pW3, pb3, logits);
  hipLaunchKernelGGL(k_value, dim3(1), dim3(128), 0, stream,
                     pooled, vW1, vb1, vW2, vb2, vW3, vb3, val);
}